// Round 2
// baseline (439.337 us; speedup 1.0000x reference)
//
#include <hip/hip_runtime.h>
#include <hip/hip_bf16.h>
#include <stdint.h>

#define SEQ      4096
#define BATCH    2
#define NTOK     (BATCH*SEQ)        // 8192
#define DMODEL   768
#define DINNER   1536
#define NHEADS   24
#define HEADDIM  64
#define DSTATE   16
#define CONVDIM  1568               // 1536 x-heads + 16 B + 16 C
#define NPAD     3200               // GEMM1 padded N (25 * 128); cols >=3104 dropped
#define NREAL    3104               // z (1536) + xBC (1568)
#define EPSV     1e-5f
#define CHUNK    256
#define NCHUNK   (SEQ/CHUNK)        // 16
#define SUB      32

typedef __bf16 bf16x8 __attribute__((ext_vector_type(8)));
typedef float  floatx4 __attribute__((ext_vector_type(4)));

__device__ __forceinline__ unsigned short f2bf(float f) {
    union { float f; uint32_t u; } v; v.f = f;
    uint32_t u = v.u;
    uint32_t r = (u + 0x7fffu + ((u >> 16) & 1u)) >> 16;
    return (unsigned short)r;
}

__device__ __forceinline__ float bf2f(unsigned short h) {
    union { uint32_t u; float f; } v; v.u = (uint32_t)h << 16;
    return v.f;
}

__device__ __forceinline__ float siluf(float x) { return x / (1.f + __expf(-x)); }

__device__ __forceinline__ float dot4(float4 a, float4 b) {
    return a.x*b.x + a.y*b.y + a.z*b.z + a.w*b.w;
}

__device__ __forceinline__ void async_cp16(const void* g, void* l) {
    __builtin_amdgcn_global_load_lds(
        (const __attribute__((address_space(1))) void*)g,
        (__attribute__((address_space(3))) void*)l,
        16, 0, 0);
}

// ---------------------------------------------------------------------------
// Weight conversion: W_in [3128,768] f32 -> bf16 padded to [3200,768] (zero pad),
// W_out [768,1536] f32 -> bf16.
// ---------------------------------------------------------------------------
__global__ __launch_bounds__(256) void cvt_kernel(
    const float* __restrict__ Win, const float* __restrict__ Wout,
    unsigned short* __restrict__ win16, unsigned short* __restrict__ wout16)
{
    int idx = blockIdx.x * 256 + threadIdx.x;
    const int n1 = NPAD * DMODEL;          // 2457600
    if (idx < n1) {
        int r = idx / DMODEL;
        win16[idx] = (r < 3128) ? f2bf(Win[idx]) : (unsigned short)0;
    } else {
        int i2 = idx - n1;
        if (i2 < DMODEL * DINNER) wout16[i2] = f2bf(Wout[i2]);
    }
}

// ---------------------------------------------------------------------------
// Fused LayerNorm + dt path.  One wave per token.
// u = LN(x); u16 = bf16(u); raw_h = u . W_in[3104+h] (f32);
// dt = softplus(raw+bias); dA = exp(dt * -exp(A_log)).
// ---------------------------------------------------------------------------
__global__ __launch_bounds__(256) void ln_dt_kernel(
    const float* __restrict__ x, const float* __restrict__ lnw, const float* __restrict__ lnb,
    const float* __restrict__ Win, const float* __restrict__ dt_bias, const float* __restrict__ A_log,
    unsigned short* __restrict__ u16, float* __restrict__ dtv, float* __restrict__ dAv)
{
    int wave = threadIdx.x >> 6, lane = threadIdx.x & 63;
    int token = blockIdx.x * 4 + wave;
    const float* row = x + (size_t)token * DMODEL;
    float4 v[3];
    float s = 0.f, ss = 0.f;
#pragma unroll
    for (int j = 0; j < 3; ++j) {
        v[j] = *(const float4*)(row + lane*4 + j*256);
        s  += v[j].x + v[j].y + v[j].z + v[j].w;
        ss += v[j].x*v[j].x + v[j].y*v[j].y + v[j].z*v[j].z + v[j].w*v[j].w;
    }
#pragma unroll
    for (int o = 32; o > 0; o >>= 1) { s += __shfl_xor(s, o, 64); ss += __shfl_xor(ss, o, 64); }
    float mean = s * (1.f/768.f);
    float var  = ss * (1.f/768.f) - mean*mean;
    float rstd = rsqrtf(var + EPSV);
    unsigned short* brow = u16 + (size_t)token * DMODEL;
    float4 u[3];
#pragma unroll
    for (int j = 0; j < 3; ++j) {
        int cidx = lane*4 + j*256;
        float4 w4 = *(const float4*)(lnw + cidx);
        float4 b4 = *(const float4*)(lnb + cidx);
        u[j].x = (v[j].x - mean)*rstd*w4.x + b4.x;
        u[j].y = (v[j].y - mean)*rstd*w4.y + b4.y;
        u[j].z = (v[j].z - mean)*rstd*w4.z + b4.z;
        u[j].w = (v[j].w - mean)*rstd*w4.w + b4.w;
        ushort4 p; p.x = f2bf(u[j].x); p.y = f2bf(u[j].y); p.z = f2bf(u[j].z); p.w = f2bf(u[j].w);
        *(ushort4*)(brow + cidx) = p;
    }
    for (int hh = 0; hh < NHEADS; ++hh) {
        const float* wrow = Win + (size_t)(3104 + hh) * DMODEL;
        float p = 0.f;
#pragma unroll
        for (int j = 0; j < 3; ++j) {
            float4 wv = *(const float4*)(wrow + lane*4 + j*256);
            p += dot4(u[j], wv);
        }
#pragma unroll
        for (int o = 32; o > 0; o >>= 1) p += __shfl_xor(p, o, 64);
        if (lane == 0) {
            float raw = p + dt_bias[hh];
            float dt = (raw > 20.f) ? raw : log1pf(__expf(raw));
            float A = -__expf(A_log[hh]);
            dtv[(size_t)token*NHEADS + hh] = dt;
            dAv[(size_t)token*NHEADS + hh] = __expf(dt * A);
        }
    }
}

// ---------------------------------------------------------------------------
// bf16 MFMA GEMM, B^T layout.  128x128 tile, BK=32, global_load_lds width 16.
// MODE 0: C = u16 @ win16^T, split store: cols<1536 -> z16 (bf16), cols 1536..3103 -> xbcr f32
// MODE 1: C = g16 @ wout16^T + resid -> Cf f32
// ---------------------------------------------------------------------------
template<int MODE>
__global__ __launch_bounds__(256, 2) void gemm_bt(
    const unsigned short* __restrict__ A, const unsigned short* __restrict__ Bt,
    float* __restrict__ Cf, unsigned short* __restrict__ z16,
    float* __restrict__ xbcr, const float* __restrict__ resid)
{
    constexpr int K = (MODE == 0) ? DMODEL : DINNER;
    __shared__ unsigned short As[128*32];
    __shared__ unsigned short Bs[128*32];
    const int tid  = threadIdx.x;
    const int lane = tid & 63;
    const int wave = tid >> 6;
    const int m0 = blockIdx.y * 128;
    const int n0 = blockIdx.x * 128;
    const int wm = (wave & 1) * 64;
    const int wn = (wave >> 1) * 64;

    floatx4 acc[4][4];
#pragma unroll
    for (int i = 0; i < 4; ++i)
#pragma unroll
        for (int j = 0; j < 4; ++j) acc[i][j] = floatx4{0.f, 0.f, 0.f, 0.f};

    const int srow = lane >> 2;           // 0..15
    const int scol = (lane & 3) * 8;      // k-element offset

    for (int k0 = 0; k0 < K; k0 += 32) {
        __syncthreads();
#pragma unroll
        for (int r = 0; r < 2; ++r) {
            int trow = r*64 + wave*16;
            const unsigned short* ga = A  + (size_t)(m0 + trow + srow) * K + k0 + scol;
            const unsigned short* gb = Bt + (size_t)(n0 + trow + srow) * K + k0 + scol;
            async_cp16(ga, As + (size_t)trow * 32);
            async_cp16(gb, Bs + (size_t)trow * 32);
        }
        __syncthreads();
        const int fr = lane & 15;
        const int fq = (lane >> 4) * 8;
        bf16x8 a[4], b[4];
#pragma unroll
        for (int i = 0; i < 4; ++i) a[i] = *(const bf16x8*)(As + (wm + i*16 + fr)*32 + fq);
#pragma unroll
        for (int j = 0; j < 4; ++j) b[j] = *(const bf16x8*)(Bs + (wn + j*16 + fr)*32 + fq);
#pragma unroll
        for (int i = 0; i < 4; ++i)
#pragma unroll
            for (int j = 0; j < 4; ++j)
                acc[i][j] = __builtin_amdgcn_mfma_f32_16x16x32_bf16(a[i], b[j], acc[i][j], 0, 0, 0);
    }

    const int col = lane & 15;
    const int rq  = (lane >> 4) * 4;
#pragma unroll
    for (int i = 0; i < 4; ++i) {
#pragma unroll
        for (int j = 0; j < 4; ++j) {
#pragma unroll
            for (int r = 0; r < 4; ++r) {
                int gm = m0 + wm + i*16 + rq + r;
                int gn = n0 + wn + j*16 + col;
                float v = acc[i][j][r];
                if (MODE == 0) {
                    if (gn < DINNER)
                        z16[(size_t)gm * DINNER + gn] = f2bf(v);
                    else if (gn < NREAL)
                        xbcr[(size_t)gm * CONVDIM + (gn - DINNER)] = v;
                } else {
                    Cf[(size_t)gm * DMODEL + gn] = v + resid[(size_t)gm * DMODEL + gn];
                }
            }
        }
    }
}

// ---------------------------------------------------------------------------
// Depthwise causal conv(4) + bias + silu: xbcr [8192,1568] f32 -> xbc [8192,1568]
// ---------------------------------------------------------------------------
__global__ __launch_bounds__(256) void conv_kernel(
    const float* __restrict__ xbcr, const float* __restrict__ cw,
    const float* __restrict__ cb, float* __restrict__ xbc)
{
    int c4 = blockIdx.x * 256 + threadIdx.x;
    if (c4 >= CONVDIM/4) return;
    int row = blockIdx.y;
    int l = row & (SEQ - 1);
    int c = c4 * 4;
    const float* base = xbcr + (size_t)row * CONVDIM + c;
    float4 w0 = *(const float4*)(cw + (c+0)*4);
    float4 w1 = *(const float4*)(cw + (c+1)*4);
    float4 w2 = *(const float4*)(cw + (c+2)*4);
    float4 w3 = *(const float4*)(cw + (c+3)*4);
    float4 acc = *(const float4*)(cb + c);
#pragma unroll
    for (int i = 0; i < 4; ++i) {
        int dl = i - 3;
        if (l + dl >= 0) {
            float4 in = *(const float4*)(base + (ptrdiff_t)dl * CONVDIM);
            acc.x += in.x * ((const float*)&w0)[i];
            acc.y += in.y * ((const float*)&w1)[i];
            acc.z += in.z * ((const float*)&w2)[i];
            acc.w += in.w * ((const float*)&w3)[i];
        }
    }
    acc.x = siluf(acc.x); acc.y = siluf(acc.y); acc.z = siluf(acc.z); acc.w = siluf(acc.w);
    *(float4*)(xbc + (size_t)row * CONVDIM + c) = acc;
}

// ---------------------------------------------------------------------------
// SSM scan, chunked. Pass 1: per (b,h,chunk) local end-state + decay product.
// ---------------------------------------------------------------------------
__global__ __launch_bounds__(64) void scan_pass1(
    const float* __restrict__ xbc, const float* __restrict__ dAv, const float* __restrict__ dtv,
    float* __restrict__ hloc, float* __restrict__ pprod)
{
    int blk = blockIdx.x;                 // (b*24+h)*16 + c
    int c = blk & 15, bh = blk >> 4;
    int h = bh % NHEADS, b = bh / NHEADS;
    int lane = threadIdx.x;
    int row0 = b * SEQ + c * CHUNK;
    __shared__ float xs[SUB][64];
    __shared__ float bs[SUB][16];
    __shared__ float av[SUB], dv[SUB];
    float hst[16];
#pragma unroll
    for (int n = 0; n < 16; ++n) hst[n] = 0.f;
    float aprod = 1.f;
    for (int sc = 0; sc < CHUNK/SUB; ++sc) {
        int rb = row0 + sc * SUB;
        __syncthreads();
#pragma unroll
        for (int it = 0; it < 8; ++it) {
            int idx = it*64 + lane, s = idx >> 4, q = idx & 15;
            *(float4*)&xs[s][q*4] = *(const float4*)(xbc + (size_t)(rb+s)*CONVDIM + h*64 + q*4);
        }
#pragma unroll
        for (int it = 0; it < 2; ++it) {
            int idx = it*64 + lane, s = idx >> 2, q = idx & 3;
            *(float4*)&bs[s][q*4] = *(const float4*)(xbc + (size_t)(rb+s)*CONVDIM + DINNER + q*4);
        }
        if (lane < 32) av[lane] = dAv[(size_t)(rb+lane)*NHEADS + h];
        else           dv[lane-32] = dtv[(size_t)(rb+lane-32)*NHEADS + h];
        __syncthreads();
#pragma unroll 4
        for (int s = 0; s < SUB; ++s) {
            float a = av[s];
            float scale = dv[s] * xs[s][lane];
            const float* bp = bs[s];
#pragma unroll
            for (int n = 0; n < 16; ++n) hst[n] = a*hst[n] + scale*bp[n];
            aprod *= a;
        }
    }
    float* o = hloc + (size_t)blk * 1024 + lane * 16;
#pragma unroll
    for (int n = 0; n < 16; ++n) o[n] = hst[n];
    if (lane == 0) pprod[blk] = aprod;
}

// Pass 2: sequential recombine over 16 chunks per (b,h).
__global__ __launch_bounds__(64) void scan_pass2(
    const float* __restrict__ hloc, const float* __restrict__ pprod, float* __restrict__ hstart)
{
    int bh = blockIdx.x, lane = threadIdx.x;
    float hst[16];
#pragma unroll
    for (int n = 0; n < 16; ++n) hst[n] = 0.f;
    for (int c = 0; c < NCHUNK; ++c) {
        int blk = bh * NCHUNK + c;
        float* o = hstart + (size_t)blk * 1024 + lane * 16;
#pragma unroll
        for (int n = 0; n < 16; ++n) o[n] = hst[n];
        float P = pprod[blk];
        const float* hl = hloc + (size_t)blk * 1024 + lane * 16;
#pragma unroll
        for (int n = 0; n < 16; ++n) hst[n] = P * hst[n] + hl[n];
    }
}

// Pass 3: replay chunk from h_start, emit y = C.h + D*x.
__global__ __launch_bounds__(64) void scan_pass3(
    const float* __restrict__ xbc, const float* __restrict__ dAv, const float* __restrict__ dtv,
    const float* __restrict__ hstart, const float* __restrict__ Dp, float* __restrict__ yv)
{
    int blk = blockIdx.x;
    int c = blk & 15, bh = blk >> 4;
    int h = bh % NHEADS, b = bh / NHEADS;
    int lane = threadIdx.x;
    int row0 = b * SEQ + c * CHUNK;
    __shared__ float xs[SUB][64];
    __shared__ float bcs[SUB][32];        // B then C
    __shared__ float av[SUB], dv[SUB];
    float hst[16];
    const float* hs = hstart + (size_t)blk * 1024 + lane * 16;
#pragma unroll
    for (int n = 0; n < 16; ++n) hst[n] = hs[n];
    float Dh = Dp[h];
    for (int sc = 0; sc < CHUNK/SUB; ++sc) {
        int rb = row0 + sc * SUB;
        __syncthreads();
#pragma unroll
        for (int it = 0; it < 8; ++it) {
            int idx = it*64 + lane, s = idx >> 4, q = idx & 15;
            *(float4*)&xs[s][q*4] = *(const float4*)(xbc + (size_t)(rb+s)*CONVDIM + h*64 + q*4);
        }
#pragma unroll
        for (int it = 0; it < 4; ++it) {
            int idx = it*64 + lane, s = idx >> 3, q = idx & 7;
            *(float4*)&bcs[s][q*4] = *(const float4*)(xbc + (size_t)(rb+s)*CONVDIM + DINNER + q*4);
        }
        if (lane < 32) av[lane] = dAv[(size_t)(rb+lane)*NHEADS + h];
        else           dv[lane-32] = dtv[(size_t)(rb+lane-32)*NHEADS + h];
        __syncthreads();
#pragma unroll 4
        for (int s = 0; s < SUB; ++s) {
            float a = av[s];
            float xv = xs[s][lane];
            float scale = dv[s] * xv;
            const float* bp = bcs[s];
            float y = Dh * xv;
#pragma unroll
            for (int n = 0; n < 16; ++n) hst[n] = a*hst[n] + scale*bp[n];
#pragma unroll
            for (int n = 0; n < 16; ++n) y += hst[n] * bp[16+n];
            yv[(size_t)(rb+s)*DINNER + h*64 + lane] = y;
        }
    }
}

// ---------------------------------------------------------------------------
// Gating + RMSNorm: g = y*silu(z); g *= rsqrt(mean g^2 + eps)*gate_w; -> bf16
// ---------------------------------------------------------------------------
__global__ __launch_bounds__(256) void gate_kernel(
    const float* __restrict__ yv, const unsigned short* __restrict__ z16,
    const float* __restrict__ gw, unsigned short* __restrict__ g16)
{
    int wave = threadIdx.x >> 6, lane = threadIdx.x & 63;
    int token = blockIdx.x * 4 + wave;
    const float* yrow = yv + (size_t)token * DINNER;
    const unsigned short* zrow = z16 + (size_t)token * DINNER;
    float4 gv[6];
    float ss = 0.f;
#pragma unroll
    for (int j = 0; j < 6; ++j) {
        int cidx = lane*4 + j*256;
        float4 y4 = *(const float4*)(yrow + cidx);
        ushort4 z4 = *(const ushort4*)(zrow + cidx);
        gv[j].x = y4.x * siluf(bf2f(z4.x));
        gv[j].y = y4.y * siluf(bf2f(z4.y));
        gv[j].z = y4.z * siluf(bf2f(z4.z));
        gv[j].w = y4.w * siluf(bf2f(z4.w));
        ss += gv[j].x*gv[j].x + gv[j].y*gv[j].y + gv[j].z*gv[j].z + gv[j].w*gv[j].w;
    }
#pragma unroll
    for (int o = 32; o > 0; o >>= 1) ss += __shfl_xor(ss, o, 64);
    float scale = rsqrtf(ss * (1.f/1536.f) + EPSV);
    unsigned short* orow = g16 + (size_t)token * DINNER;
#pragma unroll
    for (int j = 0; j < 6; ++j) {
        int cidx = lane*4 + j*256;
        float4 w4 = *(const float4*)(gw + cidx);
        ushort4 p;
        p.x = f2bf(gv[j].x * scale * w4.x);
        p.y = f2bf(gv[j].y * scale * w4.y);
        p.z = f2bf(gv[j].z * scale * w4.z);
        p.w = f2bf(gv[j].w * scale * w4.w);
        *(ushort4*)(orow + cidx) = p;
    }
}

// ---------------------------------------------------------------------------
extern "C" void kernel_launch(void* const* d_in, const int* in_sizes, int n_in,
                              void* d_out, int out_size, void* d_ws, size_t ws_size,
                              hipStream_t stream)
{
    const float* x        = (const float*)d_in[0];
    const float* ln_w     = (const float*)d_in[1];
    const float* ln_b     = (const float*)d_in[2];
    const float* W_in     = (const float*)d_in[3];
    const float* conv_w   = (const float*)d_in[4];
    const float* conv_b   = (const float*)d_in[5];
    const float* dt_bias  = (const float*)d_in[6];
    const float* A_log    = (const float*)d_in[7];
    const float* Dp       = (const float*)d_in[8];
    const float* gate_w   = (const float*)d_in[9];
    const float* W_out    = (const float*)d_in[10];
    float* out = (float*)d_out;

    char* ws = (char*)d_ws;
    size_t off = 0;
    auto alloc = [&](size_t bytes) -> void* {
        void* p = ws + off;
        off += (bytes + 255) & ~(size_t)255;
        return p;
    };
    // ---- region 0: dead after scan_pass3; g16 aliases it (gate runs after) ----
    unsigned short* u16    = (unsigned short*)alloc((size_t)NTOK*DMODEL*2);       // 12.6 MB
    unsigned short* win16  = (unsigned short*)alloc((size_t)NPAD*DMODEL*2);       //  4.9 MB
    float*          hloc   = (float*)alloc((size_t)BATCH*NHEADS*NCHUNK*1024*4);   //  3.1 MB
    float*          hstart = (float*)alloc((size_t)BATCH*NHEADS*NCHUNK*1024*4);   //  3.1 MB
    float*          dtv    = (float*)alloc((size_t)NTOK*NHEADS*4);                //  0.8 MB
    float*          dAv    = (float*)alloc((size_t)NTOK*NHEADS*4);                //  0.8 MB
    // ---- region 1: xbcr dead after conv; yv aliases it (pass3 runs after) ----
    float*          xbcr   = (float*)alloc((size_t)NTOK*CONVDIM*4);               // 51.4 MB
    // ---- long-lived ----
    unsigned short* wout16 = (unsigned short*)alloc((size_t)DMODEL*DINNER*2);     //  2.4 MB
    unsigned short* z16    = (unsigned short*)alloc((size_t)NTOK*DINNER*2);       // 25.2 MB
    float*          xbc    = (float*)alloc((size_t)NTOK*CONVDIM*4);               // 51.4 MB
    float*          pprod  = (float*)alloc((size_t)BATCH*NHEADS*NCHUNK*4);
    // aliases
    unsigned short* g16 = (unsigned short*)ws;    // 25.2 MB over region 0 (<= 25.4 MB)
    float*          yv  = xbcr;                   // 50.3 MB over region 1 (<= 51.4 MB)
    // high-water: ~148.5 MiB total

    cvt_kernel<<<(NPAD*DMODEL + DMODEL*DINNER)/256, 256, 0, stream>>>(W_in, W_out, win16, wout16);
    ln_dt_kernel<<<NTOK/4, 256, 0, stream>>>(x, ln_w, ln_b, W_in, dt_bias, A_log, u16, dtv, dAv);
    gemm_bt<0><<<dim3(NPAD/128, NTOK/128), 256, 0, stream>>>(
        u16, win16, nullptr, z16, xbcr, nullptr);
    conv_kernel<<<dim3(2, NTOK), 256, 0, stream>>>(xbcr, conv_w, conv_b, xbc);
    scan_pass1<<<BATCH*NHEADS*NCHUNK, 64, 0, stream>>>(xbc, dAv, dtv, hloc, pprod);
    scan_pass2<<<BATCH*NHEADS, 64, 0, stream>>>(hloc, pprod, hstart);
    scan_pass3<<<BATCH*NHEADS*NCHUNK, 64, 0, stream>>>(xbc, dAv, dtv, hstart, Dp, yv);
    gate_kernel<<<NTOK/4, 256, 0, stream>>>(yv, z16, gate_w, g16);
    gemm_bt<1><<<dim3(DMODEL/128, NTOK/128), 256, 0, stream>>>(
        g16, wout16, out, nullptr, nullptr, x);
}

// Round 3
// 399.526 us; speedup vs baseline: 1.0996x; 1.0996x over previous
//
#include <hip/hip_runtime.h>
#include <hip/hip_bf16.h>
#include <stdint.h>

#define SEQ      4096
#define BATCH    2
#define NTOK     (BATCH*SEQ)        // 8192
#define DMODEL   768
#define DINNER   1536
#define NHEADS   24
#define HEADDIM  64
#define DSTATE   16
#define CONVDIM  1568               // 1536 x-heads + 16 B + 16 C
#define NPAD     3200               // GEMM1 padded N (25 * 128); cols >=3104 dropped
#define NREAL    3104               // z (1536) + xBC (1568)
#define EPSV     1e-5f
#define CHUNK    128
#define NCHUNK   (SEQ/CHUNK)        // 32
#define SUB      32

typedef __bf16 bf16x8 __attribute__((ext_vector_type(8)));
typedef float  floatx4 __attribute__((ext_vector_type(4)));

__device__ __forceinline__ unsigned short f2bf(float f) {
    union { float f; uint32_t u; } v; v.f = f;
    uint32_t u = v.u;
    uint32_t r = (u + 0x7fffu + ((u >> 16) & 1u)) >> 16;
    return (unsigned short)r;
}

__device__ __forceinline__ float bf2f(unsigned short h) {
    union { uint32_t u; float f; } v; v.u = (uint32_t)h << 16;
    return v.f;
}

__device__ __forceinline__ float siluf(float x) { return x / (1.f + __expf(-x)); }

__device__ __forceinline__ float dot4(float4 a, float4 b) {
    return a.x*b.x + a.y*b.y + a.z*b.z + a.w*b.w;
}

__device__ __forceinline__ void async_cp16(const void* g, void* l) {
    __builtin_amdgcn_global_load_lds(
        (const __attribute__((address_space(1))) void*)g,
        (__attribute__((address_space(3))) void*)l,
        16, 0, 0);
}

// ---------------------------------------------------------------------------
// Weight conversion.
// ---------------------------------------------------------------------------
__global__ __launch_bounds__(256) void cvt_kernel(
    const float* __restrict__ Win, const float* __restrict__ Wout,
    unsigned short* __restrict__ win16, unsigned short* __restrict__ wout16)
{
    int idx = blockIdx.x * 256 + threadIdx.x;
    const int n1 = NPAD * DMODEL;
    if (idx < n1) {
        int r = idx / DMODEL;
        win16[idx] = (r < 3128) ? f2bf(Win[idx]) : (unsigned short)0;
    } else {
        int i2 = idx - n1;
        if (i2 < DMODEL * DINNER) wout16[i2] = f2bf(Wout[i2]);
    }
}

// ---------------------------------------------------------------------------
// Fused LayerNorm + dt path.  One wave per token.
// ---------------------------------------------------------------------------
__global__ __launch_bounds__(256) void ln_dt_kernel(
    const float* __restrict__ x, const float* __restrict__ lnw, const float* __restrict__ lnb,
    const float* __restrict__ Win, const float* __restrict__ dt_bias, const float* __restrict__ A_log,
    unsigned short* __restrict__ u16, float* __restrict__ dtv, float* __restrict__ dAv)
{
    int wave = threadIdx.x >> 6, lane = threadIdx.x & 63;
    int token = blockIdx.x * 4 + wave;
    const float* row = x + (size_t)token * DMODEL;
    float4 v[3];
    float s = 0.f, ss = 0.f;
#pragma unroll
    for (int j = 0; j < 3; ++j) {
        v[j] = *(const float4*)(row + lane*4 + j*256);
        s  += v[j].x + v[j].y + v[j].z + v[j].w;
        ss += v[j].x*v[j].x + v[j].y*v[j].y + v[j].z*v[j].z + v[j].w*v[j].w;
    }
#pragma unroll
    for (int o = 32; o > 0; o >>= 1) { s += __shfl_xor(s, o, 64); ss += __shfl_xor(ss, o, 64); }
    float mean = s * (1.f/768.f);
    float var  = ss * (1.f/768.f) - mean*mean;
    float rstd = rsqrtf(var + EPSV);
    unsigned short* brow = u16 + (size_t)token * DMODEL;
    float4 u[3];
#pragma unroll
    for (int j = 0; j < 3; ++j) {
        int cidx = lane*4 + j*256;
        float4 w4 = *(const float4*)(lnw + cidx);
        float4 b4 = *(const float4*)(lnb + cidx);
        u[j].x = (v[j].x - mean)*rstd*w4.x + b4.x;
        u[j].y = (v[j].y - mean)*rstd*w4.y + b4.y;
        u[j].z = (v[j].z - mean)*rstd*w4.z + b4.z;
        u[j].w = (v[j].w - mean)*rstd*w4.w + b4.w;
        ushort4 p; p.x = f2bf(u[j].x); p.y = f2bf(u[j].y); p.z = f2bf(u[j].z); p.w = f2bf(u[j].w);
        *(ushort4*)(brow + cidx) = p;
    }
    for (int hh = 0; hh < NHEADS; ++hh) {
        const float* wrow = Win + (size_t)(3104 + hh) * DMODEL;
        float p = 0.f;
#pragma unroll
        for (int j = 0; j < 3; ++j) {
            float4 wv = *(const float4*)(wrow + lane*4 + j*256);
            p += dot4(u[j], wv);
        }
#pragma unroll
        for (int o = 32; o > 0; o >>= 1) p += __shfl_xor(p, o, 64);
        if (lane == 0) {
            float raw = p + dt_bias[hh];
            float dt = (raw > 20.f) ? raw : log1pf(__expf(raw));
            float A = -__expf(A_log[hh]);
            dtv[(size_t)token*NHEADS + hh] = dt;
            dAv[(size_t)token*NHEADS + hh] = __expf(dt * A);
        }
    }
}

// ---------------------------------------------------------------------------
// GEMM1: C = u16 @ win16^T.  Block 256x128, BK=32, wave tile 128x64.
// Split store: cols<1536 -> z16 (bf16), 1536..3103 -> xbcr f32.
// Wide wave-tile raises FLOP per LDS byte (LDS-read BW was the binding pipe).
// ---------------------------------------------------------------------------
__global__ __launch_bounds__(256, 2) void gemm1_kernel(
    const unsigned short* __restrict__ A, const unsigned short* __restrict__ Bt,
    unsigned short* __restrict__ z16, float* __restrict__ xbcr)
{
    constexpr int K = DMODEL;
    __shared__ unsigned short As[256*32];   // 16 KB
    __shared__ unsigned short Bs[128*32];   //  8 KB
    const int tid  = threadIdx.x;
    const int lane = tid & 63;
    const int wave = tid >> 6;
    const int m0 = blockIdx.y * 256;
    const int n0 = blockIdx.x * 128;
    const int wm = (wave & 1) * 128;
    const int wn = (wave >> 1) * 64;

    floatx4 acc[8][4];
#pragma unroll
    for (int i = 0; i < 8; ++i)
#pragma unroll
        for (int j = 0; j < 4; ++j) acc[i][j] = floatx4{0.f, 0.f, 0.f, 0.f};

    const int srow = lane >> 2;           // 0..15
    const int scol = (lane & 3) * 8;      // k-element offset

    for (int k0 = 0; k0 < K; k0 += 32) {
        __syncthreads();
#pragma unroll
        for (int r = 0; r < 4; ++r) {       // A: wave stages rows [wave*64, wave*64+64)
            int trow = wave*64 + r*16 + srow;
            async_cp16(A + (size_t)(m0 + trow) * K + k0 + scol, As + trow*32 + scol);
        }
#pragma unroll
        for (int r = 0; r < 2; ++r) {       // B: wave stages rows [wave*32, wave*32+32)
            int trow = wave*32 + r*16 + srow;
            async_cp16(Bt + (size_t)(n0 + trow) * K + k0 + scol, Bs + trow*32 + scol);
        }
        __syncthreads();
        const int fr = lane & 15;
        const int fq = (lane >> 4) * 8;
        bf16x8 b[4];
#pragma unroll
        for (int j = 0; j < 4; ++j) b[j] = *(const bf16x8*)(Bs + (wn + j*16 + fr)*32 + fq);
#pragma unroll
        for (int i = 0; i < 8; ++i) {
            bf16x8 a = *(const bf16x8*)(As + (wm + i*16 + fr)*32 + fq);
#pragma unroll
            for (int j = 0; j < 4; ++j)
                acc[i][j] = __builtin_amdgcn_mfma_f32_16x16x32_bf16(a, b[j], acc[i][j], 0, 0, 0);
        }
    }

    const int col = lane & 15;
    const int rq  = (lane >> 4) * 4;
    if (n0 < DINNER) {                      // whole tile -> z16 (12 tiles cover 0..1535)
#pragma unroll
        for (int i = 0; i < 8; ++i)
#pragma unroll
            for (int j = 0; j < 4; ++j)
#pragma unroll
                for (int r = 0; r < 4; ++r) {
                    int gm = m0 + wm + i*16 + rq + r;
                    int gn = n0 + wn + j*16 + col;
                    z16[(size_t)gm * DINNER + gn] = f2bf(acc[i][j][r]);
                }
    } else {                                // tile -> xbcr (guard cols >= 3104 pad)
#pragma unroll
        for (int i = 0; i < 8; ++i)
#pragma unroll
            for (int j = 0; j < 4; ++j)
#pragma unroll
                for (int r = 0; r < 4; ++r) {
                    int gm = m0 + wm + i*16 + rq + r;
                    int gn = n0 + wn + j*16 + col;
                    if (gn < NREAL)
                        xbcr[(size_t)gm * CONVDIM + (gn - DINNER)] = acc[i][j][r];
                }
    }
}

// ---------------------------------------------------------------------------
// GEMM2: out = g16 @ wout16^T + x.  128x128 tile (N=768 -> 6x64 grid).
// ---------------------------------------------------------------------------
__global__ __launch_bounds__(256, 2) void gemm2_kernel(
    const unsigned short* __restrict__ A, const unsigned short* __restrict__ Bt,
    float* __restrict__ Cf, const float* __restrict__ resid)
{
    constexpr int K = DINNER;
    __shared__ unsigned short As[128*32];
    __shared__ unsigned short Bs[128*32];
    const int tid  = threadIdx.x;
    const int lane = tid & 63;
    const int wave = tid >> 6;
    const int m0 = blockIdx.y * 128;
    const int n0 = blockIdx.x * 128;
    const int wm = (wave & 1) * 64;
    const int wn = (wave >> 1) * 64;

    floatx4 acc[4][4];
#pragma unroll
    for (int i = 0; i < 4; ++i)
#pragma unroll
        for (int j = 0; j < 4; ++j) acc[i][j] = floatx4{0.f, 0.f, 0.f, 0.f};

    const int srow = lane >> 2;
    const int scol = (lane & 3) * 8;

    for (int k0 = 0; k0 < K; k0 += 32) {
        __syncthreads();
#pragma unroll
        for (int r = 0; r < 2; ++r) {
            int trow = r*64 + wave*16;
            async_cp16(A  + (size_t)(m0 + trow + srow) * K + k0 + scol, As + (size_t)trow * 32);
            async_cp16(Bt + (size_t)(n0 + trow + srow) * K + k0 + scol, Bs + (size_t)trow * 32);
        }
        __syncthreads();
        const int fr = lane & 15;
        const int fq = (lane >> 4) * 8;
        bf16x8 a[4], b[4];
#pragma unroll
        for (int i = 0; i < 4; ++i) a[i] = *(const bf16x8*)(As + (wm + i*16 + fr)*32 + fq);
#pragma unroll
        for (int j = 0; j < 4; ++j) b[j] = *(const bf16x8*)(Bs + (wn + j*16 + fr)*32 + fq);
#pragma unroll
        for (int i = 0; i < 4; ++i)
#pragma unroll
            for (int j = 0; j < 4; ++j)
                acc[i][j] = __builtin_amdgcn_mfma_f32_16x16x32_bf16(a[i], b[j], acc[i][j], 0, 0, 0);
    }

    const int col = lane & 15;
    const int rq  = (lane >> 4) * 4;
#pragma unroll
    for (int i = 0; i < 4; ++i)
#pragma unroll
        for (int j = 0; j < 4; ++j)
#pragma unroll
            for (int r = 0; r < 4; ++r) {
                int gm = m0 + wm + i*16 + rq + r;
                int gn = n0 + wn + j*16 + col;
                Cf[(size_t)gm * DMODEL + gn] = acc[i][j][r] + resid[(size_t)gm * DMODEL + gn];
            }
}

// ---------------------------------------------------------------------------
// Depthwise causal conv(4) + bias + silu.
// ---------------------------------------------------------------------------
__global__ __launch_bounds__(256) void conv_kernel(
    const float* __restrict__ xbcr, const float* __restrict__ cw,
    const float* __restrict__ cb, float* __restrict__ xbc)
{
    int c4 = blockIdx.x * 256 + threadIdx.x;
    if (c4 >= CONVDIM/4) return;
    int row = blockIdx.y;
    int l = row & (SEQ - 1);
    int c = c4 * 4;
    const float* base = xbcr + (size_t)row * CONVDIM + c;
    float4 w0 = *(const float4*)(cw + (c+0)*4);
    float4 w1 = *(const float4*)(cw + (c+1)*4);
    float4 w2 = *(const float4*)(cw + (c+2)*4);
    float4 w3 = *(const float4*)(cw + (c+3)*4);
    float4 acc = *(const float4*)(cb + c);
#pragma unroll
    for (int i = 0; i < 4; ++i) {
        int dl = i - 3;
        if (l + dl >= 0) {
            float4 in = *(const float4*)(base + (ptrdiff_t)dl * CONVDIM);
            acc.x += in.x * ((const float*)&w0)[i];
            acc.y += in.y * ((const float*)&w1)[i];
            acc.z += in.z * ((const float*)&w2)[i];
            acc.w += in.w * ((const float*)&w3)[i];
        }
    }
    acc.x = siluf(acc.x); acc.y = siluf(acc.y); acc.z = siluf(acc.z); acc.w = siluf(acc.w);
    *(float4*)(xbc + (size_t)row * CONVDIM + c) = acc;
}

// ---------------------------------------------------------------------------
// SSM scan, chunked (CHUNK=128, 32 chunks -> 1536 one-wave blocks).
// ---------------------------------------------------------------------------
__global__ __launch_bounds__(64) void scan_pass1(
    const float* __restrict__ xbc, const float* __restrict__ dAv, const float* __restrict__ dtv,
    float* __restrict__ hloc, float* __restrict__ pprod)
{
    int blk = blockIdx.x;                 // (b*24+h)*NCHUNK + c
    int c = blk & (NCHUNK-1), bh = blk / NCHUNK;
    int h = bh % NHEADS, b = bh / NHEADS;
    int lane = threadIdx.x;
    int row0 = b * SEQ + c * CHUNK;
    __shared__ float xs[SUB][64];
    __shared__ float bs[SUB][16];
    __shared__ float av[SUB], dv[SUB];
    float hst[16];
#pragma unroll
    for (int n = 0; n < 16; ++n) hst[n] = 0.f;
    float aprod = 1.f;
    for (int sc = 0; sc < CHUNK/SUB; ++sc) {
        int rb = row0 + sc * SUB;
        __syncthreads();
#pragma unroll
        for (int it = 0; it < 8; ++it) {
            int idx = it*64 + lane, s = idx >> 4, q = idx & 15;
            *(float4*)&xs[s][q*4] = *(const float4*)(xbc + (size_t)(rb+s)*CONVDIM + h*64 + q*4);
        }
#pragma unroll
        for (int it = 0; it < 2; ++it) {
            int idx = it*64 + lane, s = idx >> 2, q = idx & 3;
            *(float4*)&bs[s][q*4] = *(const float4*)(xbc + (size_t)(rb+s)*CONVDIM + DINNER + q*4);
        }
        if (lane < 32) av[lane] = dAv[(size_t)(rb+lane)*NHEADS + h];
        else           dv[lane-32] = dtv[(size_t)(rb+lane-32)*NHEADS + h];
        __syncthreads();
#pragma unroll 4
        for (int s = 0; s < SUB; ++s) {
            float a = av[s];
            float scale = dv[s] * xs[s][lane];
            float4 b0 = *(const float4*)&bs[s][0];
            float4 b1 = *(const float4*)&bs[s][4];
            float4 b2 = *(const float4*)&bs[s][8];
            float4 b3 = *(const float4*)&bs[s][12];
            const float* bp = (const float*)&b0;  // b0..b3 contiguous in regs
            float bb[16] = {b0.x,b0.y,b0.z,b0.w, b1.x,b1.y,b1.z,b1.w,
                            b2.x,b2.y,b2.z,b2.w, b3.x,b3.y,b3.z,b3.w};
            (void)bp;
#pragma unroll
            for (int n = 0; n < 16; ++n) hst[n] = a*hst[n] + scale*bb[n];
            aprod *= a;
        }
    }
    float* o = hloc + (size_t)blk * 1024 + lane * 16;
#pragma unroll
    for (int n = 0; n < 16; ++n) o[n] = hst[n];
    if (lane == 0) pprod[blk] = aprod;
}

__global__ __launch_bounds__(64) void scan_pass2(
    const float* __restrict__ hloc, const float* __restrict__ pprod, float* __restrict__ hstart)
{
    int bh = blockIdx.x, lane = threadIdx.x;
    float hst[16];
#pragma unroll
    for (int n = 0; n < 16; ++n) hst[n] = 0.f;
    for (int c = 0; c < NCHUNK; ++c) {
        int blk = bh * NCHUNK + c;
        float* o = hstart + (size_t)blk * 1024 + lane * 16;
#pragma unroll
        for (int n = 0; n < 16; ++n) o[n] = hst[n];
        float P = pprod[blk];
        const float* hl = hloc + (size_t)blk * 1024 + lane * 16;
#pragma unroll
        for (int n = 0; n < 16; ++n) hst[n] = P * hst[n] + hl[n];
    }
}

__global__ __launch_bounds__(64) void scan_pass3(
    const float* __restrict__ xbc, const float* __restrict__ dAv, const float* __restrict__ dtv,
    const float* __restrict__ hstart, const float* __restrict__ Dp, float* __restrict__ yv)
{
    int blk = blockIdx.x;
    int c = blk & (NCHUNK-1), bh = blk / NCHUNK;
    int h = bh % NHEADS, b = bh / NHEADS;
    int lane = threadIdx.x;
    int row0 = b * SEQ + c * CHUNK;
    __shared__ float xs[SUB][64];
    __shared__ float bcs[SUB][32];        // B then C
    __shared__ float av[SUB], dv[SUB];
    float hst[16];
    const float* hs = hstart + (size_t)blk * 1024 + lane * 16;
#pragma unroll
    for (int n = 0; n < 16; ++n) hst[n] = hs[n];
    float Dh = Dp[h];
    for (int sc = 0; sc < CHUNK/SUB; ++sc) {
        int rb = row0 + sc * SUB;
        __syncthreads();
#pragma unroll
        for (int it = 0; it < 8; ++it) {
            int idx = it*64 + lane, s = idx >> 4, q = idx & 15;
            *(float4*)&xs[s][q*4] = *(const float4*)(xbc + (size_t)(rb+s)*CONVDIM + h*64 + q*4);
        }
#pragma unroll
        for (int it = 0; it < 4; ++it) {
            int idx = it*64 + lane, s = idx >> 3, q = idx & 7;
            *(float4*)&bcs[s][q*4] = *(const float4*)(xbc + (size_t)(rb+s)*CONVDIM + DINNER + q*4);
        }
        if (lane < 32) av[lane] = dAv[(size_t)(rb+lane)*NHEADS + h];
        else           dv[lane-32] = dtv[(size_t)(rb+lane-32)*NHEADS + h];
        __syncthreads();
#pragma unroll 4
        for (int s = 0; s < SUB; ++s) {
            float a = av[s];
            float xv = xs[s][lane];
            float scale = dv[s] * xv;
            const float* bp = bcs[s];
            float y = Dh * xv;
#pragma unroll
            for (int n = 0; n < 16; ++n) hst[n] = a*hst[n] + scale*bp[n];
#pragma unroll
            for (int n = 0; n < 16; ++n) y += hst[n] * bp[16+n];
            yv[(size_t)(rb+s)*DINNER + h*64 + lane] = y;
        }
    }
}

// ---------------------------------------------------------------------------
// Gating + RMSNorm -> bf16
// ---------------------------------------------------------------------------
__global__ __launch_bounds__(256) void gate_kernel(
    const float* __restrict__ yv, const unsigned short* __restrict__ z16,
    const float* __restrict__ gw, unsigned short* __restrict__ g16)
{
    int wave = threadIdx.x >> 6, lane = threadIdx.x & 63;
    int token = blockIdx.x * 4 + wave;
    const float* yrow = yv + (size_t)token * DINNER;
    const unsigned short* zrow = z16 + (size_t)token * DINNER;
    float4 gv[6];
    float ss = 0.f;
#pragma unroll
    for (int j = 0; j < 6; ++j) {
        int cidx = lane*4 + j*256;
        float4 y4 = *(const float4*)(yrow + cidx);
        ushort4 z4 = *(const ushort4*)(zrow + cidx);
        gv[j].x = y4.x * siluf(bf2f(z4.x));
        gv[j].y = y4.y * siluf(bf2f(z4.y));
        gv[j].z = y4.z * siluf(bf2f(z4.z));
        gv[j].w = y4.w * siluf(bf2f(z4.w));
        ss += gv[j].x*gv[j].x + gv[j].y*gv[j].y + gv[j].z*gv[j].z + gv[j].w*gv[j].w;
    }
#pragma unroll
    for (int o = 32; o > 0; o >>= 1) ss += __shfl_xor(ss, o, 64);
    float scale = rsqrtf(ss * (1.f/1536.f) + EPSV);
    unsigned short* orow = g16 + (size_t)token * DINNER;
#pragma unroll
    for (int j = 0; j < 6; ++j) {
        int cidx = lane*4 + j*256;
        float4 w4 = *(const float4*)(gw + cidx);
        ushort4 p;
        p.x = f2bf(gv[j].x * scale * w4.x);
        p.y = f2bf(gv[j].y * scale * w4.y);
        p.z = f2bf(gv[j].z * scale * w4.z);
        p.w = f2bf(gv[j].w * scale * w4.w);
        *(ushort4*)(orow + cidx) = p;
    }
}

// ---------------------------------------------------------------------------
extern "C" void kernel_launch(void* const* d_in, const int* in_sizes, int n_in,
                              void* d_out, int out_size, void* d_ws, size_t ws_size,
                              hipStream_t stream)
{
    const float* x        = (const float*)d_in[0];
    const float* ln_w     = (const float*)d_in[1];
    const float* ln_b     = (const float*)d_in[2];
    const float* W_in     = (const float*)d_in[3];
    const float* conv_w   = (const float*)d_in[4];
    const float* conv_b   = (const float*)d_in[5];
    const float* dt_bias  = (const float*)d_in[6];
    const float* A_log    = (const float*)d_in[7];
    const float* Dp       = (const float*)d_in[8];
    const float* gate_w   = (const float*)d_in[9];
    const float* W_out    = (const float*)d_in[10];
    float* out = (float*)d_out;

    char* ws = (char*)d_ws;
    size_t off = 0;
    auto alloc = [&](size_t bytes) -> void* {
        void* p = ws + off;
        off += (bytes + 255) & ~(size_t)255;
        return p;
    };
    // region A (dead after gemm1): u16; hloc+hstart alias it exactly (12.58 MB)
    unsigned short* u16    = (unsigned short*)alloc((size_t)NTOK*DMODEL*2);            // 12.58 MB
    unsigned short* win16  = (unsigned short*)alloc((size_t)NPAD*DMODEL*2);            //  4.92 MB
    float*          dtv    = (float*)alloc((size_t)NTOK*NHEADS*4);                     //  0.79 MB
    float*          dAv    = (float*)alloc((size_t)NTOK*NHEADS*4);                     //  0.79 MB
    float*          xbcr   = (float*)alloc((size_t)NTOK*CONVDIM*4);                    // 51.38 MB (yv aliases)
    unsigned short* wout16 = (unsigned short*)alloc((size_t)DMODEL*DINNER*2);          //  2.36 MB
    unsigned short* z16    = (unsigned short*)alloc((size_t)NTOK*DINNER*2);            // 25.17 MB
    float*          xbc    = (float*)alloc((size_t)NTOK*CONVDIM*4);                    // 51.38 MB (g16 aliases)
    float*          pprod  = (float*)alloc((size_t)BATCH*NHEADS*NCHUNK*4);
    // aliases (lifetime-checked):
    float*          hloc   = (float*)ws;                                  // 6.29 MB, over u16 (dead after gemm1)
    float*          hstart = hloc + (size_t)BATCH*NHEADS*NCHUNK*1024;     // 6.29 MB, still within u16
    float*          yv     = xbcr;                                        // xbcr dead after conv
    unsigned short* g16    = (unsigned short*)xbc;                        // xbc dead after pass3
    // high-water ~149.4 MB

    cvt_kernel<<<(NPAD*DMODEL + DMODEL*DINNER)/256, 256, 0, stream>>>(W_in, W_out, win16, wout16);
    ln_dt_kernel<<<NTOK/4, 256, 0, stream>>>(x, ln_w, ln_b, W_in, dt_bias, A_log, u16, dtv, dAv);
    gemm1_kernel<<<dim3(NPAD/128, NTOK/256), 256, 0, stream>>>(u16, win16, z16, xbcr);
    conv_kernel<<<dim3(2, NTOK), 256, 0, stream>>>(xbcr, conv_w, conv_b, xbc);
    scan_pass1<<<BATCH*NHEADS*NCHUNK, 64, 0, stream>>>(xbc, dAv, dtv, hloc, pprod);
    scan_pass2<<<BATCH*NHEADS, 64, 0, stream>>>(hloc, pprod, hstart);
    scan_pass3<<<BATCH*NHEADS*NCHUNK, 64, 0, stream>>>(xbc, dAv, dtv, hstart, Dp, yv);
    gate_kernel<<<NTOK/4, 256, 0, stream>>>(yv, z16, gate_w, g16);
    gemm2_kernel<<<dim3(DMODEL/128, NTOK/128), 256, 0, stream>>>(g16, wout16, out, x);
}

// Round 4
// 394.671 us; speedup vs baseline: 1.1132x; 1.0123x over previous
//
#include <hip/hip_runtime.h>
#include <hip/hip_bf16.h>
#include <stdint.h>

#define SEQ      4096
#define BATCH    2
#define NTOK     (BATCH*SEQ)        // 8192
#define DMODEL   768
#define DINNER   1536
#define NHEADS   24
#define HEADDIM  64
#define DSTATE   16
#define CONVDIM  1568               // 1536 x + 16 B + 16 C
#define NPAD     3200               // GEMM1 padded N (25*128); cols >=3104 dropped
#define NREAL    3104
#define EPSV     1e-5f
#define CHUNK    64
#define NCHUNK   (SEQ/CHUNK)        // 64
#define SUB      32

typedef __bf16 bf16x8 __attribute__((ext_vector_type(8)));
typedef float  floatx4 __attribute__((ext_vector_type(4)));

__device__ __forceinline__ unsigned short f2bf(float f) {
    union { float f; uint32_t u; } v; v.f = f;
    uint32_t u = v.u;
    uint32_t r = (u + 0x7fffu + ((u >> 16) & 1u)) >> 16;
    return (unsigned short)r;
}

__device__ __forceinline__ float bf2f(unsigned short h) {
    union { uint32_t u; float f; } v; v.u = (uint32_t)h << 16;
    return v.f;
}

__device__ __forceinline__ float siluf(float x) { return x / (1.f + __expf(-x)); }

__device__ __forceinline__ float dot4(float4 a, float4 b) {
    return a.x*b.x + a.y*b.y + a.z*b.z + a.w*b.w;
}

__device__ __forceinline__ void async_cp16(const void* g, void* l) {
    __builtin_amdgcn_global_load_lds(
        (const __attribute__((address_space(1))) void*)g,
        (__attribute__((address_space(3))) void*)l,
        16, 0, 0);
}

// ---------------------------------------------------------------------------
// Weight conversion.
// ---------------------------------------------------------------------------
__global__ __launch_bounds__(256) void cvt_kernel(
    const float* __restrict__ Win, const float* __restrict__ Wout,
    unsigned short* __restrict__ win16, unsigned short* __restrict__ wout16)
{
    int idx = blockIdx.x * 256 + threadIdx.x;
    const int n1 = NPAD * DMODEL;
    if (idx < n1) {
        int r = idx / DMODEL;
        win16[idx] = (r < 3128) ? f2bf(Win[idx]) : (unsigned short)0;
    } else {
        int i2 = idx - n1;
        if (i2 < DMODEL * DINNER) wout16[i2] = f2bf(Wout[i2]);
    }
}

// ---------------------------------------------------------------------------
// Fused LayerNorm + dt path.  One wave per token.
// ---------------------------------------------------------------------------
__global__ __launch_bounds__(256) void ln_dt_kernel(
    const float* __restrict__ x, const float* __restrict__ lnw, const float* __restrict__ lnb,
    const float* __restrict__ Win, const float* __restrict__ dt_bias, const float* __restrict__ A_log,
    unsigned short* __restrict__ u16, float* __restrict__ dtv, float* __restrict__ dAv)
{
    int wave = threadIdx.x >> 6, lane = threadIdx.x & 63;
    int token = blockIdx.x * 4 + wave;
    const float* row = x + (size_t)token * DMODEL;
    float4 v[3];
    float s = 0.f, ss = 0.f;
#pragma unroll
    for (int j = 0; j < 3; ++j) {
        v[j] = *(const float4*)(row + lane*4 + j*256);
        s  += v[j].x + v[j].y + v[j].z + v[j].w;
        ss += v[j].x*v[j].x + v[j].y*v[j].y + v[j].z*v[j].z + v[j].w*v[j].w;
    }
#pragma unroll
    for (int o = 32; o > 0; o >>= 1) { s += __shfl_xor(s, o, 64); ss += __shfl_xor(ss, o, 64); }
    float mean = s * (1.f/768.f);
    float var  = ss * (1.f/768.f) - mean*mean;
    float rstd = rsqrtf(var + EPSV);
    unsigned short* brow = u16 + (size_t)token * DMODEL;
    float4 u[3];
#pragma unroll
    for (int j = 0; j < 3; ++j) {
        int cidx = lane*4 + j*256;
        float4 w4 = *(const float4*)(lnw + cidx);
        float4 b4 = *(const float4*)(lnb + cidx);
        u[j].x = (v[j].x - mean)*rstd*w4.x + b4.x;
        u[j].y = (v[j].y - mean)*rstd*w4.y + b4.y;
        u[j].z = (v[j].z - mean)*rstd*w4.z + b4.z;
        u[j].w = (v[j].w - mean)*rstd*w4.w + b4.w;
        ushort4 p; p.x = f2bf(u[j].x); p.y = f2bf(u[j].y); p.z = f2bf(u[j].z); p.w = f2bf(u[j].w);
        *(ushort4*)(brow + cidx) = p;
    }
    for (int hh = 0; hh < NHEADS; ++hh) {
        const float* wrow = Win + (size_t)(3104 + hh) * DMODEL;
        float p = 0.f;
#pragma unroll
        for (int j = 0; j < 3; ++j) {
            float4 wv = *(const float4*)(wrow + lane*4 + j*256);
            p += dot4(u[j], wv);
        }
#pragma unroll
        for (int o = 32; o > 0; o >>= 1) p += __shfl_xor(p, o, 64);
        if (lane == 0) {
            float raw = p + dt_bias[hh];
            float dt = (raw > 20.f) ? raw : log1pf(__expf(raw));
            float A = -__expf(A_log[hh]);
            dtv[(size_t)token*NHEADS + hh] = dt;
            dAv[(size_t)token*NHEADS + hh] = __expf(dt * A);
        }
    }
}

// ---------------------------------------------------------------------------
// GEMM1: C = u16 @ win16^T.  Block 256x128, BK=32, wave tile 128x64.
// XOR-swizzled LDS: LDS[r][t] = G[r][t ^ (r&3)] (k-quads of 8 elem).
// ---------------------------------------------------------------------------
__global__ __launch_bounds__(256, 2) void gemm1_kernel(
    const unsigned short* __restrict__ A, const unsigned short* __restrict__ Bt,
    unsigned short* __restrict__ z16, float* __restrict__ xbcr)
{
    constexpr int K = DMODEL;
    __shared__ unsigned short As[256*32];   // 16 KB
    __shared__ unsigned short Bs[128*32];   //  8 KB
    const int tid  = threadIdx.x;
    const int lane = tid & 63;
    const int wave = tid >> 6;
    const int m0 = blockIdx.y * 256;
    const int n0 = blockIdx.x * 128;
    const int wm = (wave & 1) * 128;
    const int wn = (wave >> 1) * 64;

    floatx4 acc[8][4];
#pragma unroll
    for (int i = 0; i < 8; ++i)
#pragma unroll
        for (int j = 0; j < 4; ++j) acc[i][j] = floatx4{0.f, 0.f, 0.f, 0.f};

    const int srow = lane >> 2;                       // 0..15
    const int sq   = ((lane & 3) ^ (srow & 3)) * 8;   // swizzled source k-quad
    const int dcol = (lane & 3) * 8;                  // fixed LDS dst quad

    for (int k0 = 0; k0 < K; k0 += 32) {
        __syncthreads();
#pragma unroll
        for (int r = 0; r < 4; ++r) {
            int trow = wave*64 + r*16 + srow;
            async_cp16(A + (size_t)(m0 + trow) * K + k0 + sq, As + trow*32 + dcol);
        }
#pragma unroll
        for (int r = 0; r < 2; ++r) {
            int trow = wave*32 + r*16 + srow;
            async_cp16(Bt + (size_t)(n0 + trow) * K + k0 + sq, Bs + trow*32 + dcol);
        }
        __syncthreads();
        const int fr = lane & 15;
        const int q8 = lane >> 4;
        const int fq = (q8 ^ (fr & 3)) * 8;           // de-swizzled read quad
        bf16x8 b[4];
#pragma unroll
        for (int j = 0; j < 4; ++j) b[j] = *(const bf16x8*)(Bs + (wn + j*16 + fr)*32 + fq);
#pragma unroll
        for (int i = 0; i < 8; ++i) {
            bf16x8 a = *(const bf16x8*)(As + (wm + i*16 + fr)*32 + fq);
#pragma unroll
            for (int j = 0; j < 4; ++j)
                acc[i][j] = __builtin_amdgcn_mfma_f32_16x16x32_bf16(a, b[j], acc[i][j], 0, 0, 0);
        }
    }

    const int col = lane & 15;
    const int rq  = (lane >> 4) * 4;
    if (n0 < DINNER) {
#pragma unroll
        for (int i = 0; i < 8; ++i)
#pragma unroll
            for (int j = 0; j < 4; ++j)
#pragma unroll
                for (int r = 0; r < 4; ++r) {
                    int gm = m0 + wm + i*16 + rq + r;
                    int gn = n0 + wn + j*16 + col;
                    z16[(size_t)gm * DINNER + gn] = f2bf(acc[i][j][r]);
                }
    } else {
#pragma unroll
        for (int i = 0; i < 8; ++i)
#pragma unroll
            for (int j = 0; j < 4; ++j)
#pragma unroll
                for (int r = 0; r < 4; ++r) {
                    int gm = m0 + wm + i*16 + rq + r;
                    int gn = n0 + wn + j*16 + col;
                    if (gn < NREAL)
                        xbcr[(size_t)gm * CONVDIM + (gn - DINNER)] = acc[i][j][r];
                }
    }
}

// ---------------------------------------------------------------------------
// GEMM2: out = g16 @ wout16^T + x.  128x128 tile, XOR-swizzled LDS.
// ---------------------------------------------------------------------------
__global__ __launch_bounds__(256, 2) void gemm2_kernel(
    const unsigned short* __restrict__ A, const unsigned short* __restrict__ Bt,
    float* __restrict__ Cf, const float* __restrict__ resid)
{
    constexpr int K = DINNER;
    __shared__ unsigned short As[128*32];
    __shared__ unsigned short Bs[128*32];
    const int tid  = threadIdx.x;
    const int lane = tid & 63;
    const int wave = tid >> 6;
    const int m0 = blockIdx.y * 128;
    const int n0 = blockIdx.x * 128;
    const int wm = (wave & 1) * 64;
    const int wn = (wave >> 1) * 64;

    floatx4 acc[4][4];
#pragma unroll
    for (int i = 0; i < 4; ++i)
#pragma unroll
        for (int j = 0; j < 4; ++j) acc[i][j] = floatx4{0.f, 0.f, 0.f, 0.f};

    const int srow = lane >> 2;
    const int sq   = ((lane & 3) ^ (srow & 3)) * 8;
    const int dcol = (lane & 3) * 8;

    for (int k0 = 0; k0 < K; k0 += 32) {
        __syncthreads();
#pragma unroll
        for (int r = 0; r < 2; ++r) {
            int trow = r*64 + wave*16 + srow;
            async_cp16(A  + (size_t)(m0 + trow) * K + k0 + sq, As + trow*32 + dcol);
            async_cp16(Bt + (size_t)(n0 + trow) * K + k0 + sq, Bs + trow*32 + dcol);
        }
        __syncthreads();
        const int fr = lane & 15;
        const int q8 = lane >> 4;
        const int fq = (q8 ^ (fr & 3)) * 8;
        bf16x8 a[4], b[4];
#pragma unroll
        for (int i = 0; i < 4; ++i) a[i] = *(const bf16x8*)(As + (wm + i*16 + fr)*32 + fq);
#pragma unroll
        for (int j = 0; j < 4; ++j) b[j] = *(const bf16x8*)(Bs + (wn + j*16 + fr)*32 + fq);
#pragma unroll
        for (int i = 0; i < 4; ++i)
#pragma unroll
            for (int j = 0; j < 4; ++j)
                acc[i][j] = __builtin_amdgcn_mfma_f32_16x16x32_bf16(a[i], b[j], acc[i][j], 0, 0, 0);
    }

    const int col = lane & 15;
    const int rq  = (lane >> 4) * 4;
#pragma unroll
    for (int i = 0; i < 4; ++i)
#pragma unroll
        for (int j = 0; j < 4; ++j)
#pragma unroll
            for (int r = 0; r < 4; ++r) {
                int gm = m0 + wm + i*16 + rq + r;
                int gn = n0 + wn + j*16 + col;
                Cf[(size_t)gm * DMODEL + gn] = acc[i][j][r] + resid[(size_t)gm * DMODEL + gn];
            }
}

// ---------------------------------------------------------------------------
// SSM scan with fused depthwise conv(4)+bias+silu, reading raw xbcr.
// Pass 1: per (b,h,chunk) local end-state + decay product.  CHUNK=64, SUB=32.
// ---------------------------------------------------------------------------
__global__ __launch_bounds__(64) void scan_pass1(
    const float* __restrict__ xbcr, const float* __restrict__ dAv, const float* __restrict__ dtv,
    const float* __restrict__ cw, const float* __restrict__ cb,
    float* __restrict__ hloc, float* __restrict__ pprod)
{
    int blk = blockIdx.x;                 // bh*NCHUNK + c
    int c = blk & (NCHUNK-1), bh = blk >> 6;
    int h = bh % NHEADS, b = bh / NHEADS;
    int lane = threadIdx.x;
    int row0 = b * SEQ + c * CHUNK;
    int l0 = c * CHUNK;
    __shared__ float xraw[35][64];
    __shared__ float braw[35][16];
    __shared__ float bsc[SUB][16];
    __shared__ float av[SUB], dv[SUB];

    int cx = h*64 + lane;
    float cwx0 = cw[cx*4+0], cwx1 = cw[cx*4+1], cwx2 = cw[cx*4+2], cwx3 = cw[cx*4+3];
    float cbx = cb[cx];
    int nB = lane & 15;
    float cwb0 = cw[(DINNER+nB)*4+0], cwb1 = cw[(DINNER+nB)*4+1];
    float cwb2 = cw[(DINNER+nB)*4+2], cwb3 = cw[(DINNER+nB)*4+3];
    float cbb = cb[DINNER+nB];

    float hst[16];
#pragma unroll
    for (int n = 0; n < 16; ++n) hst[n] = 0.f;
    float aprod = 1.f;

    for (int sc = 0; sc < CHUNK/SUB; ++sc) {
        int rb = row0 + sc * SUB;
        int lb = l0 + sc * SUB;
        __syncthreads();
#pragma unroll
        for (int it = 0; it < 9; ++it) {        // x rows rb-3 .. rb+31 (35x16 float4)
            int idx = it*64 + lane;
            if (idx < 560) {
                int s = idx >> 4, q = idx & 15;
                float4 val = {0.f,0.f,0.f,0.f};
                if (lb - 3 + s >= 0)
                    val = *(const float4*)(xbcr + (size_t)(rb-3+s)*CONVDIM + h*64 + q*4);
                *(float4*)&xraw[s][q*4] = val;
            }
        }
#pragma unroll
        for (int it = 0; it < 3; ++it) {        // B rows (35x4 float4)
            int idx = it*64 + lane;
            if (idx < 140) {
                int s = idx >> 2, q = idx & 3;
                float4 val = {0.f,0.f,0.f,0.f};
                if (lb - 3 + s >= 0)
                    val = *(const float4*)(xbcr + (size_t)(rb-3+s)*CONVDIM + DINNER + q*4);
                *(float4*)&braw[s][q*4] = val;
            }
        }
        if (lane < 32) av[lane] = dAv[(size_t)(rb+lane)*NHEADS + h];
        else           dv[lane-32] = dtv[(size_t)(rb+lane-32)*NHEADS + h];
        __syncthreads();
#pragma unroll
        for (int it = 0; it < 8; ++it) {        // conv B -> bsc
            int s = it*4 + (lane >> 4);
            float v = cbb + braw[s][nB]*cwb0 + braw[s+1][nB]*cwb1
                          + braw[s+2][nB]*cwb2 + braw[s+3][nB]*cwb3;
            bsc[s][nB] = siluf(v);
        }
        __syncthreads();
#pragma unroll 4
        for (int s = 0; s < SUB; ++s) {
            float a = av[s];
            float xc = siluf(cbx + xraw[s][lane]*cwx0 + xraw[s+1][lane]*cwx1
                                 + xraw[s+2][lane]*cwx2 + xraw[s+3][lane]*cwx3);
            float scale = dv[s] * xc;
            const float* bp = bsc[s];
#pragma unroll
            for (int n = 0; n < 16; ++n) hst[n] = a*hst[n] + scale*bp[n];
            aprod *= a;
        }
    }
    float* o = hloc + (size_t)blk * 1024 + lane * 16;
#pragma unroll
    for (int n = 0; n < 16; ++n) o[n] = hst[n];
    if (lane == 0) pprod[blk] = aprod;
}

__global__ __launch_bounds__(64) void scan_pass2(
    const float* __restrict__ hloc, const float* __restrict__ pprod, float* __restrict__ hstart)
{
    int bh = blockIdx.x, lane = threadIdx.x;
    float hst[16];
#pragma unroll
    for (int n = 0; n < 16; ++n) hst[n] = 0.f;
    for (int c = 0; c < NCHUNK; ++c) {
        int blk = bh * NCHUNK + c;
        float* o = hstart + (size_t)blk * 1024 + lane * 16;
#pragma unroll
        for (int n = 0; n < 16; ++n) o[n] = hst[n];
        float P = pprod[blk];
        const float* hl = hloc + (size_t)blk * 1024 + lane * 16;
#pragma unroll
        for (int n = 0; n < 16; ++n) hst[n] = P * hst[n] + hl[n];
    }
}

// Pass 3: replay chunk from h_start with fused conv; emit y = C.h + D*x  (bf16).
__global__ __launch_bounds__(64) void scan_pass3(
    const float* __restrict__ xbcr, const float* __restrict__ dAv, const float* __restrict__ dtv,
    const float* __restrict__ cw, const float* __restrict__ cb,
    const float* __restrict__ hstart, const float* __restrict__ Dp,
    unsigned short* __restrict__ yv16)
{
    int blk = blockIdx.x;
    int c = blk & (NCHUNK-1), bh = blk >> 6;
    int h = bh % NHEADS, b = bh / NHEADS;
    int lane = threadIdx.x;
    int row0 = b * SEQ + c * CHUNK;
    int l0 = c * CHUNK;
    __shared__ float xraw[35][64];
    __shared__ float bcraw[35][32];
    __shared__ float bcsc[SUB][32];       // conv'd: 0..15 = B, 16..31 = C
    __shared__ float av[SUB], dv[SUB];

    int cx = h*64 + lane;
    float cwx0 = cw[cx*4+0], cwx1 = cw[cx*4+1], cwx2 = cw[cx*4+2], cwx3 = cw[cx*4+3];
    float cbx = cb[cx];
    int nBC = lane & 31;
    float cwc0 = cw[(DINNER+nBC)*4+0], cwc1 = cw[(DINNER+nBC)*4+1];
    float cwc2 = cw[(DINNER+nBC)*4+2], cwc3 = cw[(DINNER+nBC)*4+3];
    float cbc = cb[DINNER+nBC];

    float hst[16];
    const float* hs = hstart + (size_t)blk * 1024 + lane * 16;
#pragma unroll
    for (int n = 0; n < 16; ++n) hst[n] = hs[n];
    float Dh = Dp[h];

    for (int sc = 0; sc < CHUNK/SUB; ++sc) {
        int rb = row0 + sc * SUB;
        int lb = l0 + sc * SUB;
        __syncthreads();
#pragma unroll
        for (int it = 0; it < 9; ++it) {
            int idx = it*64 + lane;
            if (idx < 560) {
                int s = idx >> 4, q = idx & 15;
                float4 val = {0.f,0.f,0.f,0.f};
                if (lb - 3 + s >= 0)
                    val = *(const float4*)(xbcr + (size_t)(rb-3+s)*CONVDIM + h*64 + q*4);
                *(float4*)&xraw[s][q*4] = val;
            }
        }
#pragma unroll
        for (int it = 0; it < 5; ++it) {        // B+C rows (35x8 float4)
            int idx = it*64 + lane;
            if (idx < 280) {
                int s = idx >> 3, q = idx & 7;
                float4 val = {0.f,0.f,0.f,0.f};
                if (lb - 3 + s >= 0)
                    val = *(const float4*)(xbcr + (size_t)(rb-3+s)*CONVDIM + DINNER + q*4);
                *(float4*)&bcraw[s][q*4] = val;
            }
        }
        if (lane < 32) av[lane] = dAv[(size_t)(rb+lane)*NHEADS + h];
        else           dv[lane-32] = dtv[(size_t)(rb+lane-32)*NHEADS + h];
        __syncthreads();
#pragma unroll
        for (int it = 0; it < 16; ++it) {       // conv B,C -> bcsc
            int s = it*2 + (lane >> 5);
            float v = cbc + bcraw[s][nBC]*cwc0 + bcraw[s+1][nBC]*cwc1
                          + bcraw[s+2][nBC]*cwc2 + bcraw[s+3][nBC]*cwc3;
            bcsc[s][nBC] = siluf(v);
        }
        __syncthreads();
#pragma unroll 4
        for (int s = 0; s < SUB; ++s) {
            float a = av[s];
            float xc = siluf(cbx + xraw[s][lane]*cwx0 + xraw[s+1][lane]*cwx1
                                 + xraw[s+2][lane]*cwx2 + xraw[s+3][lane]*cwx3);
            float scale = dv[s] * xc;
            const float* bp = bcsc[s];
            float y = Dh * xc;
#pragma unroll
            for (int n = 0; n < 16; ++n) hst[n] = a*hst[n] + scale*bp[n];
#pragma unroll
            for (int n = 0; n < 16; ++n) y += hst[n] * bp[16+n];
            yv16[(size_t)(rb+s)*DINNER + h*64 + lane] = f2bf(y);
        }
    }
}

// ---------------------------------------------------------------------------
// Gating + RMSNorm -> bf16
// ---------------------------------------------------------------------------
__global__ __launch_bounds__(256) void gate_kernel(
    const unsigned short* __restrict__ yv16, const unsigned short* __restrict__ z16,
    const float* __restrict__ gw, unsigned short* __restrict__ g16)
{
    int wave = threadIdx.x >> 6, lane = threadIdx.x & 63;
    int token = blockIdx.x * 4 + wave;
    const unsigned short* yrow = yv16 + (size_t)token * DINNER;
    const unsigned short* zrow = z16 + (size_t)token * DINNER;
    float4 gv[6];
    float ss = 0.f;
#pragma unroll
    for (int j = 0; j < 6; ++j) {
        int cidx = lane*4 + j*256;
        ushort4 y4 = *(const ushort4*)(yrow + cidx);
        ushort4 z4 = *(const ushort4*)(zrow + cidx);
        gv[j].x = bf2f(y4.x) * siluf(bf2f(z4.x));
        gv[j].y = bf2f(y4.y) * siluf(bf2f(z4.y));
        gv[j].z = bf2f(y4.z) * siluf(bf2f(z4.z));
        gv[j].w = bf2f(y4.w) * siluf(bf2f(z4.w));
        ss += gv[j].x*gv[j].x + gv[j].y*gv[j].y + gv[j].z*gv[j].z + gv[j].w*gv[j].w;
    }
#pragma unroll
    for (int o = 32; o > 0; o >>= 1) ss += __shfl_xor(ss, o, 64);
    float scale = rsqrtf(ss * (1.f/1536.f) + EPSV);
    unsigned short* orow = g16 + (size_t)token * DINNER;
#pragma unroll
    for (int j = 0; j < 6; ++j) {
        int cidx = lane*4 + j*256;
        float4 w4 = *(const float4*)(gw + cidx);
        ushort4 p;
        p.x = f2bf(gv[j].x * scale * w4.x);
        p.y = f2bf(gv[j].y * scale * w4.y);
        p.z = f2bf(gv[j].z * scale * w4.z);
        p.w = f2bf(gv[j].w * scale * w4.w);
        *(ushort4*)(orow + cidx) = p;
    }
}

// ---------------------------------------------------------------------------
extern "C" void kernel_launch(void* const* d_in, const int* in_sizes, int n_in,
                              void* d_out, int out_size, void* d_ws, size_t ws_size,
                              hipStream_t stream)
{
    const float* x        = (const float*)d_in[0];
    const float* ln_w     = (const float*)d_in[1];
    const float* ln_b     = (const float*)d_in[2];
    const float* W_in     = (const float*)d_in[3];
    const float* conv_w   = (const float*)d_in[4];
    const float* conv_b   = (const float*)d_in[5];
    const float* dt_bias  = (const float*)d_in[6];
    const float* A_log    = (const float*)d_in[7];
    const float* Dp       = (const float*)d_in[8];
    const float* gate_w   = (const float*)d_in[9];
    const float* W_out    = (const float*)d_in[10];
    float* out = (float*)d_out;

    char* ws = (char*)d_ws;
    size_t off = 0;
    auto alloc = [&](size_t bytes) -> void* {
        void* p = ws + off;
        off += (bytes + 255) & ~(size_t)255;
        return p;
    };
    // u16 dead after gemm1; hloc aliases it (12.58 MB == 12.58 MB exactly)
    unsigned short* u16    = (unsigned short*)alloc((size_t)NTOK*DMODEL*2);            // 12.58 MB
    unsigned short* win16  = (unsigned short*)alloc((size_t)NPAD*DMODEL*2);            //  4.92 MB
    float*          dtv    = (float*)alloc((size_t)NTOK*NHEADS*4);                     //  0.79 MB
    float*          dAv    = (float*)alloc((size_t)NTOK*NHEADS*4);                     //  0.79 MB
    float*          xbcr   = (float*)alloc((size_t)NTOK*CONVDIM*4);                    // 51.38 MB (live thru pass3)
    unsigned short* wout16 = (unsigned short*)alloc((size_t)DMODEL*DINNER*2);          //  2.36 MB
    unsigned short* z16    = (unsigned short*)alloc((size_t)NTOK*DINNER*2);            // 25.17 MB
    unsigned short* yv16   = (unsigned short*)alloc((size_t)NTOK*DINNER*2);            // 25.17 MB
    unsigned short* g16    = (unsigned short*)alloc((size_t)NTOK*DINNER*2);            // 25.17 MB
    float*          pprod  = (float*)alloc((size_t)BATCH*NHEADS*NCHUNK*4);             //  0.01 MB
    // aliases (lifetime-checked):
    float* hloc   = (float*)u16;    // 12.58 MB; u16 dead after gemm1, pass1 writes after
    float* hstart = (float*)g16;    // 12.58 MB; g16 written only at gate (after pass3 reads hstart)
    // high-water ~148.4 MB

    cvt_kernel<<<(NPAD*DMODEL + DMODEL*DINNER)/256, 256, 0, stream>>>(W_in, W_out, win16, wout16);
    ln_dt_kernel<<<NTOK/4, 256, 0, stream>>>(x, ln_w, ln_b, W_in, dt_bias, A_log, u16, dtv, dAv);
    gemm1_kernel<<<dim3(NPAD/128, NTOK/256), 256, 0, stream>>>(u16, win16, z16, xbcr);
    scan_pass1<<<BATCH*NHEADS*NCHUNK, 64, 0, stream>>>(xbcr, dAv, dtv, conv_w, conv_b, hloc, pprod);
    scan_pass2<<<BATCH*NHEADS, 64, 0, stream>>>(hloc, pprod, hstart);
    scan_pass3<<<BATCH*NHEADS*NCHUNK, 64, 0, stream>>>(xbcr, dAv, dtv, conv_w, conv_b, hstart, Dp, yv16);
    gate_kernel<<<NTOK/4, 256, 0, stream>>>(yv16, z16, gate_w, g16);
    gemm2_kernel<<<dim3(DMODEL/128, NTOK/128), 256, 0, stream>>>(g16, wout16, out, x);
}

// Round 5
// 353.637 us; speedup vs baseline: 1.2423x; 1.1160x over previous
//
#include <hip/hip_runtime.h>
#include <hip/hip_bf16.h>
#include <stdint.h>

#define SEQ      4096
#define BATCH    2
#define NTOK     (BATCH*SEQ)        // 8192
#define DMODEL   768
#define DINNER   1536
#define NHEADS   24
#define HEADDIM  64
#define DSTATE   16
#define CONVDIM  1568               // 1536 x + 16 B + 16 C
#define NPAD     3200               // GEMM1 padded N (25*128); cols >=3104 dropped
#define NREAL    3104
#define EPSV     1e-5f
#define CHUNK    64
#define NCHUNK   (SEQ/CHUNK)        // 64
#define SUB      32

typedef __bf16 bf16x8 __attribute__((ext_vector_type(8)));
typedef float  floatx4 __attribute__((ext_vector_type(4)));

__device__ __forceinline__ unsigned short f2bf(float f) {
    union { float f; uint32_t u; } v; v.f = f;
    uint32_t u = v.u;
    uint32_t r = (u + 0x7fffu + ((u >> 16) & 1u)) >> 16;
    return (unsigned short)r;
}

__device__ __forceinline__ float bf2f(unsigned short h) {
    union { uint32_t u; float f; } v; v.u = (uint32_t)h << 16;
    return v.f;
}

__device__ __forceinline__ float siluf(float x) { return x / (1.f + __expf(-x)); }

__device__ __forceinline__ float dot4(float4 a, float4 b) {
    return a.x*b.x + a.y*b.y + a.z*b.z + a.w*b.w;
}

__device__ __forceinline__ void async_cp16(const void* g, void* l) {
    __builtin_amdgcn_global_load_lds(
        (const __attribute__((address_space(1))) void*)g,
        (__attribute__((address_space(3))) void*)l,
        16, 0, 0);
}

// ---------------------------------------------------------------------------
// Weight conversion.
// ---------------------------------------------------------------------------
__global__ __launch_bounds__(256) void cvt_kernel(
    const float* __restrict__ Win, const float* __restrict__ Wout,
    unsigned short* __restrict__ win16, unsigned short* __restrict__ wout16)
{
    int idx = blockIdx.x * 256 + threadIdx.x;
    const int n1 = NPAD * DMODEL;
    if (idx < n1) {
        int r = idx / DMODEL;
        win16[idx] = (r < 3128) ? f2bf(Win[idx]) : (unsigned short)0;
    } else {
        int i2 = idx - n1;
        if (i2 < DMODEL * DINNER) wout16[i2] = f2bf(Wout[i2]);
    }
}

// ---------------------------------------------------------------------------
// Fused LayerNorm + dt path.  One wave per token.
// ---------------------------------------------------------------------------
__global__ __launch_bounds__(256) void ln_dt_kernel(
    const float* __restrict__ x, const float* __restrict__ lnw, const float* __restrict__ lnb,
    const float* __restrict__ Win, const float* __restrict__ dt_bias, const float* __restrict__ A_log,
    unsigned short* __restrict__ u16, float* __restrict__ dtv, float* __restrict__ dAv)
{
    int wave = threadIdx.x >> 6, lane = threadIdx.x & 63;
    int token = blockIdx.x * 4 + wave;
    const float* row = x + (size_t)token * DMODEL;
    float4 v[3];
    float s = 0.f, ss = 0.f;
#pragma unroll
    for (int j = 0; j < 3; ++j) {
        v[j] = *(const float4*)(row + lane*4 + j*256);
        s  += v[j].x + v[j].y + v[j].z + v[j].w;
        ss += v[j].x*v[j].x + v[j].y*v[j].y + v[j].z*v[j].z + v[j].w*v[j].w;
    }
#pragma unroll
    for (int o = 32; o > 0; o >>= 1) { s += __shfl_xor(s, o, 64); ss += __shfl_xor(ss, o, 64); }
    float mean = s * (1.f/768.f);
    float var  = ss * (1.f/768.f) - mean*mean;
    float rstd = rsqrtf(var + EPSV);
    unsigned short* brow = u16 + (size_t)token * DMODEL;
    float4 u[3];
#pragma unroll
    for (int j = 0; j < 3; ++j) {
        int cidx = lane*4 + j*256;
        float4 w4 = *(const float4*)(lnw + cidx);
        float4 b4 = *(const float4*)(lnb + cidx);
        u[j].x = (v[j].x - mean)*rstd*w4.x + b4.x;
        u[j].y = (v[j].y - mean)*rstd*w4.y + b4.y;
        u[j].z = (v[j].z - mean)*rstd*w4.z + b4.z;
        u[j].w = (v[j].w - mean)*rstd*w4.w + b4.w;
        ushort4 p; p.x = f2bf(u[j].x); p.y = f2bf(u[j].y); p.z = f2bf(u[j].z); p.w = f2bf(u[j].w);
        *(ushort4*)(brow + cidx) = p;
    }
    for (int hh = 0; hh < NHEADS; ++hh) {
        const float* wrow = Win + (size_t)(3104 + hh) * DMODEL;
        float p = 0.f;
#pragma unroll
        for (int j = 0; j < 3; ++j) {
            float4 wv = *(const float4*)(wrow + lane*4 + j*256);
            p += dot4(u[j], wv);
        }
#pragma unroll
        for (int o = 32; o > 0; o >>= 1) p += __shfl_xor(p, o, 64);
        if (lane == 0) {
            float raw = p + dt_bias[hh];
            float dt = (raw > 20.f) ? raw : log1pf(__expf(raw));
            float A = -__expf(A_log[hh]);
            dtv[(size_t)token*NHEADS + hh] = dt;
            dAv[(size_t)token*NHEADS + hh] = __expf(dt * A);
        }
    }
}

// ---------------------------------------------------------------------------
// GEMM1: C = u16 @ win16^T.  Block 256x128, BK=32, wave tile 128x64.
// XOR-swizzled LDS.
// ---------------------------------------------------------------------------
__global__ __launch_bounds__(256, 2) void gemm1_kernel(
    const unsigned short* __restrict__ A, const unsigned short* __restrict__ Bt,
    unsigned short* __restrict__ z16, float* __restrict__ xbcr)
{
    constexpr int K = DMODEL;
    __shared__ unsigned short As[256*32];   // 16 KB
    __shared__ unsigned short Bs[128*32];   //  8 KB
    const int tid  = threadIdx.x;
    const int lane = tid & 63;
    const int wave = tid >> 6;
    const int m0 = blockIdx.y * 256;
    const int n0 = blockIdx.x * 128;
    const int wm = (wave & 1) * 128;
    const int wn = (wave >> 1) * 64;

    floatx4 acc[8][4];
#pragma unroll
    for (int i = 0; i < 8; ++i)
#pragma unroll
        for (int j = 0; j < 4; ++j) acc[i][j] = floatx4{0.f, 0.f, 0.f, 0.f};

    const int srow = lane >> 2;
    const int sq   = ((lane & 3) ^ (srow & 3)) * 8;
    const int dcol = (lane & 3) * 8;

    for (int k0 = 0; k0 < K; k0 += 32) {
        __syncthreads();
#pragma unroll
        for (int r = 0; r < 4; ++r) {
            int trow = wave*64 + r*16 + srow;
            async_cp16(A + (size_t)(m0 + trow) * K + k0 + sq, As + trow*32 + dcol);
        }
#pragma unroll
        for (int r = 0; r < 2; ++r) {
            int trow = wave*32 + r*16 + srow;
            async_cp16(Bt + (size_t)(n0 + trow) * K + k0 + sq, Bs + trow*32 + dcol);
        }
        __syncthreads();
        const int fr = lane & 15;
        const int q8 = lane >> 4;
        const int fq = (q8 ^ (fr & 3)) * 8;
        bf16x8 b[4];
#pragma unroll
        for (int j = 0; j < 4; ++j) b[j] = *(const bf16x8*)(Bs + (wn + j*16 + fr)*32 + fq);
#pragma unroll
        for (int i = 0; i < 8; ++i) {
            bf16x8 a = *(const bf16x8*)(As + (wm + i*16 + fr)*32 + fq);
#pragma unroll
            for (int j = 0; j < 4; ++j)
                acc[i][j] = __builtin_amdgcn_mfma_f32_16x16x32_bf16(a, b[j], acc[i][j], 0, 0, 0);
        }
    }

    const int col = lane & 15;
    const int rq  = (lane >> 4) * 4;
    if (n0 < DINNER) {
#pragma unroll
        for (int i = 0; i < 8; ++i)
#pragma unroll
            for (int j = 0; j < 4; ++j)
#pragma unroll
                for (int r = 0; r < 4; ++r) {
                    int gm = m0 + wm + i*16 + rq + r;
                    int gn = n0 + wn + j*16 + col;
                    z16[(size_t)gm * DINNER + gn] = f2bf(acc[i][j][r]);
                }
    } else {
#pragma unroll
        for (int i = 0; i < 8; ++i)
#pragma unroll
            for (int j = 0; j < 4; ++j)
#pragma unroll
                for (int r = 0; r < 4; ++r) {
                    int gm = m0 + wm + i*16 + rq + r;
                    int gn = n0 + wn + j*16 + col;
                    if (gn < NREAL)
                        xbcr[(size_t)gm * CONVDIM + (gn - DINNER)] = acc[i][j][r];
                }
    }
}

// ---------------------------------------------------------------------------
// GEMM2: out = g16 @ wout16^T + x.  128x128 tile, XOR-swizzled LDS.
// ---------------------------------------------------------------------------
__global__ __launch_bounds__(256, 2) void gemm2_kernel(
    const unsigned short* __restrict__ A, const unsigned short* __restrict__ Bt,
    float* __restrict__ Cf, const float* __restrict__ resid)
{
    constexpr int K = DINNER;
    __shared__ unsigned short As[128*32];
    __shared__ unsigned short Bs[128*32];
    const int tid  = threadIdx.x;
    const int lane = tid & 63;
    const int wave = tid >> 6;
    const int m0 = blockIdx.y * 128;
    const int n0 = blockIdx.x * 128;
    const int wm = (wave & 1) * 64;
    const int wn = (wave >> 1) * 64;

    floatx4 acc[4][4];
#pragma unroll
    for (int i = 0; i < 4; ++i)
#pragma unroll
        for (int j = 0; j < 4; ++j) acc[i][j] = floatx4{0.f, 0.f, 0.f, 0.f};

    const int srow = lane >> 2;
    const int sq   = ((lane & 3) ^ (srow & 3)) * 8;
    const int dcol = (lane & 3) * 8;

    for (int k0 = 0; k0 < K; k0 += 32) {
        __syncthreads();
#pragma unroll
        for (int r = 0; r < 2; ++r) {
            int trow = r*64 + wave*16 + srow;
            async_cp16(A  + (size_t)(m0 + trow) * K + k0 + sq, As + trow*32 + dcol);
            async_cp16(Bt + (size_t)(n0 + trow) * K + k0 + sq, Bs + trow*32 + dcol);
        }
        __syncthreads();
        const int fr = lane & 15;
        const int q8 = lane >> 4;
        const int fq = (q8 ^ (fr & 3)) * 8;
        bf16x8 a[4], b[4];
#pragma unroll
        for (int i = 0; i < 4; ++i) a[i] = *(const bf16x8*)(As + (wm + i*16 + fr)*32 + fq);
#pragma unroll
        for (int j = 0; j < 4; ++j) b[j] = *(const bf16x8*)(Bs + (wn + j*16 + fr)*32 + fq);
#pragma unroll
        for (int i = 0; i < 4; ++i)
#pragma unroll
            for (int j = 0; j < 4; ++j)
                acc[i][j] = __builtin_amdgcn_mfma_f32_16x16x32_bf16(a[i], b[j], acc[i][j], 0, 0, 0);
    }

    const int col = lane & 15;
    const int rq  = (lane >> 4) * 4;
#pragma unroll
    for (int i = 0; i < 4; ++i)
#pragma unroll
        for (int j = 0; j < 4; ++j)
#pragma unroll
            for (int r = 0; r < 4; ++r) {
                int gm = m0 + wm + i*16 + rq + r;
                int gn = n0 + wn + j*16 + col;
                Cf[(size_t)gm * DMODEL + gn] = acc[i][j][r] + resid[(size_t)gm * DMODEL + gn];
            }
}

// ---------------------------------------------------------------------------
// Pass 1: local scan (h init 0) with fused conv+silu.  Emits:
//   y_local[t] = C.h_local + D*xc   (bf16)
//   hloc = h_local end state, pprod = decay product over chunk.
// x path in registers (rolling 3-tap window); B/C via LDS halo tile.
// ---------------------------------------------------------------------------
__global__ __launch_bounds__(64) void scan_pass1(
    const float* __restrict__ xbcr, const float* __restrict__ dAv, const float* __restrict__ dtv,
    const float* __restrict__ cw, const float* __restrict__ cb, const float* __restrict__ Dp,
    float* __restrict__ hloc, float* __restrict__ pprod, unsigned short* __restrict__ ylocal16)
{
    int blk = blockIdx.x;                 // bh*NCHUNK + c
    int c = blk & (NCHUNK-1), bh = blk >> 6;
    int h = bh % NHEADS, b = bh / NHEADS;
    int lane = threadIdx.x;
    int row0 = b * SEQ + c * CHUNK;
    int l0 = c * CHUNK;
    __shared__ float bcraw[35][32];
    __shared__ float bcsc[SUB][32];       // conv'd: 0..15 = B, 16..31 = C
    __shared__ float av[SUB], dv[SUB];

    const int cx = h*64 + lane;
    float cwx0 = cw[cx*4+0], cwx1 = cw[cx*4+1], cwx2 = cw[cx*4+2], cwx3 = cw[cx*4+3];
    float cbx = cb[cx];
    const int nBC = lane & 31;
    float cwc0 = cw[(DINNER+nBC)*4+0], cwc1 = cw[(DINNER+nBC)*4+1];
    float cwc2 = cw[(DINNER+nBC)*4+2], cwc3 = cw[(DINNER+nBC)*4+3];
    float cbc = cb[DINNER+nBC];
    float Dh = Dp[h];

    // rolling raw-x window (rows row0-3..row0-1), zero outside sequence
    float xm3 = (l0 >= 3) ? xbcr[(size_t)(row0-3)*CONVDIM + cx] : 0.f;
    float xm2 = (l0 >= 2) ? xbcr[(size_t)(row0-2)*CONVDIM + cx] : 0.f;
    float xm1 = (l0 >= 1) ? xbcr[(size_t)(row0-1)*CONVDIM + cx] : 0.f;

    float hst[16];
#pragma unroll
    for (int n = 0; n < 16; ++n) hst[n] = 0.f;
    float aprod = 1.f;

    for (int sc = 0; sc < CHUNK/SUB; ++sc) {
        int rb = row0 + sc * SUB;
        int lb = l0 + sc * SUB;
        __syncthreads();
#pragma unroll
        for (int it = 0; it < 5; ++it) {        // B+C rows rb-3..rb+31 (35x8 float4)
            int idx = it*64 + lane;
            if (idx < 280) {
                int s = idx >> 3, q = idx & 7;
                float4 val = {0.f,0.f,0.f,0.f};
                if (lb - 3 + s >= 0)
                    val = *(const float4*)(xbcr + (size_t)(rb-3+s)*CONVDIM + DINNER + q*4);
                *(float4*)&bcraw[s][q*4] = val;
            }
        }
        if (lane < 32) av[lane] = dAv[(size_t)(rb+lane)*NHEADS + h];
        else           dv[lane-32] = dtv[(size_t)(rb+lane-32)*NHEADS + h];
        float xr[SUB];
#pragma unroll
        for (int s = 0; s < SUB; ++s)
            xr[s] = xbcr[(size_t)(rb+s)*CONVDIM + cx];
        __syncthreads();
#pragma unroll
        for (int it = 0; it < 16; ++it) {       // conv B,C -> bcsc
            int s = it*2 + (lane >> 5);
            float v = cbc + bcraw[s][nBC]*cwc0 + bcraw[s+1][nBC]*cwc1
                          + bcraw[s+2][nBC]*cwc2 + bcraw[s+3][nBC]*cwc3;
            bcsc[s][nBC] = siluf(v);
        }
        __syncthreads();
#pragma unroll 4
        for (int s = 0; s < SUB; ++s) {
            float a = av[s];
            float xc = siluf(cbx + xm3*cwx0 + xm2*cwx1 + xm1*cwx2 + xr[s]*cwx3);
            xm3 = xm2; xm2 = xm1; xm1 = xr[s];
            float scale = dv[s] * xc;
            const float* bp = bcsc[s];
            float y = Dh * xc;
#pragma unroll
            for (int n = 0; n < 16; ++n) hst[n] = a*hst[n] + scale*bp[n];
#pragma unroll
            for (int n = 0; n < 16; ++n) y += hst[n] * bp[16+n];
            aprod *= a;
            ylocal16[(size_t)(rb+s)*DINNER + cx] = f2bf(y);
        }
    }
    float* o = hloc + (size_t)blk * 1024 + lane * 16;
#pragma unroll
    for (int n = 0; n < 16; ++n) o[n] = hst[n];
    if (lane == 0) pprod[blk] = aprod;
}

// Pass 2: sequential recombine over NCHUNK chunks per (b,h).
__global__ __launch_bounds__(64) void scan_pass2(
    const float* __restrict__ hloc, const float* __restrict__ pprod, float* __restrict__ hstart)
{
    int bh = blockIdx.x, lane = threadIdx.x;
    float hst[16];
#pragma unroll
    for (int n = 0; n < 16; ++n) hst[n] = 0.f;
    for (int c = 0; c < NCHUNK; ++c) {
        int blk = bh * NCHUNK + c;
        float* o = hstart + (size_t)blk * 1024 + lane * 16;
#pragma unroll
        for (int n = 0; n < 16; ++n) o[n] = hst[n];
        float P = pprod[blk];
        const float* hl = hloc + (size_t)blk * 1024 + lane * 16;
#pragma unroll
        for (int n = 0; n < 16; ++n) hst[n] = P * hst[n] + hl[n];
    }
}

// ---------------------------------------------------------------------------
// Pass 3 (lite): y[t] += cumdecay[t] * (C[t] . h_start), in-place on ylocal16.
// No x read, no h-update chain.  C conv'd from raw xbcr (16 channels).
// ---------------------------------------------------------------------------
__global__ __launch_bounds__(64) void scan_pass3(
    const float* __restrict__ xbcr, const float* __restrict__ dAv,
    const float* __restrict__ cw, const float* __restrict__ cb,
    const float* __restrict__ hstart, unsigned short* __restrict__ ylocal16)
{
    int blk = blockIdx.x;
    int c = blk & (NCHUNK-1), bh = blk >> 6;
    int h = bh % NHEADS, b = bh / NHEADS;
    int lane = threadIdx.x;
    int row0 = b * SEQ + c * CHUNK;
    int l0 = c * CHUNK;
    __shared__ float craw[35][16];
    __shared__ float csc[SUB][16];
    __shared__ float av[SUB];

    const int cx = h*64 + lane;
    const int nC = lane & 15;
    float cwc0 = cw[(DINNER+16+nC)*4+0], cwc1 = cw[(DINNER+16+nC)*4+1];
    float cwc2 = cw[(DINNER+16+nC)*4+2], cwc3 = cw[(DINNER+16+nC)*4+3];
    float cbc = cb[DINNER+16+nC];

    float h0[16];
    const float* hs = hstart + (size_t)blk * 1024 + lane * 16;
#pragma unroll
    for (int n = 0; n < 16; ++n) h0[n] = hs[n];
    float cd = 1.f;

    for (int sc = 0; sc < CHUNK/SUB; ++sc) {
        int rb = row0 + sc * SUB;
        int lb = l0 + sc * SUB;
        __syncthreads();
#pragma unroll
        for (int it = 0; it < 3; ++it) {        // C rows rb-3..rb+31 (35x4 float4)
            int idx = it*64 + lane;
            if (idx < 140) {
                int s = idx >> 2, q = idx & 3;
                float4 val = {0.f,0.f,0.f,0.f};
                if (lb - 3 + s >= 0)
                    val = *(const float4*)(xbcr + (size_t)(rb-3+s)*CONVDIM + DINNER + 16 + q*4);
                *(float4*)&craw[s][q*4] = val;
            }
        }
        if (lane < 32) av[lane] = dAv[(size_t)(rb+lane)*NHEADS + h];
        float yr[SUB];
#pragma unroll
        for (int s = 0; s < SUB; ++s)
            yr[s] = bf2f(ylocal16[(size_t)(rb+s)*DINNER + cx]);
        __syncthreads();
#pragma unroll
        for (int it = 0; it < 8; ++it) {        // conv C -> csc
            int s = it*4 + (lane >> 4);
            float v = cbc + craw[s][nC]*cwc0 + craw[s+1][nC]*cwc1
                          + craw[s+2][nC]*cwc2 + craw[s+3][nC]*cwc3;
            csc[s][nC] = siluf(v);
        }
        __syncthreads();
#pragma unroll 4
        for (int s = 0; s < SUB; ++s) {
            cd *= av[s];
            const float* cp = csc[s];
            float corr = 0.f;
#pragma unroll
            for (int n = 0; n < 16; ++n) corr += cp[n] * h0[n];
            ylocal16[(size_t)(rb+s)*DINNER + cx] = f2bf(yr[s] + cd * corr);
        }
    }
}

// ---------------------------------------------------------------------------
// Gating + RMSNorm -> bf16
// ---------------------------------------------------------------------------
__global__ __launch_bounds__(256) void gate_kernel(
    const unsigned short* __restrict__ yv16, const unsigned short* __restrict__ z16,
    const float* __restrict__ gw, unsigned short* __restrict__ g16)
{
    int wave = threadIdx.x >> 6, lane = threadIdx.x & 63;
    int token = blockIdx.x * 4 + wave;
    const unsigned short* yrow = yv16 + (size_t)token * DINNER;
    const unsigned short* zrow = z16 + (size_t)token * DINNER;
    float4 gv[6];
    float ss = 0.f;
#pragma unroll
    for (int j = 0; j < 6; ++j) {
        int cidx = lane*4 + j*256;
        ushort4 y4 = *(const ushort4*)(yrow + cidx);
        ushort4 z4 = *(const ushort4*)(zrow + cidx);
        gv[j].x = bf2f(y4.x) * siluf(bf2f(z4.x));
        gv[j].y = bf2f(y4.y) * siluf(bf2f(z4.y));
        gv[j].z = bf2f(y4.z) * siluf(bf2f(z4.z));
        gv[j].w = bf2f(y4.w) * siluf(bf2f(z4.w));
        ss += gv[j].x*gv[j].x + gv[j].y*gv[j].y + gv[j].z*gv[j].z + gv[j].w*gv[j].w;
    }
#pragma unroll
    for (int o = 32; o > 0; o >>= 1) ss += __shfl_xor(ss, o, 64);
    float scale = rsqrtf(ss * (1.f/1536.f) + EPSV);
    unsigned short* orow = g16 + (size_t)token * DINNER;
#pragma unroll
    for (int j = 0; j < 6; ++j) {
        int cidx = lane*4 + j*256;
        float4 w4 = *(const float4*)(gw + cidx);
        ushort4 p;
        p.x = f2bf(gv[j].x * scale * w4.x);
        p.y = f2bf(gv[j].y * scale * w4.y);
        p.z = f2bf(gv[j].z * scale * w4.z);
        p.w = f2bf(gv[j].w * scale * w4.w);
        *(ushort4*)(orow + cidx) = p;
    }
}

// ---------------------------------------------------------------------------
extern "C" void kernel_launch(void* const* d_in, const int* in_sizes, int n_in,
                              void* d_out, int out_size, void* d_ws, size_t ws_size,
                              hipStream_t stream)
{
    const float* x        = (const float*)d_in[0];
    const float* ln_w     = (const float*)d_in[1];
    const float* ln_b     = (const float*)d_in[2];
    const float* W_in     = (const float*)d_in[3];
    const float* conv_w   = (const float*)d_in[4];
    const float* conv_b   = (const float*)d_in[5];
    const float* dt_bias  = (const float*)d_in[6];
    const float* A_log    = (const float*)d_in[7];
    const float* Dp       = (const float*)d_in[8];
    const float* gate_w   = (const float*)d_in[9];
    const float* W_out    = (const float*)d_in[10];
    float* out = (float*)d_out;

    char* ws = (char*)d_ws;
    size_t off = 0;
    auto alloc = [&](size_t bytes) -> void* {
        void* p = ws + off;
        off += (bytes + 255) & ~(size_t)255;
        return p;
    };
    unsigned short* u16    = (unsigned short*)alloc((size_t)NTOK*DMODEL*2);            // 12.58 MB
    unsigned short* win16  = (unsigned short*)alloc((size_t)NPAD*DMODEL*2);            //  4.92 MB
    float*          dtv    = (float*)alloc((size_t)NTOK*NHEADS*4);                     //  0.79 MB
    float*          dAv    = (float*)alloc((size_t)NTOK*NHEADS*4);                     //  0.79 MB
    float*          xbcr   = (float*)alloc((size_t)NTOK*CONVDIM*4);                    // 51.38 MB (live thru pass3)
    unsigned short* wout16 = (unsigned short*)alloc((size_t)DMODEL*DINNER*2);          //  2.36 MB
    unsigned short* z16    = (unsigned short*)alloc((size_t)NTOK*DINNER*2);            // 25.17 MB
    unsigned short* y16    = (unsigned short*)alloc((size_t)NTOK*DINNER*2);            // 25.17 MB (ylocal, then final y in-place)
    unsigned short* g16    = (unsigned short*)alloc((size_t)NTOK*DINNER*2);            // 25.17 MB
    float*          pprod  = (float*)alloc((size_t)BATCH*NHEADS*NCHUNK*4);             //  0.01 MB
    // aliases (lifetime-checked):
    float* hloc   = (float*)u16;    // 12.58 MB == u16 size; u16 dead after gemm1
    float* hstart = (float*)g16;    // 12.58 MB <= g16; g16 written at gate, after pass3 reads hstart
    // high-water ~148.4 MB

    cvt_kernel<<<(NPAD*DMODEL + DMODEL*DINNER)/256, 256, 0, stream>>>(W_in, W_out, win16, wout16);
    ln_dt_kernel<<<NTOK/4, 256, 0, stream>>>(x, ln_w, ln_b, W_in, dt_bias, A_log, u16, dtv, dAv);
    gemm1_kernel<<<dim3(NPAD/128, NTOK/256), 256, 0, stream>>>(u16, win16, z16, xbcr);
    scan_pass1<<<BATCH*NHEADS*NCHUNK, 64, 0, stream>>>(xbcr, dAv, dtv, conv_w, conv_b, Dp, hloc, pprod, y16);
    scan_pass2<<<BATCH*NHEADS, 64, 0, stream>>>(hloc, pprod, hstart);
    scan_pass3<<<BATCH*NHEADS*NCHUNK, 64, 0, stream>>>(xbcr, dAv, conv_w, conv_b, hstart, y16);
    gate_kernel<<<NTOK/4, 256, 0, stream>>>(y16, z16, gate_w, g16);
    gemm2_kernel<<<dim3(DMODEL/128, NTOK/128), 256, 0, stream>>>(g16, wout16, out, x);
}

// Round 6
// 350.156 us; speedup vs baseline: 1.2547x; 1.0099x over previous
//
#include <hip/hip_runtime.h>
#include <hip/hip_bf16.h>
#include <stdint.h>

#define SEQ      4096
#define BATCH    2
#define NTOK     (BATCH*SEQ)        // 8192
#define DMODEL   768
#define DINNER   1536
#define NHEADS   24
#define HEADDIM  64
#define DSTATE   16
#define NPAD     3200               // GEMM1 padded N (25*128)
#define EPSV     1e-5f
#define CHUNK    64
#define NCHUNK   (SEQ/CHUNK)        // 64
#define SUB      32

typedef __bf16 bf16x8 __attribute__((ext_vector_type(8)));
typedef float  floatx4 __attribute__((ext_vector_type(4)));

__device__ __forceinline__ unsigned short f2bf(float f) {
    union { float f; uint32_t u; } v; v.f = f;
    uint32_t u = v.u;
    uint32_t r = (u + 0x7fffu + ((u >> 16) & 1u)) >> 16;
    return (unsigned short)r;
}

__device__ __forceinline__ float bf2f(unsigned short h) {
    union { uint32_t u; float f; } v; v.u = (uint32_t)h << 16;
    return v.f;
}

__device__ __forceinline__ float siluf(float x) { return x / (1.f + __expf(-x)); }

__device__ __forceinline__ float dot4(float4 a, float4 b) {
    return a.x*b.x + a.y*b.y + a.z*b.z + a.w*b.w;
}

__device__ __forceinline__ void async_cp16(const void* g, void* l) {
    __builtin_amdgcn_global_load_lds(
        (const __attribute__((address_space(1))) void*)g,
        (__attribute__((address_space(3))) void*)l,
        16, 0, 0);
}

// ---------------------------------------------------------------------------
// Weight conversion.
// ---------------------------------------------------------------------------
__global__ __launch_bounds__(256) void cvt_kernel(
    const float* __restrict__ Win, const float* __restrict__ Wout,
    unsigned short* __restrict__ win16, unsigned short* __restrict__ wout16)
{
    int idx = blockIdx.x * 256 + threadIdx.x;
    const int n1 = NPAD * DMODEL;
    if (idx < n1) {
        int r = idx / DMODEL;
        win16[idx] = (r < 3128) ? f2bf(Win[idx]) : (unsigned short)0;
    } else {
        int i2 = idx - n1;
        if (i2 < DMODEL * DINNER) wout16[i2] = f2bf(Wout[i2]);
    }
}

// ---------------------------------------------------------------------------
// Fused LayerNorm + dt path.  One wave per token.
// ---------------------------------------------------------------------------
__global__ __launch_bounds__(256) void ln_dt_kernel(
    const float* __restrict__ x, const float* __restrict__ lnw, const float* __restrict__ lnb,
    const float* __restrict__ Win, const float* __restrict__ dt_bias, const float* __restrict__ A_log,
    unsigned short* __restrict__ u16, float* __restrict__ dtv, float* __restrict__ dAv)
{
    int wave = threadIdx.x >> 6, lane = threadIdx.x & 63;
    int token = blockIdx.x * 4 + wave;
    const float* row = x + (size_t)token * DMODEL;
    float4 v[3];
    float s = 0.f, ss = 0.f;
#pragma unroll
    for (int j = 0; j < 3; ++j) {
        v[j] = *(const float4*)(row + lane*4 + j*256);
        s  += v[j].x + v[j].y + v[j].z + v[j].w;
        ss += v[j].x*v[j].x + v[j].y*v[j].y + v[j].z*v[j].z + v[j].w*v[j].w;
    }
#pragma unroll
    for (int o = 32; o > 0; o >>= 1) { s += __shfl_xor(s, o, 64); ss += __shfl_xor(ss, o, 64); }
    float mean = s * (1.f/768.f);
    float var  = ss * (1.f/768.f) - mean*mean;
    float rstd = rsqrtf(var + EPSV);
    unsigned short* brow = u16 + (size_t)token * DMODEL;
    float4 u[3];
#pragma unroll
    for (int j = 0; j < 3; ++j) {
        int cidx = lane*4 + j*256;
        float4 w4 = *(const float4*)(lnw + cidx);
        float4 b4 = *(const float4*)(lnb + cidx);
        u[j].x = (v[j].x - mean)*rstd*w4.x + b4.x;
        u[j].y = (v[j].y - mean)*rstd*w4.y + b4.y;
        u[j].z = (v[j].z - mean)*rstd*w4.z + b4.z;
        u[j].w = (v[j].w - mean)*rstd*w4.w + b4.w;
        ushort4 p; p.x = f2bf(u[j].x); p.y = f2bf(u[j].y); p.z = f2bf(u[j].z); p.w = f2bf(u[j].w);
        *(ushort4*)(brow + cidx) = p;
    }
    for (int hh = 0; hh < NHEADS; ++hh) {
        const float* wrow = Win + (size_t)(3104 + hh) * DMODEL;
        float p = 0.f;
#pragma unroll
        for (int j = 0; j < 3; ++j) {
            float4 wv = *(const float4*)(wrow + lane*4 + j*256);
            p += dot4(u[j], wv);
        }
#pragma unroll
        for (int o = 32; o > 0; o >>= 1) p += __shfl_xor(p, o, 64);
        if (lane == 0) {
            float raw = p + dt_bias[hh];
            float dt = (raw > 20.f) ? raw : log1pf(__expf(raw));
            float A = -__expf(A_log[hh]);
            dtv[(size_t)token*NHEADS + hh] = dt;
            dAv[(size_t)token*NHEADS + hh] = __expf(dt * A);
        }
    }
}

// ---------------------------------------------------------------------------
// GEMM1: C = u16 @ win16^T.  Block 256x128, BK=32, wave tile 128x64.
// 1D grid (800) with XCD swizzle: id&7 = XCD, each XCD owns 4 M-tiles and
// sweeps N-tiles; u-tiles stay hot in that XCD's L2, win16 streams once.
// Split store: z16 (bf16) | x16 (bf16) | bcr (f32, 32 cols).
// Note: SQ_LDS_BANK_CONFLICT ~= 4/b128 is structural (same count with and
// without XOR swizzle) - not addressable at source level.
// ---------------------------------------------------------------------------
__global__ __launch_bounds__(256, 2) void gemm1_kernel(
    const unsigned short* __restrict__ A, const unsigned short* __restrict__ Bt,
    unsigned short* __restrict__ z16, unsigned short* __restrict__ x16,
    float* __restrict__ bcr)
{
    constexpr int K = DMODEL;
    __shared__ unsigned short As[256*32];   // 16 KB
    __shared__ unsigned short Bs[128*32];   //  8 KB
    const int tid  = threadIdx.x;
    const int lane = tid & 63;
    const int wave = tid >> 6;
    const int id   = blockIdx.x;
    const int xcd  = id & 7;
    const int j5   = id >> 3;               // 0..99
    const int m0 = (xcd*4 + (j5 & 3)) * 256;
    const int n0 = (j5 >> 2) * 128;
    const int wm = (wave & 1) * 128;
    const int wn = (wave >> 1) * 64;

    floatx4 acc[8][4];
#pragma unroll
    for (int i = 0; i < 8; ++i)
#pragma unroll
        for (int j = 0; j < 4; ++j) acc[i][j] = floatx4{0.f, 0.f, 0.f, 0.f};

    const int srow = lane >> 2;
    const int sq   = ((lane & 3) ^ (srow & 3)) * 8;
    const int dcol = (lane & 3) * 8;

    for (int k0 = 0; k0 < K; k0 += 32) {
        __syncthreads();
#pragma unroll
        for (int r = 0; r < 4; ++r) {
            int trow = wave*64 + r*16 + srow;
            async_cp16(A + (size_t)(m0 + trow) * K + k0 + sq, As + trow*32 + dcol);
        }
#pragma unroll
        for (int r = 0; r < 2; ++r) {
            int trow = wave*32 + r*16 + srow;
            async_cp16(Bt + (size_t)(n0 + trow) * K + k0 + sq, Bs + trow*32 + dcol);
        }
        __syncthreads();
        const int fr = lane & 15;
        const int q8 = lane >> 4;
        const int fq = (q8 ^ (fr & 3)) * 8;
        bf16x8 b[4];
#pragma unroll
        for (int j = 0; j < 4; ++j) b[j] = *(const bf16x8*)(Bs + (wn + j*16 + fr)*32 + fq);
#pragma unroll
        for (int i = 0; i < 8; ++i) {
            bf16x8 a = *(const bf16x8*)(As + (wm + i*16 + fr)*32 + fq);
#pragma unroll
            for (int j = 0; j < 4; ++j)
                acc[i][j] = __builtin_amdgcn_mfma_f32_16x16x32_bf16(a, b[j], acc[i][j], 0, 0, 0);
        }
    }

    const int col = lane & 15;
    const int rq  = (lane >> 4) * 4;
    if (n0 < DINNER) {                      // tiles 0..11 -> z
#pragma unroll
        for (int i = 0; i < 8; ++i)
#pragma unroll
            for (int j = 0; j < 4; ++j)
#pragma unroll
                for (int r = 0; r < 4; ++r) {
                    int gm = m0 + wm + i*16 + rq + r;
                    int gn = n0 + wn + j*16 + col;
                    z16[(size_t)gm * DINNER + gn] = f2bf(acc[i][j][r]);
                }
    } else if (n0 < 3072) {                 // tiles 12..23 -> x (bf16)
#pragma unroll
        for (int i = 0; i < 8; ++i)
#pragma unroll
            for (int j = 0; j < 4; ++j)
#pragma unroll
                for (int r = 0; r < 4; ++r) {
                    int gm = m0 + wm + i*16 + rq + r;
                    int gn = n0 + wn + j*16 + col;
                    x16[(size_t)gm * DINNER + (gn - DINNER)] = f2bf(acc[i][j][r]);
                }
    } else {                                // tile 24: first 32 cols -> bcr f32
#pragma unroll
        for (int i = 0; i < 8; ++i)
#pragma unroll
            for (int j = 0; j < 4; ++j)
#pragma unroll
                for (int r = 0; r < 4; ++r) {
                    int gm = m0 + wm + i*16 + rq + r;
                    int gn = n0 + wn + j*16 + col;
                    if (gn < 3104)
                        bcr[(size_t)gm * 32 + (gn - 3072)] = acc[i][j][r];
                }
    }
}

// ---------------------------------------------------------------------------
// GEMM2: out = g16 @ wout16^T + x.  Block 64x128 (768 blocks, fully resident),
// wave tile 32x64, XCD swizzle.
// ---------------------------------------------------------------------------
__global__ __launch_bounds__(256, 4) void gemm2_kernel(
    const unsigned short* __restrict__ A, const unsigned short* __restrict__ Bt,
    float* __restrict__ Cf, const float* __restrict__ resid)
{
    constexpr int K = DINNER;
    __shared__ unsigned short As[64*32];    // 4 KB
    __shared__ unsigned short Bs[128*32];   // 8 KB
    const int tid  = threadIdx.x;
    const int lane = tid & 63;
    const int wave = tid >> 6;
    const int id   = blockIdx.x;
    const int xcd  = id & 7;
    const int j6   = id >> 3;               // 0..95
    const int m0 = (xcd*16 + j6/6) * 64;    // 128 M-tiles
    const int n0 = (j6 % 6) * 128;          // 6 N-tiles
    const int wm = (wave & 1) * 32;
    const int wn = (wave >> 1) * 64;

    floatx4 acc[2][4];
#pragma unroll
    for (int i = 0; i < 2; ++i)
#pragma unroll
        for (int j = 0; j < 4; ++j) acc[i][j] = floatx4{0.f, 0.f, 0.f, 0.f};

    const int srow = lane >> 2;
    const int sq   = ((lane & 3) ^ (srow & 3)) * 8;
    const int dcol = (lane & 3) * 8;

    for (int k0 = 0; k0 < K; k0 += 32) {
        __syncthreads();
        {
            int trow = wave*16 + srow;
            async_cp16(A + (size_t)(m0 + trow) * K + k0 + sq, As + trow*32 + dcol);
        }
#pragma unroll
        for (int r = 0; r < 2; ++r) {
            int trow = wave*32 + r*16 + srow;
            async_cp16(Bt + (size_t)(n0 + trow) * K + k0 + sq, Bs + trow*32 + dcol);
        }
        __syncthreads();
        const int fr = lane & 15;
        const int q8 = lane >> 4;
        const int fq = (q8 ^ (fr & 3)) * 8;
        bf16x8 a[2], b[4];
#pragma unroll
        for (int i = 0; i < 2; ++i) a[i] = *(const bf16x8*)(As + (wm + i*16 + fr)*32 + fq);
#pragma unroll
        for (int j = 0; j < 4; ++j) b[j] = *(const bf16x8*)(Bs + (wn + j*16 + fr)*32 + fq);
#pragma unroll
        for (int i = 0; i < 2; ++i)
#pragma unroll
            for (int j = 0; j < 4; ++j)
                acc[i][j] = __builtin_amdgcn_mfma_f32_16x16x32_bf16(a[i], b[j], acc[i][j], 0, 0, 0);
    }

    const int col = lane & 15;
    const int rq  = (lane >> 4) * 4;
#pragma unroll
    for (int i = 0; i < 2; ++i)
#pragma unroll
        for (int j = 0; j < 4; ++j)
#pragma unroll
            for (int r = 0; r < 4; ++r) {
                int gm = m0 + wm + i*16 + rq + r;
                int gn = n0 + wn + j*16 + col;
                Cf[(size_t)gm * DMODEL + gn] = acc[i][j][r] + resid[(size_t)gm * DMODEL + gn];
            }
}

// ---------------------------------------------------------------------------
// Pass 1: local scan (h init 0) with fused conv+silu.  Emits y_local (bf16),
// hloc end-state, pprod decay product.  x from bf16 x16 (register window),
// B/C from f32 bcr via LDS halo tile.
// ---------------------------------------------------------------------------
__global__ __launch_bounds__(64) void scan_pass1(
    const unsigned short* __restrict__ x16, const float* __restrict__ bcr,
    const float* __restrict__ dAv, const float* __restrict__ dtv,
    const float* __restrict__ cw, const float* __restrict__ cb, const float* __restrict__ Dp,
    float* __restrict__ hloc, float* __restrict__ pprod, unsigned short* __restrict__ ylocal16)
{
    int blk = blockIdx.x;                 // bh*NCHUNK + c
    int c = blk & (NCHUNK-1), bh = blk >> 6;
    int h = bh % NHEADS, b = bh / NHEADS;
    int lane = threadIdx.x;
    int row0 = b * SEQ + c * CHUNK;
    int l0 = c * CHUNK;
    __shared__ float bcraw[35][32];
    __shared__ float bcsc[SUB][32];       // conv'd: 0..15 = B, 16..31 = C
    __shared__ float av[SUB], dv[SUB];

    const int cx = h*64 + lane;
    float cwx0 = cw[cx*4+0], cwx1 = cw[cx*4+1], cwx2 = cw[cx*4+2], cwx3 = cw[cx*4+3];
    float cbx = cb[cx];
    const int nBC = lane & 31;
    float cwc0 = cw[(DINNER+nBC)*4+0], cwc1 = cw[(DINNER+nBC)*4+1];
    float cwc2 = cw[(DINNER+nBC)*4+2], cwc3 = cw[(DINNER+nBC)*4+3];
    float cbc = cb[DINNER+nBC];
    float Dh = Dp[h];

    float xm3 = (l0 >= 3) ? bf2f(x16[(size_t)(row0-3)*DINNER + cx]) : 0.f;
    float xm2 = (l0 >= 2) ? bf2f(x16[(size_t)(row0-2)*DINNER + cx]) : 0.f;
    float xm1 = (l0 >= 1) ? bf2f(x16[(size_t)(row0-1)*DINNER + cx]) : 0.f;

    float hst[16];
#pragma unroll
    for (int n = 0; n < 16; ++n) hst[n] = 0.f;
    float aprod = 1.f;

    for (int sc = 0; sc < CHUNK/SUB; ++sc) {
        int rb = row0 + sc * SUB;
        int lb = l0 + sc * SUB;
        __syncthreads();
#pragma unroll
        for (int it = 0; it < 5; ++it) {        // B+C rows rb-3..rb+31 (35x8 float4)
            int idx = it*64 + lane;
            if (idx < 280) {
                int s = idx >> 3, q = idx & 7;
                float4 val = {0.f,0.f,0.f,0.f};
                if (lb - 3 + s >= 0)
                    val = *(const float4*)(bcr + (size_t)(rb-3+s)*32 + q*4);
                *(float4*)&bcraw[s][q*4] = val;
            }
        }
        if (lane < 32) av[lane] = dAv[(size_t)(rb+lane)*NHEADS + h];
        else           dv[lane-32] = dtv[(size_t)(rb+lane-32)*NHEADS + h];
        float xr[SUB];
#pragma unroll
        for (int s = 0; s < SUB; ++s)
            xr[s] = bf2f(x16[(size_t)(rb+s)*DINNER + cx]);
        __syncthreads();
#pragma unroll
        for (int it = 0; it < 16; ++it) {       // conv B,C -> bcsc
            int s = it*2 + (lane >> 5);
            float v = cbc + bcraw[s][nBC]*cwc0 + bcraw[s+1][nBC]*cwc1
                          + bcraw[s+2][nBC]*cwc2 + bcraw[s+3][nBC]*cwc3;
            bcsc[s][nBC] = siluf(v);
        }
        __syncthreads();
#pragma unroll 4
        for (int s = 0; s < SUB; ++s) {
            float a = av[s];
            float xc = siluf(cbx + xm3*cwx0 + xm2*cwx1 + xm1*cwx2 + xr[s]*cwx3);
            xm3 = xm2; xm2 = xm1; xm1 = xr[s];
            float scale = dv[s] * xc;
            const float* bp = bcsc[s];
            float y = Dh * xc;
#pragma unroll
            for (int n = 0; n < 16; ++n) hst[n] = a*hst[n] + scale*bp[n];
#pragma unroll
            for (int n = 0; n < 16; ++n) y += hst[n] * bp[16+n];
            aprod *= a;
            ylocal16[(size_t)(rb+s)*DINNER + cx] = f2bf(y);
        }
    }
    float* o = hloc + (size_t)blk * 1024 + lane * 16;
#pragma unroll
    for (int n = 0; n < 16; ++n) o[n] = hst[n];
    if (lane == 0) pprod[blk] = aprod;
}

// Pass 2: sequential recombine over NCHUNK chunks per (b,h).
__global__ __launch_bounds__(64) void scan_pass2(
    const float* __restrict__ hloc, const float* __restrict__ pprod, float* __restrict__ hstart)
{
    int bh = blockIdx.x, lane = threadIdx.x;
    float hst[16];
#pragma unroll
    for (int n = 0; n < 16; ++n) hst[n] = 0.f;
    for (int c = 0; c < NCHUNK; ++c) {
        int blk = bh * NCHUNK + c;
        float* o = hstart + (size_t)blk * 1024 + lane * 16;
#pragma unroll
        for (int n = 0; n < 16; ++n) o[n] = hst[n];
        float P = pprod[blk];
        const float* hl = hloc + (size_t)blk * 1024 + lane * 16;
#pragma unroll
        for (int n = 0; n < 16; ++n) hst[n] = P * hst[n] + hl[n];
    }
}

// ---------------------------------------------------------------------------
// Pass 3 (lite): y[t] += cumdecay[t] * (C[t] . h_start), in-place on ylocal16.
// ---------------------------------------------------------------------------
__global__ __launch_bounds__(64) void scan_pass3(
    const float* __restrict__ bcr, const float* __restrict__ dAv,
    const float* __restrict__ cw, const float* __restrict__ cb,
    const float* __restrict__ hstart, unsigned short* __restrict__ ylocal16)
{
    int blk = blockIdx.x;
    int c = blk & (NCHUNK-1), bh = blk >> 6;
    int h = bh % NHEADS, b = bh / NHEADS;
    int lane = threadIdx.x;
    int row0 = b * SEQ + c * CHUNK;
    int l0 = c * CHUNK;
    __shared__ float craw[35][16];
    __shared__ float csc[SUB][16];
    __shared__ float av[SUB];

    const int cx = h*64 + lane;
    const int nC = lane & 15;
    float cwc0 = cw[(DINNER+16+nC)*4+0], cwc1 = cw[(DINNER+16+nC)*4+1];
    float cwc2 = cw[(DINNER+16+nC)*4+2], cwc3 = cw[(DINNER+16+nC)*4+3];
    float cbc = cb[DINNER+16+nC];

    float h0[16];
    const float* hs = hstart + (size_t)blk * 1024 + lane * 16;
#pragma unroll
    for (int n = 0; n < 16; ++n) h0[n] = hs[n];
    float cd = 1.f;

    for (int sc = 0; sc < CHUNK/SUB; ++sc) {
        int rb = row0 + sc * SUB;
        int lb = l0 + sc * SUB;
        __syncthreads();
#pragma unroll
        for (int it = 0; it < 3; ++it) {        // C rows rb-3..rb+31 (35x4 float4)
            int idx = it*64 + lane;
            if (idx < 140) {
                int s = idx >> 2, q = idx & 3;
                float4 val = {0.f,0.f,0.f,0.f};
                if (lb - 3 + s >= 0)
                    val = *(const float4*)(bcr + (size_t)(rb-3+s)*32 + 16 + q*4);
                *(float4*)&craw[s][q*4] = val;
            }
        }
        if (lane < 32) av[lane] = dAv[(size_t)(rb+lane)*NHEADS + h];
        float yr[SUB];
#pragma unroll
        for (int s = 0; s < SUB; ++s)
            yr[s] = bf2f(ylocal16[(size_t)(rb+s)*DINNER + cx]);
        __syncthreads();
#pragma unroll
        for (int it = 0; it < 8; ++it) {        // conv C -> csc
            int s = it*4 + (lane >> 4);
            float v = cbc + craw[s][nC]*cwc0 + craw[s+1][nC]*cwc1
                          + craw[s+2][nC]*cwc2 + craw[s+3][nC]*cwc3;
            csc[s][nC] = siluf(v);
        }
        __syncthreads();
#pragma unroll 4
        for (int s = 0; s < SUB; ++s) {
            cd *= av[s];
            const float* cp = csc[s];
            float corr = 0.f;
#pragma unroll
            for (int n = 0; n < 16; ++n) corr += cp[n] * h0[n];
            ylocal16[(size_t)(rb+s)*DINNER + cx] = f2bf(yr[s] + cd * corr);
        }
    }
}

// ---------------------------------------------------------------------------
// Gating + RMSNorm -> bf16
// ---------------------------------------------------------------------------
__global__ __launch_bounds__(256) void gate_kernel(
    const unsigned short* __restrict__ yv16, const unsigned short* __restrict__ z16,
    const float* __restrict__ gw, unsigned short* __restrict__ g16)
{
    int wave = threadIdx.x >> 6, lane = threadIdx.x & 63;
    int token = blockIdx.x * 4 + wave;
    const unsigned short* yrow = yv16 + (size_t)token * DINNER;
    const unsigned short* zrow = z16 + (size_t)token * DINNER;
    float4 gv[6];
    float ss = 0.f;
#pragma unroll
    for (int j = 0; j < 6; ++j) {
        int cidx = lane*4 + j*256;
        ushort4 y4 = *(const ushort4*)(yrow + cidx);
        ushort4 z4 = *(const ushort4*)(zrow + cidx);
        gv[j].x = bf2f(y4.x) * siluf(bf2f(z4.x));
        gv[j].y = bf2f(y4.y) * siluf(bf2f(z4.y));
        gv[j].z = bf2f(y4.z) * siluf(bf2f(z4.z));
        gv[j].w = bf2f(y4.w) * siluf(bf2f(z4.w));
        ss += gv[j].x*gv[j].x + gv[j].y*gv[j].y + gv[j].z*gv[j].z + gv[j].w*gv[j].w;
    }
#pragma unroll
    for (int o = 32; o > 0; o >>= 1) ss += __shfl_xor(ss, o, 64);
    float scale = rsqrtf(ss * (1.f/1536.f) + EPSV);
    unsigned short* orow = g16 + (size_t)token * DINNER;
#pragma unroll
    for (int j = 0; j < 6; ++j) {
        int cidx = lane*4 + j*256;
        float4 w4 = *(const float4*)(gw + cidx);
        ushort4 p;
        p.x = f2bf(gv[j].x * scale * w4.x);
        p.y = f2bf(gv[j].y * scale * w4.y);
        p.z = f2bf(gv[j].z * scale * w4.z);
        p.w = f2bf(gv[j].w * scale * w4.w);
        *(ushort4*)(orow + cidx) = p;
    }
}

// ---------------------------------------------------------------------------
extern "C" void kernel_launch(void* const* d_in, const int* in_sizes, int n_in,
                              void* d_out, int out_size, void* d_ws, size_t ws_size,
                              hipStream_t stream)
{
    const float* x        = (const float*)d_in[0];
    const float* ln_w     = (const float*)d_in[1];
    const float* ln_b     = (const float*)d_in[2];
    const float* W_in     = (const float*)d_in[3];
    const float* conv_w   = (const float*)d_in[4];
    const float* conv_b   = (const float*)d_in[5];
    const float* dt_bias  = (const float*)d_in[6];
    const float* A_log    = (const float*)d_in[7];
    const float* Dp       = (const float*)d_in[8];
    const float* gate_w   = (const float*)d_in[9];
    const float* W_out    = (const float*)d_in[10];
    float* out = (float*)d_out;

    char* ws = (char*)d_ws;
    size_t off = 0;
    auto alloc = [&](size_t bytes) -> void* {
        void* p = ws + off;
        off += (bytes + 255) & ~(size_t)255;
        return p;
    };
    unsigned short* u16    = (unsigned short*)alloc((size_t)NTOK*DMODEL*2);            // 12.58 MB
    unsigned short* win16  = (unsigned short*)alloc((size_t)NPAD*DMODEL*2);            //  4.92 MB
    float*          dtv    = (float*)alloc((size_t)NTOK*NHEADS*4);                     //  0.79 MB
    float*          dAv    = (float*)alloc((size_t)NTOK*NHEADS*4);                     //  0.79 MB
    unsigned short* x16    = (unsigned short*)alloc((size_t)NTOK*DINNER*2);            // 25.17 MB
    float*          bcr    = (float*)alloc((size_t)NTOK*32*4);                         //  1.05 MB
    unsigned short* wout16 = (unsigned short*)alloc((size_t)DMODEL*DINNER*2);          //  2.36 MB
    unsigned short* z16    = (unsigned short*)alloc((size_t)NTOK*DINNER*2);            // 25.17 MB
    unsigned short* y16    = (unsigned short*)alloc((size_t)NTOK*DINNER*2);            // 25.17 MB
    unsigned short* g16    = (unsigned short*)alloc((size_t)NTOK*DINNER*2);            // 25.17 MB
    float*          pprod  = (float*)alloc((size_t)BATCH*NHEADS*NCHUNK*4);             //  0.01 MB
    // aliases (lifetime-checked):
    float* hloc   = (float*)u16;    // 12.58 MB == u16 size; u16 dead after gemm1
    float* hstart = (float*)g16;    // 12.58 MB <= g16; g16 written at gate, after pass3 reads hstart
    // high-water ~123 MB

    cvt_kernel<<<(NPAD*DMODEL + DMODEL*DINNER)/256, 256, 0, stream>>>(W_in, W_out, win16, wout16);
    ln_dt_kernel<<<NTOK/4, 256, 0, stream>>>(x, ln_w, ln_b, W_in, dt_bias, A_log, u16, dtv, dAv);
    gemm1_kernel<<<800, 256, 0, stream>>>(u16, win16, z16, x16, bcr);
    scan_pass1<<<BATCH*NHEADS*NCHUNK, 64, 0, stream>>>(x16, bcr, dAv, dtv, conv_w, conv_b, Dp, hloc, pprod, y16);
    scan_pass2<<<BATCH*NHEADS, 64, 0, stream>>>(hloc, pprod, hstart);
    scan_pass3<<<BATCH*NHEADS*NCHUNK, 64, 0, stream>>>(bcr, dAv, conv_w, conv_b, hstart, y16);
    gate_kernel<<<NTOK/4, 256, 0, stream>>>(y16, z16, gate_w, g16);
    gemm2_kernel<<<768, 256, 0, stream>>>(g16, wout16, out, x);
}

// Round 7
// 326.215 us; speedup vs baseline: 1.3468x; 1.0734x over previous
//
#include <hip/hip_runtime.h>
#include <hip/hip_bf16.h>
#include <stdint.h>

#define SEQ      4096
#define BATCH    2
#define NTOK     (BATCH*SEQ)        // 8192
#define DMODEL   768
#define DINNER   1536
#define NHEADS   24
#define HEADDIM  64
#define DSTATE   16
#define NPAD     3200               // GEMM1 padded N (25*128)
#define EPSV     1e-5f
#define CHUNK    64
#define NCHUNK   (SEQ/CHUNK)        // 64
#define SUB      32

typedef __bf16 bf16x8 __attribute__((ext_vector_type(8)));
typedef float  floatx4 __attribute__((ext_vector_type(4)));

__device__ __forceinline__ unsigned short f2bf(float f) {
    union { float f; uint32_t u; } v; v.f = f;
    uint32_t u = v.u;
    uint32_t r = (u + 0x7fffu + ((u >> 16) & 1u)) >> 16;
    return (unsigned short)r;
}

__device__ __forceinline__ float bf2f(unsigned short h) {
    union { uint32_t u; float f; } v; v.u = (uint32_t)h << 16;
    return v.f;
}

__device__ __forceinline__ float bfl(uint32_t u) {
    union { uint32_t u; float f; } v; v.u = u << 16; return v.f;
}
__device__ __forceinline__ float bfh(uint32_t u) {
    union { uint32_t u; float f; } v; v.u = u & 0xffff0000u; return v.f;
}
__device__ __forceinline__ uint32_t packbf(float lo, float hi) {
    return (uint32_t)f2bf(lo) | ((uint32_t)f2bf(hi) << 16);
}

__device__ __forceinline__ float siluf(float x) { return x / (1.f + __expf(-x)); }

__device__ __forceinline__ float dot4(float4 a, float4 b) {
    return a.x*b.x + a.y*b.y + a.z*b.z + a.w*b.w;
}

__device__ __forceinline__ void async_cp16(const void* g, void* l) {
    __builtin_amdgcn_global_load_lds(
        (const __attribute__((address_space(1))) void*)g,
        (__attribute__((address_space(3))) void*)l,
        16, 0, 0);
}

// ---------------------------------------------------------------------------
// Weight conversion.
// ---------------------------------------------------------------------------
__global__ __launch_bounds__(256) void cvt_kernel(
    const float* __restrict__ Win, const float* __restrict__ Wout,
    unsigned short* __restrict__ win16, unsigned short* __restrict__ wout16)
{
    int idx = blockIdx.x * 256 + threadIdx.x;
    const int n1 = NPAD * DMODEL;
    if (idx < n1) {
        int r = idx / DMODEL;
        win16[idx] = (r < 3128) ? f2bf(Win[idx]) : (unsigned short)0;
    } else {
        int i2 = idx - n1;
        if (i2 < DMODEL * DINNER) wout16[i2] = f2bf(Wout[i2]);
    }
}

// ---------------------------------------------------------------------------
// Fused LayerNorm + dt path.  One wave per token.  dt/dA written TRANSPOSED
// [head][token] so scan loads are coalesced.
// ---------------------------------------------------------------------------
__global__ __launch_bounds__(256) void ln_dt_kernel(
    const float* __restrict__ x, const float* __restrict__ lnw, const float* __restrict__ lnb,
    const float* __restrict__ Win, const float* __restrict__ dt_bias, const float* __restrict__ A_log,
    unsigned short* __restrict__ u16, float* __restrict__ dtT, float* __restrict__ dAT)
{
    int wave = threadIdx.x >> 6, lane = threadIdx.x & 63;
    int token = blockIdx.x * 4 + wave;
    const float* row = x + (size_t)token * DMODEL;
    float4 v[3];
    float s = 0.f, ss = 0.f;
#pragma unroll
    for (int j = 0; j < 3; ++j) {
        v[j] = *(const float4*)(row + lane*4 + j*256);
        s  += v[j].x + v[j].y + v[j].z + v[j].w;
        ss += v[j].x*v[j].x + v[j].y*v[j].y + v[j].z*v[j].z + v[j].w*v[j].w;
    }
#pragma unroll
    for (int o = 32; o > 0; o >>= 1) { s += __shfl_xor(s, o, 64); ss += __shfl_xor(ss, o, 64); }
    float mean = s * (1.f/768.f);
    float var  = ss * (1.f/768.f) - mean*mean;
    float rstd = rsqrtf(var + EPSV);
    unsigned short* brow = u16 + (size_t)token * DMODEL;
    float4 u[3];
#pragma unroll
    for (int j = 0; j < 3; ++j) {
        int cidx = lane*4 + j*256;
        float4 w4 = *(const float4*)(lnw + cidx);
        float4 b4 = *(const float4*)(lnb + cidx);
        u[j].x = (v[j].x - mean)*rstd*w4.x + b4.x;
        u[j].y = (v[j].y - mean)*rstd*w4.y + b4.y;
        u[j].z = (v[j].z - mean)*rstd*w4.z + b4.z;
        u[j].w = (v[j].w - mean)*rstd*w4.w + b4.w;
        ushort4 p; p.x = f2bf(u[j].x); p.y = f2bf(u[j].y); p.z = f2bf(u[j].z); p.w = f2bf(u[j].w);
        *(ushort4*)(brow + cidx) = p;
    }
    for (int hh = 0; hh < NHEADS; ++hh) {
        const float* wrow = Win + (size_t)(3104 + hh) * DMODEL;
        float p = 0.f;
#pragma unroll
        for (int j = 0; j < 3; ++j) {
            float4 wv = *(const float4*)(wrow + lane*4 + j*256);
            p += dot4(u[j], wv);
        }
#pragma unroll
        for (int o = 32; o > 0; o >>= 1) p += __shfl_xor(p, o, 64);
        if (lane == 0) {
            float raw = p + dt_bias[hh];
            float dt = (raw > 20.f) ? raw : log1pf(__expf(raw));
            float A = -__expf(A_log[hh]);
            dtT[(size_t)hh*NTOK + token] = dt;
            dAT[(size_t)hh*NTOK + token] = __expf(dt * A);
        }
    }
}

// ---------------------------------------------------------------------------
// GEMM1: C = u16 @ win16^T.  Block 256x128, BK=64 (12 iters), wave tile 128x64.
// XCD swizzle for L2.  LDS rows are 64 elems (128 B); staging applies an
// 8-way chunk XOR swizzle (chunk ^ (row&7)) so fragment ds_read_b128s are
// bank-conflict-free.  Src-side swizzle keeps the LDS dst = base + lane*16.
// ---------------------------------------------------------------------------
__global__ __launch_bounds__(256, 2) void gemm1_kernel(
    const unsigned short* __restrict__ A, const unsigned short* __restrict__ Bt,
    unsigned short* __restrict__ z16, unsigned short* __restrict__ x16,
    float* __restrict__ bcr)
{
    constexpr int K = DMODEL;
    __shared__ unsigned short As[256*64];   // 32 KB
    __shared__ unsigned short Bs[128*64];   // 16 KB
    const int tid  = threadIdx.x;
    const int lane = tid & 63;
    const int wave = tid >> 6;
    const int id   = blockIdx.x;
    const int xcd  = id & 7;
    const int j5   = id >> 3;               // 0..99
    const int m0 = (xcd*4 + (j5 & 3)) * 256;
    const int n0 = (j5 >> 2) * 128;
    const int wm = (wave & 1) * 128;
    const int wn = (wave >> 1) * 64;

    floatx4 acc[8][4];
#pragma unroll
    for (int i = 0; i < 8; ++i)
#pragma unroll
        for (int j = 0; j < 4; ++j) acc[i][j] = floatx4{0.f, 0.f, 0.f, 0.f};

    const int srow8  = lane >> 3;                 // 0..7 row within 8-row op group
    const int schunk = lane & 7;                  // dst 16B chunk
    const int sscol  = (schunk ^ srow8) * 8;      // swizzled src col (elements)

    for (int k0 = 0; k0 < K; k0 += 64) {
        __syncthreads();
#pragma unroll
        for (int o = 0; o < 8; ++o) {             // A: wave rows [wave*64, +64)
            int row = wave*64 + o*8 + srow8;
            async_cp16(A + (size_t)(m0 + row) * K + k0 + sscol, As + row*64 + schunk*8);
        }
#pragma unroll
        for (int o = 0; o < 4; ++o) {             // B: wave rows [wave*32, +32)
            int row = wave*32 + o*8 + srow8;
            async_cp16(Bt + (size_t)(n0 + row) * K + k0 + sscol, Bs + row*64 + schunk*8);
        }
        __syncthreads();
        const int fr  = lane & 15;
        const int q8  = lane >> 4;                // 0..3
        const int key = fr & 7;
#pragma unroll
        for (int ks = 0; ks < 2; ++ks) {
            const int ch = ((ks*4 + q8) ^ key) * 8;
            bf16x8 b[4];
#pragma unroll
            for (int j = 0; j < 4; ++j)
                b[j] = *(const bf16x8*)(Bs + (wn + j*16 + fr)*64 + ch);
#pragma unroll
            for (int i = 0; i < 8; ++i) {
                bf16x8 a = *(const bf16x8*)(As + (wm + i*16 + fr)*64 + ch);
#pragma unroll
                for (int j = 0; j < 4; ++j)
                    acc[i][j] = __builtin_amdgcn_mfma_f32_16x16x32_bf16(a, b[j], acc[i][j], 0, 0, 0);
            }
        }
    }

    const int col = lane & 15;
    const int rq  = (lane >> 4) * 4;
    if (n0 < DINNER) {                      // tiles 0..11 -> z
#pragma unroll
        for (int i = 0; i < 8; ++i)
#pragma unroll
            for (int j = 0; j < 4; ++j)
#pragma unroll
                for (int r = 0; r < 4; ++r) {
                    int gm = m0 + wm + i*16 + rq + r;
                    int gn = n0 + wn + j*16 + col;
                    z16[(size_t)gm * DINNER + gn] = f2bf(acc[i][j][r]);
                }
    } else if (n0 < 3072) {                 // tiles 12..23 -> x (bf16)
#pragma unroll
        for (int i = 0; i < 8; ++i)
#pragma unroll
            for (int j = 0; j < 4; ++j)
#pragma unroll
                for (int r = 0; r < 4; ++r) {
                    int gm = m0 + wm + i*16 + rq + r;
                    int gn = n0 + wn + j*16 + col;
                    x16[(size_t)gm * DINNER + (gn - DINNER)] = f2bf(acc[i][j][r]);
                }
    } else {                                // tile 24: first 32 cols -> bcr f32
#pragma unroll
        for (int i = 0; i < 8; ++i)
#pragma unroll
            for (int j = 0; j < 4; ++j)
#pragma unroll
                for (int r = 0; r < 4; ++r) {
                    int gm = m0 + wm + i*16 + rq + r;
                    int gn = n0 + wn + j*16 + col;
                    if (gn < 3104)
                        bcr[(size_t)gm * 32 + (gn - 3072)] = acc[i][j][r];
                }
    }
}

// ---------------------------------------------------------------------------
// GEMM2: out = g16 @ wout16^T + x.  Block 64x128, BK=64 (24 iters),
// wave tile 32x64, XCD swizzle, same swizzled-LDS scheme.
// ---------------------------------------------------------------------------
__global__ __launch_bounds__(256, 4) void gemm2_kernel(
    const unsigned short* __restrict__ A, const unsigned short* __restrict__ Bt,
    float* __restrict__ Cf, const float* __restrict__ resid)
{
    constexpr int K = DINNER;
    __shared__ unsigned short As[64*64];    //  8 KB
    __shared__ unsigned short Bs[128*64];   // 16 KB
    const int tid  = threadIdx.x;
    const int lane = tid & 63;
    const int wave = tid >> 6;
    const int id   = blockIdx.x;
    const int xcd  = id & 7;
    const int j6   = id >> 3;               // 0..95
    const int m0 = (xcd*16 + j6/6) * 64;
    const int n0 = (j6 % 6) * 128;
    const int wm = (wave & 1) * 32;
    const int wn = (wave >> 1) * 64;

    floatx4 acc[2][4];
#pragma unroll
    for (int i = 0; i < 2; ++i)
#pragma unroll
        for (int j = 0; j < 4; ++j) acc[i][j] = floatx4{0.f, 0.f, 0.f, 0.f};

    const int srow8  = lane >> 3;
    const int schunk = lane & 7;
    const int sscol  = (schunk ^ srow8) * 8;

    for (int k0 = 0; k0 < K; k0 += 64) {
        __syncthreads();
#pragma unroll
        for (int o = 0; o < 2; ++o) {             // A: wave rows [wave*16, +16)
            int row = wave*16 + o*8 + srow8;
            async_cp16(A + (size_t)(m0 + row) * K + k0 + sscol, As + row*64 + schunk*8);
        }
#pragma unroll
        for (int o = 0; o < 4; ++o) {             // B: wave rows [wave*32, +32)
            int row = wave*32 + o*8 + srow8;
            async_cp16(Bt + (size_t)(n0 + row) * K + k0 + sscol, Bs + row*64 + schunk*8);
        }
        __syncthreads();
        const int fr  = lane & 15;
        const int q8  = lane >> 4;
        const int key = fr & 7;
#pragma unroll
        for (int ks = 0; ks < 2; ++ks) {
            const int ch = ((ks*4 + q8) ^ key) * 8;
            bf16x8 a[2], b[4];
#pragma unroll
            for (int i = 0; i < 2; ++i)
                a[i] = *(const bf16x8*)(As + (wm + i*16 + fr)*64 + ch);
#pragma unroll
            for (int j = 0; j < 4; ++j)
                b[j] = *(const bf16x8*)(Bs + (wn + j*16 + fr)*64 + ch);
#pragma unroll
            for (int i = 0; i < 2; ++i)
#pragma unroll
                for (int j = 0; j < 4; ++j)
                    acc[i][j] = __builtin_amdgcn_mfma_f32_16x16x32_bf16(a[i], b[j], acc[i][j], 0, 0, 0);
        }
    }

    const int col = lane & 15;
    const int rq  = (lane >> 4) * 4;
#pragma unroll
    for (int i = 0; i < 2; ++i)
#pragma unroll
        for (int j = 0; j < 4; ++j)
#pragma unroll
            for (int r = 0; r < 4; ++r) {
                int gm = m0 + wm + i*16 + rq + r;
                int gn = n0 + wn + j*16 + col;
                Cf[(size_t)gm * DMODEL + gn] = acc[i][j][r] + resid[(size_t)gm * DMODEL + gn];
            }
}

// ---------------------------------------------------------------------------
// Pass 1: local scan (h init 0) with fused conv+silu, 4 chunks per 256-thr
// block (one per wave).  Emits y_local bf16, hloc end-state, pprod.
// dt/dA read from transposed [head][token] (coalesced).
// ---------------------------------------------------------------------------
__global__ __launch_bounds__(256) void scan_pass1(
    const unsigned short* __restrict__ x16, const float* __restrict__ bcr,
    const float* __restrict__ dAT, const float* __restrict__ dtT,
    const float* __restrict__ cw, const float* __restrict__ cb, const float* __restrict__ Dp,
    float* __restrict__ hloc, float* __restrict__ pprod, unsigned short* __restrict__ ylocal16)
{
    int wave = threadIdx.x >> 6, lane = threadIdx.x & 63;
    int blk = blockIdx.x * 4 + wave;
    int c = blk & (NCHUNK-1), bh = blk >> 6;
    int h = bh % NHEADS, b = bh / NHEADS;
    int row0 = b * SEQ + c * CHUNK;
    int l0 = c * CHUNK;
    int tb = h * NTOK + row0;             // transposed dt/dA base
    __shared__ float bcraw[4][35][32];
    __shared__ float bcsc[4][32][32];     // conv'd: 0..15 = B, 16..31 = C
    __shared__ float av[4][32], dv[4][32];

    const int cx = h*64 + lane;
    float cwx0 = cw[cx*4+0], cwx1 = cw[cx*4+1], cwx2 = cw[cx*4+2], cwx3 = cw[cx*4+3];
    float cbx = cb[cx];
    const int nBC = lane & 31;
    float cwc0 = cw[(DINNER+nBC)*4+0], cwc1 = cw[(DINNER+nBC)*4+1];
    float cwc2 = cw[(DINNER+nBC)*4+2], cwc3 = cw[(DINNER+nBC)*4+3];
    float cbc = cb[DINNER+nBC];
    float Dh = Dp[h];

    float xm3 = (l0 >= 3) ? bf2f(x16[(size_t)(row0-3)*DINNER + cx]) : 0.f;
    float xm2 = (l0 >= 2) ? bf2f(x16[(size_t)(row0-2)*DINNER + cx]) : 0.f;
    float xm1 = (l0 >= 1) ? bf2f(x16[(size_t)(row0-1)*DINNER + cx]) : 0.f;

    float hst[16];
#pragma unroll
    for (int n = 0; n < 16; ++n) hst[n] = 0.f;
    float aprod = 1.f;

    for (int sc = 0; sc < CHUNK/SUB; ++sc) {
        int rb = row0 + sc * SUB;
        int lb = l0 + sc * SUB;
        __syncthreads();
#pragma unroll
        for (int it = 0; it < 5; ++it) {        // B+C rows rb-3..rb+31 (35x8 float4)
            int idx = it*64 + lane;
            if (idx < 280) {
                int s = idx >> 3, q = idx & 7;
                float4 val = {0.f,0.f,0.f,0.f};
                if (lb - 3 + s >= 0)
                    val = *(const float4*)(bcr + (size_t)(rb-3+s)*32 + q*4);
                *(float4*)&bcraw[wave][s][q*4] = val;
            }
        }
        if (lane < 32) av[wave][lane] = dAT[(size_t)tb + sc*SUB + lane];
        else           dv[wave][lane-32] = dtT[(size_t)tb + sc*SUB + lane - 32];
        float xr[SUB];
#pragma unroll
        for (int s = 0; s < SUB; ++s)
            xr[s] = bf2f(x16[(size_t)(rb+s)*DINNER + cx]);
        __syncthreads();
#pragma unroll
        for (int it = 0; it < 16; ++it) {       // conv B,C -> bcsc
            int s = it*2 + (lane >> 5);
            float v = cbc + bcraw[wave][s][nBC]*cwc0 + bcraw[wave][s+1][nBC]*cwc1
                          + bcraw[wave][s+2][nBC]*cwc2 + bcraw[wave][s+3][nBC]*cwc3;
            bcsc[wave][s][nBC] = siluf(v);
        }
        __syncthreads();
#pragma unroll 4
        for (int s = 0; s < SUB; ++s) {
            float a = av[wave][s];
            float xc = siluf(cbx + xm3*cwx0 + xm2*cwx1 + xm1*cwx2 + xr[s]*cwx3);
            xm3 = xm2; xm2 = xm1; xm1 = xr[s];
            float scale = dv[wave][s] * xc;
            const float* bp = bcsc[wave][s];
            float y = Dh * xc;
#pragma unroll
            for (int n = 0; n < 16; ++n) hst[n] = a*hst[n] + scale*bp[n];
#pragma unroll
            for (int n = 0; n < 16; ++n) y += hst[n] * bp[16+n];
            aprod *= a;
            ylocal16[(size_t)(rb+s)*DINNER + cx] = f2bf(y);
        }
    }
    float* o = hloc + (size_t)blk * 1024 + lane * 16;
#pragma unroll
    for (int n = 0; n < 16; ++n) o[n] = hst[n];
    if (lane == 0) pprod[blk] = aprod;
}

// Pass 2: sequential recombine over NCHUNK chunks per (b,h).
__global__ __launch_bounds__(64) void scan_pass2(
    const float* __restrict__ hloc, const float* __restrict__ pprod, float* __restrict__ hstart)
{
    int bh = blockIdx.x, lane = threadIdx.x;
    float hst[16];
#pragma unroll
    for (int n = 0; n < 16; ++n) hst[n] = 0.f;
    for (int c = 0; c < NCHUNK; ++c) {
        int blk = bh * NCHUNK + c;
        float* o = hstart + (size_t)blk * 1024 + lane * 16;
#pragma unroll
        for (int n = 0; n < 16; ++n) o[n] = hst[n];
        float P = pprod[blk];
        const float* hl = hloc + (size_t)blk * 1024 + lane * 16;
#pragma unroll
        for (int n = 0; n < 16; ++n) hst[n] = P * hst[n] + hl[n];
    }
}

// ---------------------------------------------------------------------------
// Pass 3 (lite): y[t] += cumdecay[t] * (C[t] . h_start), in-place, 4 chunks
// per block.
// ---------------------------------------------------------------------------
__global__ __launch_bounds__(256) void scan_pass3(
    const float* __restrict__ bcr, const float* __restrict__ dAT,
    const float* __restrict__ cw, const float* __restrict__ cb,
    const float* __restrict__ hstart, unsigned short* __restrict__ ylocal16)
{
    int wave = threadIdx.x >> 6, lane = threadIdx.x & 63;
    int blk = blockIdx.x * 4 + wave;
    int c = blk & (NCHUNK-1), bh = blk >> 6;
    int h = bh % NHEADS, b = bh / NHEADS;
    int row0 = b * SEQ + c * CHUNK;
    int l0 = c * CHUNK;
    int tb = h * NTOK + row0;
    __shared__ float craw[4][35][16];
    __shared__ float csc[4][32][16];
    __shared__ float av[4][32];

    const int cx = h*64 + lane;
    const int nC = lane & 15;
    float cwc0 = cw[(DINNER+16+nC)*4+0], cwc1 = cw[(DINNER+16+nC)*4+1];
    float cwc2 = cw[(DINNER+16+nC)*4+2], cwc3 = cw[(DINNER+16+nC)*4+3];
    float cbc = cb[DINNER+16+nC];

    float h0[16];
    const float* hs = hstart + (size_t)blk * 1024 + lane * 16;
#pragma unroll
    for (int n = 0; n < 16; ++n) h0[n] = hs[n];
    float cd = 1.f;

    for (int sc = 0; sc < CHUNK/SUB; ++sc) {
        int rb = row0 + sc * SUB;
        int lb = l0 + sc * SUB;
        __syncthreads();
#pragma unroll
        for (int it = 0; it < 3; ++it) {        // C rows rb-3..rb+31 (35x4 float4)
            int idx = it*64 + lane;
            if (idx < 140) {
                int s = idx >> 2, q = idx & 3;
                float4 val = {0.f,0.f,0.f,0.f};
                if (lb - 3 + s >= 0)
                    val = *(const float4*)(bcr + (size_t)(rb-3+s)*32 + 16 + q*4);
                *(float4*)&craw[wave][s][q*4] = val;
            }
        }
        if (lane < 32) av[wave][lane] = dAT[(size_t)tb + sc*SUB + lane];
        float yr[SUB];
#pragma unroll
        for (int s = 0; s < SUB; ++s)
            yr[s] = bf2f(ylocal16[(size_t)(rb+s)*DINNER + cx]);
        __syncthreads();
#pragma unroll
        for (int it = 0; it < 8; ++it) {        // conv C -> csc
            int s = it*4 + (lane >> 4);
            float v = cbc + craw[wave][s][nC]*cwc0 + craw[wave][s+1][nC]*cwc1
                          + craw[wave][s+2][nC]*cwc2 + craw[wave][s+3][nC]*cwc3;
            csc[wave][s][nC] = siluf(v);
        }
        __syncthreads();
#pragma unroll 4
        for (int s = 0; s < SUB; ++s) {
            cd *= av[wave][s];
            const float* cp = csc[wave][s];
            float corr = 0.f;
#pragma unroll
            for (int n = 0; n < 16; ++n) corr += cp[n] * h0[n];
            ylocal16[(size_t)(rb+s)*DINNER + cx] = f2bf(yr[s] + cd * corr);
        }
    }
}

// ---------------------------------------------------------------------------
// Gating + RMSNorm -> bf16 (16 B loads/stores)
// ---------------------------------------------------------------------------
__global__ __launch_bounds__(256) void gate_kernel(
    const unsigned short* __restrict__ yv16, const unsigned short* __restrict__ z16,
    const float* __restrict__ gw, unsigned short* __restrict__ g16)
{
    int wave = threadIdx.x >> 6, lane = threadIdx.x & 63;
    int token = blockIdx.x * 4 + wave;
    const uint4* yrow = (const uint4*)(yv16 + (size_t)token * DINNER);
    const uint4* zrow = (const uint4*)(z16 + (size_t)token * DINNER);
    float g[3][8];
    float ss = 0.f;
#pragma unroll
    for (int j = 0; j < 3; ++j) {
        uint4 y8 = yrow[lane + j*64];
        uint4 z8 = zrow[lane + j*64];
        const uint32_t* yp = (const uint32_t*)&y8;
        const uint32_t* zp = (const uint32_t*)&z8;
#pragma unroll
        for (int q = 0; q < 4; ++q) {
            float a = bfl(yp[q]) * siluf(bfl(zp[q]));
            float bvl = bfh(yp[q]) * siluf(bfh(zp[q]));
            g[j][q*2]   = a;
            g[j][q*2+1] = bvl;
            ss += a*a + bvl*bvl;
        }
    }
#pragma unroll
    for (int o = 32; o > 0; o >>= 1) ss += __shfl_xor(ss, o, 64);
    float scale = rsqrtf(ss * (1.f/1536.f) + EPSV);
    uint4* orow = (uint4*)(g16 + (size_t)token * DINNER);
#pragma unroll
    for (int j = 0; j < 3; ++j) {
        int ebase = (lane + j*64) * 8;
        float4 w0 = *(const float4*)(gw + ebase);
        float4 w1 = *(const float4*)(gw + ebase + 4);
        uint4 p;
        p.x = packbf(g[j][0]*scale*w0.x, g[j][1]*scale*w0.y);
        p.y = packbf(g[j][2]*scale*w0.z, g[j][3]*scale*w0.w);
        p.z = packbf(g[j][4]*scale*w1.x, g[j][5]*scale*w1.y);
        p.w = packbf(g[j][6]*scale*w1.z, g[j][7]*scale*w1.w);
        orow[lane + j*64] = p;
    }
}

// ---------------------------------------------------------------------------
extern "C" void kernel_launch(void* const* d_in, const int* in_sizes, int n_in,
                              void* d_out, int out_size, void* d_ws, size_t ws_size,
                              hipStream_t stream)
{
    const float* x        = (const float*)d_in[0];
    const float* ln_w     = (const float*)d_in[1];
    const float* ln_b     = (const float*)d_in[2];
    const float* W_in     = (const float*)d_in[3];
    const float* conv_w   = (const float*)d_in[4];
    const float* conv_b   = (const float*)d_in[5];
    const float* dt_bias  = (const float*)d_in[6];
    const float* A_log    = (const float*)d_in[7];
    const float* Dp       = (const float*)d_in[8];
    const float* gate_w   = (const float*)d_in[9];
    const float* W_out    = (const float*)d_in[10];
    float* out = (float*)d_out;

    char* ws = (char*)d_ws;
    size_t off = 0;
    auto alloc = [&](size_t bytes) -> void* {
        void* p = ws + off;
        off += (bytes + 255) & ~(size_t)255;
        return p;
    };
    unsigned short* u16    = (unsigned short*)alloc((size_t)NTOK*DMODEL*2);            // 12.58 MB
    unsigned short* win16  = (unsigned short*)alloc((size_t)NPAD*DMODEL*2);            //  4.92 MB
    float*          dtT    = (float*)alloc((size_t)NTOK*NHEADS*4);                     //  0.79 MB
    float*          dAT    = (float*)alloc((size_t)NTOK*NHEADS*4);                     //  0.79 MB
    unsigned short* x16    = (unsigned short*)alloc((size_t)NTOK*DINNER*2);            // 25.17 MB
    float*          bcr    = (float*)alloc((size_t)NTOK*32*4);                         //  1.05 MB
    unsigned short* wout16 = (unsigned short*)alloc((size_t)DMODEL*DINNER*2);          //  2.36 MB
    unsigned short* z16    = (unsigned short*)alloc((size_t)NTOK*DINNER*2);            // 25.17 MB
    unsigned short* y16    = (unsigned short*)alloc((size_t)NTOK*DINNER*2);            // 25.17 MB
    unsigned short* g16    = (unsigned short*)alloc((size_t)NTOK*DINNER*2);            // 25.17 MB
    float*          pprod  = (float*)alloc((size_t)BATCH*NHEADS*NCHUNK*4);             //  0.01 MB
    // aliases (lifetime-checked):
    float* hloc   = (float*)u16;    // 12.58 MB == u16 size; u16 dead after gemm1
    float* hstart = (float*)g16;    // 12.58 MB <= g16; g16 first written at gate (after pass3)
    // high-water ~123 MB

    cvt_kernel<<<(NPAD*DMODEL + DMODEL*DINNER)/256, 256, 0, stream>>>(W_in, W_out, win16, wout16);
    ln_dt_kernel<<<NTOK/4, 256, 0, stream>>>(x, ln_w, ln_b, W_in, dt_bias, A_log, u16, dtT, dAT);
    gemm1_kernel<<<800, 256, 0, stream>>>(u16, win16, z16, x16, bcr);
    scan_pass1<<<BATCH*NHEADS*NCHUNK/4, 256, 0, stream>>>(x16, bcr, dAT, dtT, conv_w, conv_b, Dp, hloc, pprod, y16);
    scan_pass2<<<BATCH*NHEADS, 64, 0, stream>>>(hloc, pprod, hstart);
    scan_pass3<<<BATCH*NHEADS*NCHUNK/4, 256, 0, stream>>>(bcr, dAT, conv_w, conv_b, hstart, y16);
    gate_kernel<<<NTOK/4, 256, 0, stream>>>(y16, z16, gate_w, g16);
    gemm2_kernel<<<768, 256, 0, stream>>>(g16, wout16, out, x);
}

// Round 8
// 283.273 us; speedup vs baseline: 1.5509x; 1.1516x over previous
//
#include <hip/hip_runtime.h>
#include <hip/hip_bf16.h>
#include <stdint.h>

#define SEQ      4096
#define BATCH    2
#define NTOK     (BATCH*SEQ)        // 8192
#define DMODEL   768
#define DINNER   1536
#define NHEADS   24
#define HEADDIM  64
#define DSTATE   16
#define NPAD     3200               // GEMM1 padded N (25*128)
#define EPSV     1e-5f
#define CHUNK    64
#define NCHUNK   (SEQ/CHUNK)        // 64
#define SUB      32

typedef __bf16 bf16x8 __attribute__((ext_vector_type(8)));
typedef float  floatx4 __attribute__((ext_vector_type(4)));

__device__ __forceinline__ unsigned short f2bf(float f) {
    union { float f; uint32_t u; } v; v.f = f;
    uint32_t u = v.u;
    uint32_t r = (u + 0x7fffu + ((u >> 16) & 1u)) >> 16;
    return (unsigned short)r;
}

__device__ __forceinline__ float bf2f(unsigned short h) {
    union { uint32_t u; float f; } v; v.u = (uint32_t)h << 16;
    return v.f;
}

__device__ __forceinline__ float bfl(uint32_t u) {
    union { uint32_t u; float f; } v; v.u = u << 16; return v.f;
}
__device__ __forceinline__ float bfh(uint32_t u) {
    union { uint32_t u; float f; } v; v.u = u & 0xffff0000u; return v.f;
}
__device__ __forceinline__ uint32_t packbf(float lo, float hi) {
    return (uint32_t)f2bf(lo) | ((uint32_t)f2bf(hi) << 16);
}

__device__ __forceinline__ float siluf(float x) { return x / (1.f + __expf(-x)); }

__device__ __forceinline__ void async_cp16(const void* g, void* l) {
    __builtin_amdgcn_global_load_lds(
        (const __attribute__((address_space(1))) void*)g,
        (__attribute__((address_space(3))) void*)l,
        16, 0, 0);
}

// ---------------------------------------------------------------------------
// Weight conversion.
// ---------------------------------------------------------------------------
__global__ __launch_bounds__(256) void cvt_kernel(
    const float* __restrict__ Win, const float* __restrict__ Wout,
    unsigned short* __restrict__ win16, unsigned short* __restrict__ wout16)
{
    int idx = blockIdx.x * 256 + threadIdx.x;
    const int n1 = NPAD * DMODEL;
    if (idx < n1) {
        int r = idx / DMODEL;
        win16[idx] = (r < 3128) ? f2bf(Win[idx]) : (unsigned short)0;
    } else {
        int i2 = idx - n1;
        if (i2 < DMODEL * DINNER) wout16[i2] = f2bf(Wout[i2]);
    }
}

// ---------------------------------------------------------------------------
// LayerNorm only (dt moved to gemm1 epilogue + dt_kernel).  One wave/token.
// ---------------------------------------------------------------------------
__global__ __launch_bounds__(256) void ln_kernel(
    const float* __restrict__ x, const float* __restrict__ lnw, const float* __restrict__ lnb,
    unsigned short* __restrict__ u16)
{
    int wave = threadIdx.x >> 6, lane = threadIdx.x & 63;
    int token = blockIdx.x * 4 + wave;
    const float* row = x + (size_t)token * DMODEL;
    float4 v[3];
    float s = 0.f, ss = 0.f;
#pragma unroll
    for (int j = 0; j < 3; ++j) {
        v[j] = *(const float4*)(row + lane*4 + j*256);
        s  += v[j].x + v[j].y + v[j].z + v[j].w;
        ss += v[j].x*v[j].x + v[j].y*v[j].y + v[j].z*v[j].z + v[j].w*v[j].w;
    }
#pragma unroll
    for (int o = 32; o > 0; o >>= 1) { s += __shfl_xor(s, o, 64); ss += __shfl_xor(ss, o, 64); }
    float mean = s * (1.f/768.f);
    float var  = ss * (1.f/768.f) - mean*mean;
    float rstd = rsqrtf(var + EPSV);
    unsigned short* brow = u16 + (size_t)token * DMODEL;
#pragma unroll
    for (int j = 0; j < 3; ++j) {
        int cidx = lane*4 + j*256;
        float4 w4 = *(const float4*)(lnw + cidx);
        float4 b4 = *(const float4*)(lnb + cidx);
        float a0 = (v[j].x - mean)*rstd*w4.x + b4.x;
        float a1 = (v[j].y - mean)*rstd*w4.y + b4.y;
        float a2 = (v[j].z - mean)*rstd*w4.z + b4.z;
        float a3 = (v[j].w - mean)*rstd*w4.w + b4.w;
        ushort4 p; p.x = f2bf(a0); p.y = f2bf(a1); p.z = f2bf(a2); p.w = f2bf(a3);
        *(ushort4*)(brow + cidx) = p;
    }
}

// ---------------------------------------------------------------------------
// dt: softplus(raw + bias), dA = exp(dt * -exp(A_log)).  Reads raw24 from
// gemm1's tile-24 store; writes transposed [head][token] coalesced.
// ---------------------------------------------------------------------------
__global__ __launch_bounds__(256) void dt_kernel(
    const float* __restrict__ raw24, const float* __restrict__ dt_bias,
    const float* __restrict__ A_log, float* __restrict__ dtT, float* __restrict__ dAT)
{
    int tid = blockIdx.x * 256 + threadIdx.x;   // 0 .. NHEADS*NTOK-1
    int h   = tid >> 13;                        // NTOK = 8192
    int tok = tid & (NTOK-1);
    float raw = raw24[(size_t)tok*NHEADS + h] + dt_bias[h];
    float dt = (raw > 20.f) ? raw : log1pf(__expf(raw));
    float A = -__expf(A_log[h]);
    dtT[tid] = dt;
    dAT[tid] = __expf(dt * A);
}

// ---------------------------------------------------------------------------
// GEMM1: C = u16 @ win16^T.  Block 256x128, BK=64 (12 iters), wave tile 128x64.
// XCD swizzle for L2; 8-way chunk XOR LDS swizzle (src-side).
// Split store: z16 | x16 | bcr(f32 32 cols) | raw24(f32 24 cols).
// ---------------------------------------------------------------------------
__global__ __launch_bounds__(256, 2) void gemm1_kernel(
    const unsigned short* __restrict__ A, const unsigned short* __restrict__ Bt,
    unsigned short* __restrict__ z16, unsigned short* __restrict__ x16,
    float* __restrict__ bcr, float* __restrict__ raw24)
{
    constexpr int K = DMODEL;
    __shared__ unsigned short As[256*64];   // 32 KB
    __shared__ unsigned short Bs[128*64];   // 16 KB
    const int tid  = threadIdx.x;
    const int lane = tid & 63;
    const int wave = tid >> 6;
    const int id   = blockIdx.x;
    const int xcd  = id & 7;
    const int j5   = id >> 3;               // 0..99
    const int m0 = (xcd*4 + (j5 & 3)) * 256;
    const int n0 = (j5 >> 2) * 128;
    const int wm = (wave & 1) * 128;
    const int wn = (wave >> 1) * 64;

    floatx4 acc[8][4];
#pragma unroll
    for (int i = 0; i < 8; ++i)
#pragma unroll
        for (int j = 0; j < 4; ++j) acc[i][j] = floatx4{0.f, 0.f, 0.f, 0.f};

    const int srow8  = lane >> 3;                 // 0..7
    const int schunk = lane & 7;
    const int sscol  = (schunk ^ srow8) * 8;

    for (int k0 = 0; k0 < K; k0 += 64) {
        __syncthreads();
#pragma unroll
        for (int o = 0; o < 8; ++o) {
            int row = wave*64 + o*8 + srow8;
            async_cp16(A + (size_t)(m0 + row) * K + k0 + sscol, As + row*64 + schunk*8);
        }
#pragma unroll
        for (int o = 0; o < 4; ++o) {
            int row = wave*32 + o*8 + srow8;
            async_cp16(Bt + (size_t)(n0 + row) * K + k0 + sscol, Bs + row*64 + schunk*8);
        }
        __syncthreads();
        const int fr  = lane & 15;
        const int q8  = lane >> 4;
        const int key = fr & 7;
#pragma unroll
        for (int ks = 0; ks < 2; ++ks) {
            const int ch = ((ks*4 + q8) ^ key) * 8;
            bf16x8 b[4];
#pragma unroll
            for (int j = 0; j < 4; ++j)
                b[j] = *(const bf16x8*)(Bs + (wn + j*16 + fr)*64 + ch);
#pragma unroll
            for (int i = 0; i < 8; ++i) {
                bf16x8 a = *(const bf16x8*)(As + (wm + i*16 + fr)*64 + ch);
#pragma unroll
                for (int j = 0; j < 4; ++j)
                    acc[i][j] = __builtin_amdgcn_mfma_f32_16x16x32_bf16(a, b[j], acc[i][j], 0, 0, 0);
            }
        }
    }

    const int col = lane & 15;
    const int rq  = (lane >> 4) * 4;
    if (n0 < DINNER) {                      // tiles 0..11 -> z
#pragma unroll
        for (int i = 0; i < 8; ++i)
#pragma unroll
            for (int j = 0; j < 4; ++j)
#pragma unroll
                for (int r = 0; r < 4; ++r) {
                    int gm = m0 + wm + i*16 + rq + r;
                    int gn = n0 + wn + j*16 + col;
                    z16[(size_t)gm * DINNER + gn] = f2bf(acc[i][j][r]);
                }
    } else if (n0 < 3072) {                 // tiles 12..23 -> x (bf16)
#pragma unroll
        for (int i = 0; i < 8; ++i)
#pragma unroll
            for (int j = 0; j < 4; ++j)
#pragma unroll
                for (int r = 0; r < 4; ++r) {
                    int gm = m0 + wm + i*16 + rq + r;
                    int gn = n0 + wn + j*16 + col;
                    x16[(size_t)gm * DINNER + (gn - DINNER)] = f2bf(acc[i][j][r]);
                }
    } else {                                // tile 24: B/C -> bcr, dt -> raw24
#pragma unroll
        for (int i = 0; i < 8; ++i)
#pragma unroll
            for (int j = 0; j < 4; ++j)
#pragma unroll
                for (int r = 0; r < 4; ++r) {
                    int gm = m0 + wm + i*16 + rq + r;
                    int gn = n0 + wn + j*16 + col;
                    if (gn < 3104)
                        bcr[(size_t)gm * 32 + (gn - 3072)] = acc[i][j][r];
                    else if (gn < 3128)
                        raw24[(size_t)gm * NHEADS + (gn - 3104)] = acc[i][j][r];
                }
    }
}

// ---------------------------------------------------------------------------
// GEMM2: out = g16 @ wout16^T + x.  Block 64x128, BK=64, XCD swizzle.
// ---------------------------------------------------------------------------
__global__ __launch_bounds__(256, 4) void gemm2_kernel(
    const unsigned short* __restrict__ A, const unsigned short* __restrict__ Bt,
    float* __restrict__ Cf, const float* __restrict__ resid)
{
    constexpr int K = DINNER;
    __shared__ unsigned short As[64*64];    //  8 KB
    __shared__ unsigned short Bs[128*64];   // 16 KB
    const int tid  = threadIdx.x;
    const int lane = tid & 63;
    const int wave = tid >> 6;
    const int id   = blockIdx.x;
    const int xcd  = id & 7;
    const int j6   = id >> 3;               // 0..95
    const int m0 = (xcd*16 + j6/6) * 64;
    const int n0 = (j6 % 6) * 128;
    const int wm = (wave & 1) * 32;
    const int wn = (wave >> 1) * 64;

    floatx4 acc[2][4];
#pragma unroll
    for (int i = 0; i < 2; ++i)
#pragma unroll
        for (int j = 0; j < 4; ++j) acc[i][j] = floatx4{0.f, 0.f, 0.f, 0.f};

    const int srow8  = lane >> 3;
    const int schunk = lane & 7;
    const int sscol  = (schunk ^ srow8) * 8;

    for (int k0 = 0; k0 < K; k0 += 64) {
        __syncthreads();
#pragma unroll
        for (int o = 0; o < 2; ++o) {
            int row = wave*16 + o*8 + srow8;
            async_cp16(A + (size_t)(m0 + row) * K + k0 + sscol, As + row*64 + schunk*8);
        }
#pragma unroll
        for (int o = 0; o < 4; ++o) {
            int row = wave*32 + o*8 + srow8;
            async_cp16(Bt + (size_t)(n0 + row) * K + k0 + sscol, Bs + row*64 + schunk*8);
        }
        __syncthreads();
        const int fr  = lane & 15;
        const int q8  = lane >> 4;
        const int key = fr & 7;
#pragma unroll
        for (int ks = 0; ks < 2; ++ks) {
            const int ch = ((ks*4 + q8) ^ key) * 8;
            bf16x8 a[2], b[4];
#pragma unroll
            for (int i = 0; i < 2; ++i)
                a[i] = *(const bf16x8*)(As + (wm + i*16 + fr)*64 + ch);
#pragma unroll
            for (int j = 0; j < 4; ++j)
                b[j] = *(const bf16x8*)(Bs + (wn + j*16 + fr)*64 + ch);
#pragma unroll
            for (int i = 0; i < 2; ++i)
#pragma unroll
                for (int j = 0; j < 4; ++j)
                    acc[i][j] = __builtin_amdgcn_mfma_f32_16x16x32_bf16(a[i], b[j], acc[i][j], 0, 0, 0);
        }
    }

    const int col = lane & 15;
    const int rq  = (lane >> 4) * 4;
#pragma unroll
    for (int i = 0; i < 2; ++i)
#pragma unroll
        for (int j = 0; j < 4; ++j)
#pragma unroll
            for (int r = 0; r < 4; ++r) {
                int gm = m0 + wm + i*16 + rq + r;
                int gn = n0 + wn + j*16 + col;
                Cf[(size_t)gm * DMODEL + gn] = acc[i][j][r] + resid[(size_t)gm * DMODEL + gn];
            }
}

// ---------------------------------------------------------------------------
// Pass 1: local scan (h init 0) with fused conv+silu, 4 chunks per 256-thr
// block (one per wave).  Emits y_local bf16, hloc end-state, pprod.
// ---------------------------------------------------------------------------
__global__ __launch_bounds__(256) void scan_pass1(
    const unsigned short* __restrict__ x16, const float* __restrict__ bcr,
    const float* __restrict__ dAT, const float* __restrict__ dtT,
    const float* __restrict__ cw, const float* __restrict__ cb, const float* __restrict__ Dp,
    float* __restrict__ hloc, float* __restrict__ pprod, unsigned short* __restrict__ ylocal16)
{
    int wave = threadIdx.x >> 6, lane = threadIdx.x & 63;
    int blk = blockIdx.x * 4 + wave;
    int c = blk & (NCHUNK-1), bh = blk >> 6;
    int h = bh % NHEADS, b = bh / NHEADS;
    int row0 = b * SEQ + c * CHUNK;
    int l0 = c * CHUNK;
    int tb = h * NTOK + row0;
    __shared__ float bcraw[4][35][32];
    __shared__ float bcsc[4][32][32];     // conv'd: 0..15 = B, 16..31 = C
    __shared__ float av[4][32], dv[4][32];

    const int cx = h*64 + lane;
    float cwx0 = cw[cx*4+0], cwx1 = cw[cx*4+1], cwx2 = cw[cx*4+2], cwx3 = cw[cx*4+3];
    float cbx = cb[cx];
    const int nBC = lane & 31;
    float cwc0 = cw[(DINNER+nBC)*4+0], cwc1 = cw[(DINNER+nBC)*4+1];
    float cwc2 = cw[(DINNER+nBC)*4+2], cwc3 = cw[(DINNER+nBC)*4+3];
    float cbc = cb[DINNER+nBC];
    float Dh = Dp[h];

    float xm3 = (l0 >= 3) ? bf2f(x16[(size_t)(row0-3)*DINNER + cx]) : 0.f;
    float xm2 = (l0 >= 2) ? bf2f(x16[(size_t)(row0-2)*DINNER + cx]) : 0.f;
    float xm1 = (l0 >= 1) ? bf2f(x16[(size_t)(row0-1)*DINNER + cx]) : 0.f;

    float hst[16];
#pragma unroll
    for (int n = 0; n < 16; ++n) hst[n] = 0.f;
    float aprod = 1.f;

    for (int sc = 0; sc < CHUNK/SUB; ++sc) {
        int rb = row0 + sc * SUB;
        int lb = l0 + sc * SUB;
        __syncthreads();
#pragma unroll
        for (int it = 0; it < 5; ++it) {        // B+C rows rb-3..rb+31 (35x8 float4)
            int idx = it*64 + lane;
            if (idx < 280) {
                int s = idx >> 3, q = idx & 7;
                float4 val = {0.f,0.f,0.f,0.f};
                if (lb - 3 + s >= 0)
                    val = *(const float4*)(bcr + (size_t)(rb-3+s)*32 + q*4);
                *(float4*)&bcraw[wave][s][q*4] = val;
            }
        }
        if (lane < 32) av[wave][lane] = dAT[(size_t)tb + sc*SUB + lane];
        else           dv[wave][lane-32] = dtT[(size_t)tb + sc*SUB + lane - 32];
        float xr[SUB];
#pragma unroll
        for (int s = 0; s < SUB; ++s)
            xr[s] = bf2f(x16[(size_t)(rb+s)*DINNER + cx]);
        __syncthreads();
#pragma unroll
        for (int it = 0; it < 16; ++it) {       // conv B,C -> bcsc
            int s = it*2 + (lane >> 5);
            float v = cbc + bcraw[wave][s][nBC]*cwc0 + bcraw[wave][s+1][nBC]*cwc1
                          + bcraw[wave][s+2][nBC]*cwc2 + bcraw[wave][s+3][nBC]*cwc3;
            bcsc[wave][s][nBC] = siluf(v);
        }
        __syncthreads();
#pragma unroll 4
        for (int s = 0; s < SUB; ++s) {
            float a = av[wave][s];
            float xc = siluf(cbx + xm3*cwx0 + xm2*cwx1 + xm1*cwx2 + xr[s]*cwx3);
            xm3 = xm2; xm2 = xm1; xm1 = xr[s];
            float scale = dv[wave][s] * xc;
            const float* bp = bcsc[wave][s];
            float y = Dh * xc;
#pragma unroll
            for (int n = 0; n < 16; ++n) hst[n] = a*hst[n] + scale*bp[n];
#pragma unroll
            for (int n = 0; n < 16; ++n) y += hst[n] * bp[16+n];
            aprod *= a;
            ylocal16[(size_t)(rb+s)*DINNER + cx] = f2bf(y);
        }
    }
    float* o = hloc + (size_t)blk * 1024 + lane * 16;
#pragma unroll
    for (int n = 0; n < 16; ++n) o[n] = hst[n];
    if (lane == 0) pprod[blk] = aprod;
}

// Pass 2: sequential recombine over NCHUNK chunks per (b,h).
__global__ __launch_bounds__(64) void scan_pass2(
    const float* __restrict__ hloc, const float* __restrict__ pprod, float* __restrict__ hstart)
{
    int bh = blockIdx.x, lane = threadIdx.x;
    float hst[16];
#pragma unroll
    for (int n = 0; n < 16; ++n) hst[n] = 0.f;
    for (int c = 0; c < NCHUNK; ++c) {
        int blk = bh * NCHUNK + c;
        float* o = hstart + (size_t)blk * 1024 + lane * 16;
#pragma unroll
        for (int n = 0; n < 16; ++n) o[n] = hst[n];
        float P = pprod[blk];
        const float* hl = hloc + (size_t)blk * 1024 + lane * 16;
#pragma unroll
        for (int n = 0; n < 16; ++n) hst[n] = P * hst[n] + hl[n];
    }
}

// ---------------------------------------------------------------------------
// Pass 3 (lite): y[t] += cumdecay[t] * (C[t] . h_start), in-place, 4 chunks
// per block.
// ---------------------------------------------------------------------------
__global__ __launch_bounds__(256) void scan_pass3(
    const float* __restrict__ bcr, const float* __restrict__ dAT,
    const float* __restrict__ cw, const float* __restrict__ cb,
    const float* __restrict__ hstart, unsigned short* __restrict__ ylocal16)
{
    int wave = threadIdx.x >> 6, lane = threadIdx.x & 63;
    int blk = blockIdx.x * 4 + wave;
    int c = blk & (NCHUNK-1), bh = blk >> 6;
    int h = bh % NHEADS, b = bh / NHEADS;
    int row0 = b * SEQ + c * CHUNK;
    int l0 = c * CHUNK;
    int tb = h * NTOK + row0;
    __shared__ float craw[4][35][16];
    __shared__ float csc[4][32][16];
    __shared__ float av[4][32];

    const int cx = h*64 + lane;
    const int nC = lane & 15;
    float cwc0 = cw[(DINNER+16+nC)*4+0], cwc1 = cw[(DINNER+16+nC)*4+1];
    float cwc2 = cw[(DINNER+16+nC)*4+2], cwc3 = cw[(DINNER+16+nC)*4+3];
    float cbc = cb[DINNER+16+nC];

    float h0[16];
    const float* hs = hstart + (size_t)blk * 1024 + lane * 16;
#pragma unroll
    for (int n = 0; n < 16; ++n) h0[n] = hs[n];
    float cd = 1.f;

    for (int sc = 0; sc < CHUNK/SUB; ++sc) {
        int rb = row0 + sc * SUB;
        int lb = l0 + sc * SUB;
        __syncthreads();
#pragma unroll
        for (int it = 0; it < 3; ++it) {        // C rows rb-3..rb+31 (35x4 float4)
            int idx = it*64 + lane;
            if (idx < 140) {
                int s = idx >> 2, q = idx & 3;
                float4 val = {0.f,0.f,0.f,0.f};
                if (lb - 3 + s >= 0)
                    val = *(const float4*)(bcr + (size_t)(rb-3+s)*32 + 16 + q*4);
                *(float4*)&craw[wave][s][q*4] = val;
            }
        }
        if (lane < 32) av[wave][lane] = dAT[(size_t)tb + sc*SUB + lane];
        float yr[SUB];
#pragma unroll
        for (int s = 0; s < SUB; ++s)
            yr[s] = bf2f(ylocal16[(size_t)(rb+s)*DINNER + cx]);
        __syncthreads();
#pragma unroll
        for (int it = 0; it < 8; ++it) {        // conv C -> csc
            int s = it*4 + (lane >> 4);
            float v = cbc + craw[wave][s][nC]*cwc0 + craw[wave][s+1][nC]*cwc1
                          + craw[wave][s+2][nC]*cwc2 + craw[wave][s+3][nC]*cwc3;
            csc[wave][s][nC] = siluf(v);
        }
        __syncthreads();
#pragma unroll 4
        for (int s = 0; s < SUB; ++s) {
            cd *= av[wave][s];
            const float* cp = csc[wave][s];
            float corr = 0.f;
#pragma unroll
            for (int n = 0; n < 16; ++n) corr += cp[n] * h0[n];
            ylocal16[(size_t)(rb+s)*DINNER + cx] = f2bf(yr[s] + cd * corr);
        }
    }
}

// ---------------------------------------------------------------------------
// Gating + RMSNorm -> bf16 (16 B loads/stores)
// ---------------------------------------------------------------------------
__global__ __launch_bounds__(256) void gate_kernel(
    const unsigned short* __restrict__ yv16, const unsigned short* __restrict__ z16,
    const float* __restrict__ gw, unsigned short* __restrict__ g16)
{
    int wave = threadIdx.x >> 6, lane = threadIdx.x & 63;
    int token = blockIdx.x * 4 + wave;
    const uint4* yrow = (const uint4*)(yv16 + (size_t)token * DINNER);
    const uint4* zrow = (const uint4*)(z16 + (size_t)token * DINNER);
    float g[3][8];
    float ss = 0.f;
#pragma unroll
    for (int j = 0; j < 3; ++j) {
        uint4 y8 = yrow[lane + j*64];
        uint4 z8 = zrow[lane + j*64];
        const uint32_t* yp = (const uint32_t*)&y8;
        const uint32_t* zp = (const uint32_t*)&z8;
#pragma unroll
        for (int q = 0; q < 4; ++q) {
            float a = bfl(yp[q]) * siluf(bfl(zp[q]));
            float bvl = bfh(yp[q]) * siluf(bfh(zp[q]));
            g[j][q*2]   = a;
            g[j][q*2+1] = bvl;
            ss += a*a + bvl*bvl;
        }
    }
#pragma unroll
    for (int o = 32; o > 0; o >>= 1) ss += __shfl_xor(ss, o, 64);
    float scale = rsqrtf(ss * (1.f/1536.f) + EPSV);
    uint4* orow = (uint4*)(g16 + (size_t)token * DINNER);
#pragma unroll
    for (int j = 0; j < 3; ++j) {
        int ebase = (lane + j*64) * 8;
        float4 w0 = *(const float4*)(gw + ebase);
        float4 w1 = *(const float4*)(gw + ebase + 4);
        uint4 p;
        p.x = packbf(g[j][0]*scale*w0.x, g[j][1]*scale*w0.y);
        p.y = packbf(g[j][2]*scale*w0.z, g[j][3]*scale*w0.w);
        p.z = packbf(g[j][4]*scale*w1.x, g[j][5]*scale*w1.y);
        p.w = packbf(g[j][6]*scale*w1.z, g[j][7]*scale*w1.w);
        orow[lane + j*64] = p;
    }
}

// ---------------------------------------------------------------------------
extern "C" void kernel_launch(void* const* d_in, const int* in_sizes, int n_in,
                              void* d_out, int out_size, void* d_ws, size_t ws_size,
                              hipStream_t stream)
{
    const float* x        = (const float*)d_in[0];
    const float* ln_w     = (const float*)d_in[1];
    const float* ln_b     = (const float*)d_in[2];
    const float* W_in     = (const float*)d_in[3];
    const float* conv_w   = (const float*)d_in[4];
    const float* conv_b   = (const float*)d_in[5];
    const float* dt_bias  = (const float*)d_in[6];
    const float* A_log    = (const float*)d_in[7];
    const float* Dp       = (const float*)d_in[8];
    const float* gate_w   = (const float*)d_in[9];
    const float* W_out    = (const float*)d_in[10];
    float* out = (float*)d_out;

    char* ws = (char*)d_ws;
    size_t off = 0;
    auto alloc = [&](size_t bytes) -> void* {
        void* p = ws + off;
        off += (bytes + 255) & ~(size_t)255;
        return p;
    };
    unsigned short* u16    = (unsigned short*)alloc((size_t)NTOK*DMODEL*2);            // 12.58 MB
    unsigned short* win16  = (unsigned short*)alloc((size_t)NPAD*DMODEL*2);            //  4.92 MB
    float*          dtT    = (float*)alloc((size_t)NTOK*NHEADS*4);                     //  0.79 MB
    float*          dAT    = (float*)alloc((size_t)NTOK*NHEADS*4);                     //  0.79 MB
    float*          raw24  = (float*)alloc((size_t)NTOK*NHEADS*4);                     //  0.79 MB
    unsigned short* x16    = (unsigned short*)alloc((size_t)NTOK*DINNER*2);            // 25.17 MB
    float*          bcr    = (float*)alloc((size_t)NTOK*32*4);                         //  1.05 MB
    unsigned short* wout16 = (unsigned short*)alloc((size_t)DMODEL*DINNER*2);          //  2.36 MB
    unsigned short* z16    = (unsigned short*)alloc((size_t)NTOK*DINNER*2);            // 25.17 MB
    unsigned short* y16    = (unsigned short*)alloc((size_t)NTOK*DINNER*2);            // 25.17 MB
    unsigned short* g16    = (unsigned short*)alloc((size_t)NTOK*DINNER*2);            // 25.17 MB
    float*          pprod  = (float*)alloc((size_t)BATCH*NHEADS*NCHUNK*4);             //  0.01 MB
    // aliases (lifetime-checked):
    float* hloc   = (float*)u16;    // 12.58 MB == u16 size; u16 dead after gemm1
    float* hstart = (float*)g16;    // 12.58 MB <= g16; g16 first written at gate (after pass3)
    // high-water ~124 MB

    cvt_kernel<<<(NPAD*DMODEL + DMODEL*DINNER)/256, 256, 0, stream>>>(W_in, W_out, win16, wout16);
    ln_kernel<<<NTOK/4, 256, 0, stream>>>(x, ln_w, ln_b, u16);
    gemm1_kernel<<<800, 256, 0, stream>>>(u16, win16, z16, x16, bcr, raw24);
    dt_kernel<<<NTOK*NHEADS/256, 256, 0, stream>>>(raw24, dt_bias, A_log, dtT, dAT);
    scan_pass1<<<BATCH*NHEADS*NCHUNK/4, 256, 0, stream>>>(x16, bcr, dAT, dtT, conv_w, conv_b, Dp, hloc, pprod, y16);
    scan_pass2<<<BATCH*NHEADS, 64, 0, stream>>>(hloc, pprod, hstart);
    scan_pass3<<<BATCH*NHEADS*NCHUNK/4, 256, 0, stream>>>(bcr, dAT, conv_w, conv_b, hstart, y16);
    gate_kernel<<<NTOK/4, 256, 0, stream>>>(y16, z16, gate_w, g16);
    gemm2_kernel<<<768, 256, 0, stream>>>(g16, wout16, out, x);
}

// Round 9
// 271.223 us; speedup vs baseline: 1.6198x; 1.0444x over previous
//
#include <hip/hip_runtime.h>
#include <hip/hip_bf16.h>
#include <stdint.h>

#define SEQ      4096
#define BATCH    2
#define NTOK     (BATCH*SEQ)        // 8192
#define DMODEL   768
#define DINNER   1536
#define NHEADS   24
#define HEADDIM  64
#define DSTATE   16
#define NPAD     3200               // GEMM1 padded N (25*128)
#define EPSV     1e-5f
#define CHUNK    64
#define NCHUNK   (SEQ/CHUNK)        // 64
#define SUB      32

typedef __bf16 bf16x8 __attribute__((ext_vector_type(8)));
typedef float  floatx4 __attribute__((ext_vector_type(4)));

__device__ __forceinline__ unsigned short f2bf(float f) {
    union { float f; uint32_t u; } v; v.f = f;
    uint32_t u = v.u;
    uint32_t r = (u + 0x7fffu + ((u >> 16) & 1u)) >> 16;
    return (unsigned short)r;
}

__device__ __forceinline__ float bf2f(unsigned short h) {
    union { uint32_t u; float f; } v; v.u = (uint32_t)h << 16;
    return v.f;
}

__device__ __forceinline__ float bfl(uint32_t u) {
    union { uint32_t u; float f; } v; v.u = u << 16; return v.f;
}
__device__ __forceinline__ float bfh(uint32_t u) {
    union { uint32_t u; float f; } v; v.u = u & 0xffff0000u; return v.f;
}
__device__ __forceinline__ uint32_t packbf(float lo, float hi) {
    return (uint32_t)f2bf(lo) | ((uint32_t)f2bf(hi) << 16);
}

__device__ __forceinline__ float siluf(float x) { return x / (1.f + __expf(-x)); }

__device__ __forceinline__ void async_cp16(const void* g, void* l) {
    __builtin_amdgcn_global_load_lds(
        (const __attribute__((address_space(1))) void*)g,
        (__attribute__((address_space(3))) void*)l,
        16, 0, 0);
}

// ---------------------------------------------------------------------------
// Weight conversion.
// ---------------------------------------------------------------------------
__global__ __launch_bounds__(256) void cvt_kernel(
    const float* __restrict__ Win, const float* __restrict__ Wout,
    unsigned short* __restrict__ win16, unsigned short* __restrict__ wout16)
{
    int idx = blockIdx.x * 256 + threadIdx.x;
    const int n1 = NPAD * DMODEL;
    if (idx < n1) {
        int r = idx / DMODEL;
        win16[idx] = (r < 3128) ? f2bf(Win[idx]) : (unsigned short)0;
    } else {
        int i2 = idx - n1;
        if (i2 < DMODEL * DINNER) wout16[i2] = f2bf(Wout[i2]);
    }
}

// ---------------------------------------------------------------------------
// LayerNorm.  One wave per token.
// ---------------------------------------------------------------------------
__global__ __launch_bounds__(256) void ln_kernel(
    const float* __restrict__ x, const float* __restrict__ lnw, const float* __restrict__ lnb,
    unsigned short* __restrict__ u16)
{
    int wave = threadIdx.x >> 6, lane = threadIdx.x & 63;
    int token = blockIdx.x * 4 + wave;
    const float* row = x + (size_t)token * DMODEL;
    float4 v[3];
    float s = 0.f, ss = 0.f;
#pragma unroll
    for (int j = 0; j < 3; ++j) {
        v[j] = *(const float4*)(row + lane*4 + j*256);
        s  += v[j].x + v[j].y + v[j].z + v[j].w;
        ss += v[j].x*v[j].x + v[j].y*v[j].y + v[j].z*v[j].z + v[j].w*v[j].w;
    }
#pragma unroll
    for (int o = 32; o > 0; o >>= 1) { s += __shfl_xor(s, o, 64); ss += __shfl_xor(ss, o, 64); }
    float mean = s * (1.f/768.f);
    float var  = ss * (1.f/768.f) - mean*mean;
    float rstd = rsqrtf(var + EPSV);
    unsigned short* brow = u16 + (size_t)token * DMODEL;
#pragma unroll
    for (int j = 0; j < 3; ++j) {
        int cidx = lane*4 + j*256;
        float4 w4 = *(const float4*)(lnw + cidx);
        float4 b4 = *(const float4*)(lnb + cidx);
        float a0 = (v[j].x - mean)*rstd*w4.x + b4.x;
        float a1 = (v[j].y - mean)*rstd*w4.y + b4.y;
        float a2 = (v[j].z - mean)*rstd*w4.z + b4.z;
        float a3 = (v[j].w - mean)*rstd*w4.w + b4.w;
        ushort4 p; p.x = f2bf(a0); p.y = f2bf(a1); p.z = f2bf(a2); p.w = f2bf(a3);
        *(ushort4*)(brow + cidx) = p;
    }
}

// ---------------------------------------------------------------------------
// dt: softplus(raw + bias), dA = exp(dt * -exp(A_log)).
// ---------------------------------------------------------------------------
__global__ __launch_bounds__(256) void dt_kernel(
    const float* __restrict__ raw24, const float* __restrict__ dt_bias,
    const float* __restrict__ A_log, float* __restrict__ dtT, float* __restrict__ dAT)
{
    int tid = blockIdx.x * 256 + threadIdx.x;   // 0 .. NHEADS*NTOK-1
    int h   = tid >> 13;                        // NTOK = 8192
    int tok = tid & (NTOK-1);
    float raw = raw24[(size_t)tok*NHEADS + h] + dt_bias[h];
    float dt = (raw > 20.f) ? raw : log1pf(__expf(raw));
    float A = -__expf(A_log[h]);
    dtT[tid] = dt;
    dAT[tid] = __expf(dt * A);
}

// ---------------------------------------------------------------------------
// GEMM1: C = u16 @ win16^T.  Block 128x128, BK=64 (12 iters), wave tile 64x64,
// __launch_bounds__(256,3) -> 3 blocks/CU (acc=64 AGPR).  XCD swizzle:
// each XCD owns 8 M-tiles (1.57 MB A-slice, L2-resident), sweeps 25 N-tiles.
// 8-way chunk XOR LDS swizzle (src-side) -> 0 bank conflicts.
// Split store: z16 | x16 | bcr(f32 32 cols) | raw24(f32 24 cols).
// ---------------------------------------------------------------------------
__global__ __launch_bounds__(256, 3) void gemm1_kernel(
    const unsigned short* __restrict__ A, const unsigned short* __restrict__ Bt,
    unsigned short* __restrict__ z16, unsigned short* __restrict__ x16,
    float* __restrict__ bcr, float* __restrict__ raw24)
{
    constexpr int K = DMODEL;
    __shared__ unsigned short As[128*64];   // 16 KB
    __shared__ unsigned short Bs[128*64];   // 16 KB
    const int tid  = threadIdx.x;
    const int lane = tid & 63;
    const int wave = tid >> 6;
    const int id   = blockIdx.x;
    const int xcd  = id & 7;
    const int j5   = id >> 3;               // 0..199
    const int m0 = (xcd*8 + (j5 & 7)) * 128;
    const int n0 = (j5 >> 3) * 128;
    const int wm = (wave & 1) * 64;
    const int wn = (wave >> 1) * 64;

    floatx4 acc[4][4];
#pragma unroll
    for (int i = 0; i < 4; ++i)
#pragma unroll
        for (int j = 0; j < 4; ++j) acc[i][j] = floatx4{0.f, 0.f, 0.f, 0.f};

    const int srow8  = lane >> 3;                 // 0..7
    const int schunk = lane & 7;
    const int sscol  = (schunk ^ srow8) * 8;

    for (int k0 = 0; k0 < K; k0 += 64) {
        __syncthreads();
#pragma unroll
        for (int o = 0; o < 4; ++o) {             // A: wave rows [wave*32, +32)
            int row = wave*32 + o*8 + srow8;
            async_cp16(A + (size_t)(m0 + row) * K + k0 + sscol, As + row*64 + schunk*8);
        }
#pragma unroll
        for (int o = 0; o < 4; ++o) {             // B: wave rows [wave*32, +32)
            int row = wave*32 + o*8 + srow8;
            async_cp16(Bt + (size_t)(n0 + row) * K + k0 + sscol, Bs + row*64 + schunk*8);
        }
        __syncthreads();
        const int fr  = lane & 15;
        const int q8  = lane >> 4;
        const int key = fr & 7;
#pragma unroll
        for (int ks = 0; ks < 2; ++ks) {
            const int ch = ((ks*4 + q8) ^ key) * 8;
            bf16x8 a[4], b[4];
#pragma unroll
            for (int i = 0; i < 4; ++i)
                a[i] = *(const bf16x8*)(As + (wm + i*16 + fr)*64 + ch);
#pragma unroll
            for (int j = 0; j < 4; ++j)
                b[j] = *(const bf16x8*)(Bs + (wn + j*16 + fr)*64 + ch);
#pragma unroll
            for (int i = 0; i < 4; ++i)
#pragma unroll
                for (int j = 0; j < 4; ++j)
                    acc[i][j] = __builtin_amdgcn_mfma_f32_16x16x32_bf16(a[i], b[j], acc[i][j], 0, 0, 0);
        }
    }

    const int col = lane & 15;
    const int rq  = (lane >> 4) * 4;
    if (n0 < DINNER) {                      // tiles 0..11 -> z
#pragma unroll
        for (int i = 0; i < 4; ++i)
#pragma unroll
            for (int j = 0; j < 4; ++j)
#pragma unroll
                for (int r = 0; r < 4; ++r) {
                    int gm = m0 + wm + i*16 + rq + r;
                    int gn = n0 + wn + j*16 + col;
                    z16[(size_t)gm * DINNER + gn] = f2bf(acc[i][j][r]);
                }
    } else if (n0 < 3072) {                 // tiles 12..23 -> x (bf16)
#pragma unroll
        for (int i = 0; i < 4; ++i)
#pragma unroll
            for (int j = 0; j < 4; ++j)
#pragma unroll
                for (int r = 0; r < 4; ++r) {
                    int gm = m0 + wm + i*16 + rq + r;
                    int gn = n0 + wn + j*16 + col;
                    x16[(size_t)gm * DINNER + (gn - DINNER)] = f2bf(acc[i][j][r]);
                }
    } else {                                // tile 24: B/C -> bcr, dt -> raw24
#pragma unroll
        for (int i = 0; i < 4; ++i)
#pragma unroll
            for (int j = 0; j < 4; ++j)
#pragma unroll
                for (int r = 0; r < 4; ++r) {
                    int gm = m0 + wm + i*16 + rq + r;
                    int gn = n0 + wn + j*16 + col;
                    if (gn < 3104)
                        bcr[(size_t)gm * 32 + (gn - 3072)] = acc[i][j][r];
                    else if (gn < 3128)
                        raw24[(size_t)gm * NHEADS + (gn - 3104)] = acc[i][j][r];
                }
    }
}

// ---------------------------------------------------------------------------
// GEMM2: out = g16 @ wout16^T + x.  Block 64x128, BK=64, XCD swizzle.
// ---------------------------------------------------------------------------
__global__ __launch_bounds__(256, 4) void gemm2_kernel(
    const unsigned short* __restrict__ A, const unsigned short* __restrict__ Bt,
    float* __restrict__ Cf, const float* __restrict__ resid)
{
    constexpr int K = DINNER;
    __shared__ unsigned short As[64*64];    //  8 KB
    __shared__ unsigned short Bs[128*64];   // 16 KB
    const int tid  = threadIdx.x;
    const int lane = tid & 63;
    const int wave = tid >> 6;
    const int id   = blockIdx.x;
    const int xcd  = id & 7;
    const int j6   = id >> 3;               // 0..95
    const int m0 = (xcd*16 + j6/6) * 64;
    const int n0 = (j6 % 6) * 128;
    const int wm = (wave & 1) * 32;
    const int wn = (wave >> 1) * 64;

    floatx4 acc[2][4];
#pragma unroll
    for (int i = 0; i < 2; ++i)
#pragma unroll
        for (int j = 0; j < 4; ++j) acc[i][j] = floatx4{0.f, 0.f, 0.f, 0.f};

    const int srow8  = lane >> 3;
    const int schunk = lane & 7;
    const int sscol  = (schunk ^ srow8) * 8;

    for (int k0 = 0; k0 < K; k0 += 64) {
        __syncthreads();
#pragma unroll
        for (int o = 0; o < 2; ++o) {
            int row = wave*16 + o*8 + srow8;
            async_cp16(A + (size_t)(m0 + row) * K + k0 + sscol, As + row*64 + schunk*8);
        }
#pragma unroll
        for (int o = 0; o < 4; ++o) {
            int row = wave*32 + o*8 + srow8;
            async_cp16(Bt + (size_t)(n0 + row) * K + k0 + sscol, Bs + row*64 + schunk*8);
        }
        __syncthreads();
        const int fr  = lane & 15;
        const int q8  = lane >> 4;
        const int key = fr & 7;
#pragma unroll
        for (int ks = 0; ks < 2; ++ks) {
            const int ch = ((ks*4 + q8) ^ key) * 8;
            bf16x8 a[2], b[4];
#pragma unroll
            for (int i = 0; i < 2; ++i)
                a[i] = *(const bf16x8*)(As + (wm + i*16 + fr)*64 + ch);
#pragma unroll
            for (int j = 0; j < 4; ++j)
                b[j] = *(const bf16x8*)(Bs + (wn + j*16 + fr)*64 + ch);
#pragma unroll
            for (int i = 0; i < 2; ++i)
#pragma unroll
                for (int j = 0; j < 4; ++j)
                    acc[i][j] = __builtin_amdgcn_mfma_f32_16x16x32_bf16(a[i], b[j], acc[i][j], 0, 0, 0);
        }
    }

    const int col = lane & 15;
    const int rq  = (lane >> 4) * 4;
#pragma unroll
    for (int i = 0; i < 2; ++i)
#pragma unroll
        for (int j = 0; j < 4; ++j)
#pragma unroll
            for (int r = 0; r < 4; ++r) {
                int gm = m0 + wm + i*16 + rq + r;
                int gn = n0 + wn + j*16 + col;
                Cf[(size_t)gm * DMODEL + gn] = acc[i][j][r] + resid[(size_t)gm * DMODEL + gn];
            }
}

// ---------------------------------------------------------------------------
// Pass 1: local scan (h init 0) with fused conv+silu, 4 chunks per 256-thr
// block.  B/C broadcasts read as float4 (ds_read_b128) — the scan was
// LDS-issue-bound on 32 scalar b32 reads/step.
// ---------------------------------------------------------------------------
__global__ __launch_bounds__(256) void scan_pass1(
    const unsigned short* __restrict__ x16, const float* __restrict__ bcr,
    const float* __restrict__ dAT, const float* __restrict__ dtT,
    const float* __restrict__ cw, const float* __restrict__ cb, const float* __restrict__ Dp,
    float* __restrict__ hloc, float* __restrict__ pprod, unsigned short* __restrict__ ylocal16)
{
    int wave = threadIdx.x >> 6, lane = threadIdx.x & 63;
    int blk = blockIdx.x * 4 + wave;
    int c = blk & (NCHUNK-1), bh = blk >> 6;
    int h = bh % NHEADS, b = bh / NHEADS;
    int row0 = b * SEQ + c * CHUNK;
    int l0 = c * CHUNK;
    int tb = h * NTOK + row0;
    __shared__ float bcraw[4][35][32];
    __shared__ float bcsc[4][32][32];     // conv'd: 0..15 = B, 16..31 = C
    __shared__ float av[4][32], dv[4][32];

    const int cx = h*64 + lane;
    float cwx0 = cw[cx*4+0], cwx1 = cw[cx*4+1], cwx2 = cw[cx*4+2], cwx3 = cw[cx*4+3];
    float cbx = cb[cx];
    const int nBC = lane & 31;
    float cwc0 = cw[(DINNER+nBC)*4+0], cwc1 = cw[(DINNER+nBC)*4+1];
    float cwc2 = cw[(DINNER+nBC)*4+2], cwc3 = cw[(DINNER+nBC)*4+3];
    float cbc = cb[DINNER+nBC];
    float Dh = Dp[h];

    float xm3 = (l0 >= 3) ? bf2f(x16[(size_t)(row0-3)*DINNER + cx]) : 0.f;
    float xm2 = (l0 >= 2) ? bf2f(x16[(size_t)(row0-2)*DINNER + cx]) : 0.f;
    float xm1 = (l0 >= 1) ? bf2f(x16[(size_t)(row0-1)*DINNER + cx]) : 0.f;

    float hst[16];
#pragma unroll
    for (int n = 0; n < 16; ++n) hst[n] = 0.f;
    float aprod = 1.f;

    for (int sc = 0; sc < CHUNK/SUB; ++sc) {
        int rb = row0 + sc * SUB;
        int lb = l0 + sc * SUB;
        __syncthreads();
#pragma unroll
        for (int it = 0; it < 5; ++it) {        // B+C rows rb-3..rb+31 (35x8 float4)
            int idx = it*64 + lane;
            if (idx < 280) {
                int s = idx >> 3, q = idx & 7;
                float4 val = {0.f,0.f,0.f,0.f};
                if (lb - 3 + s >= 0)
                    val = *(const float4*)(bcr + (size_t)(rb-3+s)*32 + q*4);
                *(float4*)&bcraw[wave][s][q*4] = val;
            }
        }
        if (lane < 32) av[wave][lane] = dAT[(size_t)tb + sc*SUB + lane];
        else           dv[wave][lane-32] = dtT[(size_t)tb + sc*SUB + lane - 32];
        float xr[SUB];
#pragma unroll
        for (int s = 0; s < SUB; ++s)
            xr[s] = bf2f(x16[(size_t)(rb+s)*DINNER + cx]);
        __syncthreads();
#pragma unroll
        for (int it = 0; it < 16; ++it) {       // conv B,C -> bcsc
            int s = it*2 + (lane >> 5);
            float v = cbc + bcraw[wave][s][nBC]*cwc0 + bcraw[wave][s+1][nBC]*cwc1
                          + bcraw[wave][s+2][nBC]*cwc2 + bcraw[wave][s+3][nBC]*cwc3;
            bcsc[wave][s][nBC] = siluf(v);
        }
        __syncthreads();
#pragma unroll 2
        for (int s = 0; s < SUB; ++s) {
            float a = av[wave][s];
            float xc = siluf(cbx + xm3*cwx0 + xm2*cwx1 + xm1*cwx2 + xr[s]*cwx3);
            xm3 = xm2; xm2 = xm1; xm1 = xr[s];
            float scale = dv[wave][s] * xc;
            float y = Dh * xc;
            const float4* bp4 = (const float4*)&bcsc[wave][s][0];
            float4 bv[8];
#pragma unroll
            for (int q = 0; q < 8; ++q) bv[q] = bp4[q];      // 8x ds_read_b128
            const float* bp = (const float*)bv;
#pragma unroll
            for (int n = 0; n < 16; ++n) hst[n] = a*hst[n] + scale*bp[n];
#pragma unroll
            for (int n = 0; n < 16; ++n) y += hst[n] * bp[16+n];
            aprod *= a;
            ylocal16[(size_t)(rb+s)*DINNER + cx] = f2bf(y);
        }
    }
    float* o = hloc + (size_t)blk * 1024 + lane * 16;
#pragma unroll
    for (int n = 0; n < 16; ++n) o[n] = hst[n];
    if (lane == 0) pprod[blk] = aprod;
}

// Pass 2: sequential recombine over NCHUNK chunks per (b,h).
__global__ __launch_bounds__(64) void scan_pass2(
    const float* __restrict__ hloc, const float* __restrict__ pprod, float* __restrict__ hstart)
{
    int bh = blockIdx.x, lane = threadIdx.x;
    float hst[16];
#pragma unroll
    for (int n = 0; n < 16; ++n) hst[n] = 0.f;
    for (int c = 0; c < NCHUNK; ++c) {
        int blk = bh * NCHUNK + c;
        float* o = hstart + (size_t)blk * 1024 + lane * 16;
#pragma unroll
        for (int n = 0; n < 16; ++n) o[n] = hst[n];
        float P = pprod[blk];
        const float* hl = hloc + (size_t)blk * 1024 + lane * 16;
#pragma unroll
        for (int n = 0; n < 16; ++n) hst[n] = P * hst[n] + hl[n];
    }
}

// ---------------------------------------------------------------------------
// Pass 3 (lite): y[t] += cumdecay[t] * (C[t] . h_start), in-place, 4 chunks
// per block.  C read as float4.
// ---------------------------------------------------------------------------
__global__ __launch_bounds__(256) void scan_pass3(
    const float* __restrict__ bcr, const float* __restrict__ dAT,
    const float* __restrict__ cw, const float* __restrict__ cb,
    const float* __restrict__ hstart, unsigned short* __restrict__ ylocal16)
{
    int wave = threadIdx.x >> 6, lane = threadIdx.x & 63;
    int blk = blockIdx.x * 4 + wave;
    int c = blk & (NCHUNK-1), bh = blk >> 6;
    int h = bh % NHEADS, b = bh / NHEADS;
    int row0 = b * SEQ + c * CHUNK;
    int l0 = c * CHUNK;
    int tb = h * NTOK + row0;
    __shared__ float craw[4][35][16];
    __shared__ float csc[4][32][16];
    __shared__ float av[4][32];

    const int cx = h*64 + lane;
    const int nC = lane & 15;
    float cwc0 = cw[(DINNER+16+nC)*4+0], cwc1 = cw[(DINNER+16+nC)*4+1];
    float cwc2 = cw[(DINNER+16+nC)*4+2], cwc3 = cw[(DINNER+16+nC)*4+3];
    float cbc = cb[DINNER+16+nC];

    float h0[16];
    const float* hs = hstart + (size_t)blk * 1024 + lane * 16;
#pragma unroll
    for (int n = 0; n < 16; ++n) h0[n] = hs[n];
    float cd = 1.f;

    for (int sc = 0; sc < CHUNK/SUB; ++sc) {
        int rb = row0 + sc * SUB;
        int lb = l0 + sc * SUB;
        __syncthreads();
#pragma unroll
        for (int it = 0; it < 3; ++it) {        // C rows rb-3..rb+31 (35x4 float4)
            int idx = it*64 + lane;
            if (idx < 140) {
                int s = idx >> 2, q = idx & 3;
                float4 val = {0.f,0.f,0.f,0.f};
                if (lb - 3 + s >= 0)
                    val = *(const float4*)(bcr + (size_t)(rb-3+s)*32 + 16 + q*4);
                *(float4*)&craw[wave][s][q*4] = val;
            }
        }
        if (lane < 32) av[wave][lane] = dAT[(size_t)tb + sc*SUB + lane];
        float yr[SUB];
#pragma unroll
        for (int s = 0; s < SUB; ++s)
            yr[s] = bf2f(ylocal16[(size_t)(rb+s)*DINNER + cx]);
        __syncthreads();
#pragma unroll
        for (int it = 0; it < 8; ++it) {        // conv C -> csc
            int s = it*4 + (lane >> 4);
            float v = cbc + craw[wave][s][nC]*cwc0 + craw[wave][s+1][nC]*cwc1
                          + craw[wave][s+2][nC]*cwc2 + craw[wave][s+3][nC]*cwc3;
            csc[wave][s][nC] = siluf(v);
        }
        __syncthreads();
#pragma unroll 2
        for (int s = 0; s < SUB; ++s) {
            cd *= av[wave][s];
            const float4* cp4 = (const float4*)&csc[wave][s][0];
            float4 cv[4];
#pragma unroll
            for (int q = 0; q < 4; ++q) cv[q] = cp4[q];      // 4x ds_read_b128
            const float* cp = (const float*)cv;
            float corr = 0.f;
#pragma unroll
            for (int n = 0; n < 16; ++n) corr += cp[n] * h0[n];
            ylocal16[(size_t)(rb+s)*DINNER + cx] = f2bf(yr[s] + cd * corr);
        }
    }
}

// ---------------------------------------------------------------------------
// Gating + RMSNorm -> bf16 (16 B loads/stores)
// ---------------------------------------------------------------------------
__global__ __launch_bounds__(256) void gate_kernel(
    const unsigned short* __restrict__ yv16, const unsigned short* __restrict__ z16,
    const float* __restrict__ gw, unsigned short* __restrict__ g16)
{
    int wave = threadIdx.x >> 6, lane = threadIdx.x & 63;
    int token = blockIdx.x * 4 + wave;
    const uint4* yrow = (const uint4*)(yv16 + (size_t)token * DINNER);
    const uint4* zrow = (const uint4*)(z16 + (size_t)token * DINNER);
    float g[3][8];
    float ss = 0.f;
#pragma unroll
    for (int j = 0; j < 3; ++j) {
        uint4 y8 = yrow[lane + j*64];
        uint4 z8 = zrow[lane + j*64];
        const uint32_t* yp = (const uint32_t*)&y8;
        const uint32_t* zp = (const uint32_t*)&z8;
#pragma unroll
        for (int q = 0; q < 4; ++q) {
            float a = bfl(yp[q]) * siluf(bfl(zp[q]));
            float bvl = bfh(yp[q]) * siluf(bfh(zp[q]));
            g[j][q*2]   = a;
            g[j][q*2+1] = bvl;
            ss += a*a + bvl*bvl;
        }
    }
#pragma unroll
    for (int o = 32; o > 0; o >>= 1) ss += __shfl_xor(ss, o, 64);
    float scale = rsqrtf(ss * (1.f/1536.f) + EPSV);
    uint4* orow = (uint4*)(g16 + (size_t)token * DINNER);
#pragma unroll
    for (int j = 0; j < 3; ++j) {
        int ebase = (lane + j*64) * 8;
        float4 w0 = *(const float4*)(gw + ebase);
        float4 w1 = *(const float4*)(gw + ebase + 4);
        uint4 p;
        p.x = packbf(g[j][0]*scale*w0.x, g[j][1]*scale*w0.y);
        p.y = packbf(g[j][2]*scale*w0.z, g[j][3]*scale*w0.w);
        p.z = packbf(g[j][4]*scale*w1.x, g[j][5]*scale*w1.y);
        p.w = packbf(g[j][6]*scale*w1.z, g[j][7]*scale*w1.w);
        orow[lane + j*64] = p;
    }
}

// ---------------------------------------------------------------------------
extern "C" void kernel_launch(void* const* d_in, const int* in_sizes, int n_in,
                              void* d_out, int out_size, void* d_ws, size_t ws_size,
                              hipStream_t stream)
{
    const float* x        = (const float*)d_in[0];
    const float* ln_w     = (const float*)d_in[1];
    const float* ln_b     = (const float*)d_in[2];
    const float* W_in     = (const float*)d_in[3];
    const float* conv_w   = (const float*)d_in[4];
    const float* conv_b   = (const float*)d_in[5];
    const float* dt_bias  = (const float*)d_in[6];
    const float* A_log    = (const float*)d_in[7];
    const float* Dp       = (const float*)d_in[8];
    const float* gate_w   = (const float*)d_in[9];
    const float* W_out    = (const float*)d_in[10];
    float* out = (float*)d_out;

    char* ws = (char*)d_ws;
    size_t off = 0;
    auto alloc = [&](size_t bytes) -> void* {
        void* p = ws + off;
        off += (bytes + 255) & ~(size_t)255;
        return p;
    };
    unsigned short* u16    = (unsigned short*)alloc((size_t)NTOK*DMODEL*2);            // 12.58 MB
    unsigned short* win16  = (unsigned short*)alloc((size_t)NPAD*DMODEL*2);            //  4.92 MB
    float*          dtT    = (float*)alloc((size_t)NTOK*NHEADS*4);                     //  0.79 MB
    float*          dAT    = (float*)alloc((size_t)NTOK*NHEADS*4);                     //  0.79 MB
    float*          raw24  = (float*)alloc((size_t)NTOK*NHEADS*4);                     //  0.79 MB
    unsigned short* x16    = (unsigned short*)alloc((size_t)NTOK*DINNER*2);            // 25.17 MB
    float*          bcr    = (float*)alloc((size_t)NTOK*32*4);                         //  1.05 MB
    unsigned short* wout16 = (unsigned short*)alloc((size_t)DMODEL*DINNER*2);          //  2.36 MB
    unsigned short* z16    = (unsigned short*)alloc((size_t)NTOK*DINNER*2);            // 25.17 MB
    unsigned short* y16    = (unsigned short*)alloc((size_t)NTOK*DINNER*2);            // 25.17 MB
    unsigned short* g16    = (unsigned short*)alloc((size_t)NTOK*DINNER*2);            // 25.17 MB
    float*          pprod  = (float*)alloc((size_t)BATCH*NHEADS*NCHUNK*4);             //  0.01 MB
    // aliases (lifetime-checked):
    float* hloc   = (float*)u16;    // 12.58 MB == u16 size; u16 dead after gemm1
    float* hstart = (float*)g16;    // 12.58 MB <= g16; g16 first written at gate (after pass3)
    // high-water ~124 MB

    cvt_kernel<<<(NPAD*DMODEL + DMODEL*DINNER)/256, 256, 0, stream>>>(W_in, W_out, win16, wout16);
    ln_kernel<<<NTOK/4, 256, 0, stream>>>(x, ln_w, ln_b, u16);
    gemm1_kernel<<<1600, 256, 0, stream>>>(u16, win16, z16, x16, bcr, raw24);
    dt_kernel<<<NTOK*NHEADS/256, 256, 0, stream>>>(raw24, dt_bias, A_log, dtT, dAT);
    scan_pass1<<<BATCH*NHEADS*NCHUNK/4, 256, 0, stream>>>(x16, bcr, dAT, dtT, conv_w, conv_b, Dp, hloc, pprod, y16);
    scan_pass2<<<BATCH*NHEADS, 64, 0, stream>>>(hloc, pprod, hstart);
    scan_pass3<<<BATCH*NHEADS*NCHUNK/4, 256, 0, stream>>>(bcr, dAT, conv_w, conv_b, hstart, y16);
    gate_kernel<<<NTOK/4, 256, 0, stream>>>(y16, z16, gate_w, g16);
    gemm2_kernel<<<768, 256, 0, stream>>>(g16, wout16, out, x);
}